// Round 1
// 656.182 us; speedup vs baseline: 1.1067x; 1.1067x over previous
//
#include <hip/hip_runtime.h>
#include <hip/hip_bf16.h>

#define BB 256
#define CC 64
#define TT 40
#define DD 2560   // CC*TT
#define V1 25
#define V2 10
#define INTER 16
#define NH 8
#define DSH 320   // DD/NH

typedef __hip_bfloat16 bf16;
typedef unsigned int uint;
typedef unsigned short ushort;
typedef __attribute__((ext_vector_type(8))) short bf16x8;
typedef __attribute__((ext_vector_type(4))) float f32x4;

__device__ __forceinline__ float b2f(bf16 x) { return __bfloat162float(x); }

__device__ __forceinline__ ushort f2bb(float f) {
    uint x = __float_as_uint(f);
    uint r = x + 0x7fffu + ((x >> 16) & 1u);
    return (ushort)(r >> 16);
}
__device__ __forceinline__ float blo(uint u) { return __uint_as_float(u << 16); }
__device__ __forceinline__ float bhi(uint u) { return __uint_as_float(u & 0xffff0000u); }
__device__ __forceinline__ float b2f_us(ushort h) { return __uint_as_float(((uint)h) << 16); }
__device__ __forceinline__ uint4 pack8(const float* a) {
    uint4 pk;
    pk.x = (uint)f2bb(a[0]) | ((uint)f2bb(a[1]) << 16);
    pk.y = (uint)f2bb(a[2]) | ((uint)f2bb(a[3]) << 16);
    pk.z = (uint)f2bb(a[4]) | ((uint)f2bb(a[5]) << 16);
    pk.w = (uint)f2bb(a[6]) | ((uint)f2bb(a[7]) << 16);
    return pk;
}
__device__ __forceinline__ bf16x8 ldfrag8(const ushort* p) {
    union { bf16x8 v; uint2 u[2]; } t;
    t.u[0] = *(const uint2*)p;
    t.u[1] = *(const uint2*)(p + 4);
    return t.v;
}

// ---------------------------------------------------------------------------
// gcn_S3 (V=25, fck+fcv fused): grid = (tc*256 + b), 1280 blocks.
// Per block: stage x chunk (8 t's of all v,c) once; EXPORT it as bf16 in
// transposed layout Xbf[((b*25+v)*40+t)*64+c] (coalesced, read by apply3);
// then for each subset s: proj MFMA + Gram MFMA -> Mpart.
// ---------------------------------------------------------------------------
__global__ __launch_bounds__(256) void gcn_S3(
    const float* __restrict__ X,
    const float* __restrict__ Wa0, const float* __restrict__ ba0,
    const float* __restrict__ Wb0, const float* __restrict__ bb0,
    const float* __restrict__ Wa1, const float* __restrict__ ba1,
    const float* __restrict__ Wb1, const float* __restrict__ bb1,
    bf16* __restrict__ Xw, float* __restrict__ Mpart) {
    __shared__ ushort xsT[208][72];    // [p=v*8+tl][c]; rows 200..207 garbage
    __shared__ ushort wT[64][72];      // [mat*16+j][c] for current s
    __shared__ ushort abT[4][32][136]; // [mat][v][j*8+tl]
    __shared__ float biasS[64];

    const int tid = threadIdx.x;
    const int b = blockIdx.x & 255, tc = blockIdx.x >> 8;
    const int t0 = tc * 8;
    const int lane = tid & 63, w = tid >> 6;
    const int ln = lane & 15, lq = lane >> 4;

    // stage x chunk: (v,c) -> 8 t's, bf16 into transposed rows p=v*8+tl
    const float* Xb = X + (size_t)b * V1 * DD;
    for (int e = tid; e < V1 * 64; e += 256) {
        const int v = e >> 6, c = e & 63;
        const float* src = Xb + (size_t)v * DD + c * TT + t0;
        const float4 f0 = *(const float4*)src;
        const float4 f1 = *(const float4*)(src + 4);
        const float tmp[8] = {f0.x, f0.y, f0.z, f0.w, f1.x, f1.y, f1.z, f1.w};
        #pragma unroll
        for (int tl = 0; tl < 8; ++tl) xsT[v * 8 + tl][c] = f2bb(tmp[tl]);
    }
    __syncthreads();                   // xsT complete

    // export bf16 transposed X: Xw[((b*25+v)*40 + t0+tl)*64 + c], uint4 rows
    for (int e = tid; e < 1600; e += 256) {
        const int p = e >> 3, c8 = e & 7;
        const int v = p >> 3, tl = p & 7;
        *(uint4*)(Xw + (((size_t)b * V1 + v) * TT + t0 + tl) * 64 + c8 * 8) =
            *(const uint4*)&xsT[p][c8 * 8];
    }

    for (int s = 0; s < 3; ++s) {
        if (s) __syncthreads();        // prev Gram done with abT, proj done with wT
        // stage W (4 mats x 16 x 64) + bias for this s
        for (int e = tid; e < 4096; e += 256) {
            const int mat = e >> 10, r = e & 1023;
            const float* Wp = (mat == 0) ? Wa0 : (mat == 1) ? Wb0 : (mat == 2) ? Wa1 : Wb1;
            wT[(mat << 4) + (r >> 6)][r & 63] = f2bb(Wp[s * 1024 + r]);
        }
        if (tid < 64) {
            const int mat = tid >> 4, j = tid & 15;
            const float* bp = (mat == 0) ? ba0 : (mat == 1) ? bb0 : (mat == 2) ? ba1 : bb1;
            biasS[tid] = bp[s * 16 + j];
        }
        __syncthreads();               // wT/xsT ready

        // ---- projection: wave w computes mat w over 13 n-tiles ----
        const bf16x8 a0 = *(const bf16x8*)&wT[w * 16 + ln][lq * 8];
        const bf16x8 a1 = *(const bf16x8*)&wT[w * 16 + ln][lq * 8 + 32];
        float br[4];
        #pragma unroll
        for (int r = 0; r < 4; ++r) br[r] = biasS[w * 16 + lq * 4 + r];
        for (int nt = 0; nt < 13; ++nt) {
            const bf16x8 b0 = *(const bf16x8*)&xsT[nt * 16 + ln][lq * 8];
            const bf16x8 b1 = *(const bf16x8*)&xsT[nt * 16 + ln][lq * 8 + 32];
            f32x4 acc = (f32x4){0.f, 0.f, 0.f, 0.f};
            acc = __builtin_amdgcn_mfma_f32_16x16x32_bf16(a0, b0, acc, 0, 0, 0);
            acc = __builtin_amdgcn_mfma_f32_16x16x32_bf16(a1, b1, acc, 0, 0, 0);
            const int p = nt * 16 + ln;
            if (p < 200) {
                const int v = p >> 3, tl = p & 7;
                #pragma unroll
                for (int r = 0; r < 4; ++r)
                    abT[w][v][(lq * 4 + r) * 8 + tl] = f2bb(acc[r] + br[r]);
            }
        }
        __syncthreads();               // abT ready

        // ---- Gram: 8 tile-units (np,mt,nt), wave w does units w and w+4 ----
        #pragma unroll
        for (int uu = 0; uu < 2; ++uu) {
            const int u = w + uu * 4;
            const int np = u >> 2, mt = (u >> 1) & 1, ntl = u & 1;
            const ushort* Ap = &abT[np * 2 + 0][mt * 16 + ln][lq * 8];
            const ushort* Bp = &abT[np * 2 + 1][ntl * 16 + ln][lq * 8];
            f32x4 g = (f32x4){0.f, 0.f, 0.f, 0.f};
            g = __builtin_amdgcn_mfma_f32_16x16x32_bf16(
                    *(const bf16x8*)Ap, *(const bf16x8*)Bp, g, 0, 0, 0);
            g = __builtin_amdgcn_mfma_f32_16x16x32_bf16(
                    *(const bf16x8*)(Ap + 32), *(const bf16x8*)(Bp + 32), g, 0, 0, 0);
            g = __builtin_amdgcn_mfma_f32_16x16x32_bf16(
                    *(const bf16x8*)(Ap + 64), *(const bf16x8*)(Bp + 64), g, 0, 0, 0);
            g = __builtin_amdgcn_mfma_f32_16x16x32_bf16(
                    *(const bf16x8*)(Ap + 96), *(const bf16x8*)(Bp + 96), g, 0, 0, 0);
            const int vp = ntl * 16 + ln;
            if (vp < V1) {
                float* Mb = Mpart + (((size_t)tc * 256 + b) * 6 + (s * 2 + np)) * 625;
                #pragma unroll
                for (int r = 0; r < 4; ++r) {
                    const int v = mt * 16 + lq * 4 + r;
                    if (v < V1) Mb[v * V1 + vp] = g[r];
                }
            }
        }
    }
}

// ---------------------------------------------------------------------------
// reduce_softmax: grid (b, snp=s*2+np). Sum 5 chunk-partials, column softmax
// over v (axis=-2), + PA, write S (B,3,25,25).
// ---------------------------------------------------------------------------
__global__ __launch_bounds__(128) void reduce_softmax(
    const float* __restrict__ Mpart,
    const float* __restrict__ PA0, const float* __restrict__ PA1,
    float* __restrict__ S1out, float* __restrict__ S2out) {
    __shared__ float Ms[625];
    const int tid = threadIdx.x, b = blockIdx.x, snp = blockIdx.y;
    const int s = snp >> 1, np = snp & 1;
    for (int e = tid; e < 625; e += 128) {
        float sum = 0.f;
        #pragma unroll
        for (int tcc = 0; tcc < 5; ++tcc)
            sum += Mpart[(((size_t)tcc * 256 + b) * 6 + snp) * 625 + e];
        Ms[e] = sum;
    }
    __syncthreads();
    if (tid < V1) {
        const int vp = tid;
        const float invIT = 1.0f / 640.0f;
        float mx = -1e30f;
        for (int v = 0; v < V1; ++v) mx = fmaxf(mx, Ms[v * V1 + vp]);
        float sum = 0.f;
        for (int v = 0; v < V1; ++v) sum += expf((Ms[v * V1 + vp] - mx) * invIT);
        const float rs = 1.f / sum;
        const float* PAn = np ? PA1 : PA0;
        float* Sn = np ? S2out : S1out;
        for (int v = 0; v < V1; ++v) {
            const float e_ = expf((Ms[v * V1 + vp] - mx) * invIT);
            Sn[((size_t)(b * 3 + s) * V1 + v) * V1 + vp] =
                e_ * rs + PAn[(s * V1 + v) * V1 + vp];
        }
    }
}

// ---------------------------------------------------------------------------
// gcn_S2 (VALU version, kept for the small V=10 fco case).
// ---------------------------------------------------------------------------
template<int V, int NP>
__global__ __launch_bounds__(256) void gcn_S2(
    const float* __restrict__ X,
    const float* __restrict__ Wa0, const float* __restrict__ ba0,
    const float* __restrict__ Wb0, const float* __restrict__ bb0,
    const float* __restrict__ PA0, float* __restrict__ Sout0,
    const float* __restrict__ Wa1, const float* __restrict__ ba1,
    const float* __restrict__ Wb1, const float* __restrict__ bb1,
    const float* __restrict__ PA1, float* __restrict__ Sout1) {
    constexpr int TC = 8;
    constexpr int NCH = TT / TC;
    constexpr int P = V * TC;
    constexpr int ROWS = NP * 32;
    constexpr int NRQ = ROWS / 4;
    constexpr int NC8 = P / 8;
    constexpr int NTILE = NRQ * NC8;
    constexpr int NM = NP * V * V;
    constexpr int NMI = (NM + 255) / 256;

    __shared__ ushort xs[64][P];
    __shared__ ushort ab[ROWS][P];
    __shared__ ushort wT[64][ROWS];
    __shared__ float biasL[ROWS];
    __shared__ float M[NM];

    const int tid = threadIdx.x, b = blockIdx.x, s = blockIdx.y;

    for (int e = tid; e < 16 * 64; e += 256) {
        int c = e & 63;
        int j = e >> 6;
        wT[c][j]      = f2bb(Wa0[s * 1024 + e]);
        wT[c][16 + j] = f2bb(Wb0[s * 1024 + e]);
        if constexpr (NP == 2) {
            wT[c][32 + j] = f2bb(Wa1[s * 1024 + e]);
            wT[c][48 + j] = f2bb(Wb1[s * 1024 + e]);
        }
    }
    if (tid < 16) {
        biasL[tid]      = ba0[s * 16 + tid];
        biasL[16 + tid] = bb0[s * 16 + tid];
        if constexpr (NP == 2) {
            biasL[32 + tid] = ba1[s * 16 + tid];
            biasL[48 + tid] = bb1[s * 16 + tid];
        }
    }

    float macc[NMI];
    #pragma unroll
    for (int k = 0; k < NMI; ++k) macc[k] = 0.f;

    const float* Xb = X + (size_t)b * V * DD;
    for (int tc = 0; tc < NCH; ++tc) {
        const int t0 = tc * TC;
        for (int e = tid; e < V * 64; e += 256) {
            const int v = e >> 6, c = e & 63;
            const float* src = Xb + (size_t)v * DD + c * TT + t0;
            const float4 f0 = *(const float4*)src;
            const float4 f1 = *(const float4*)(src + 4);
            const float tmp[8] = {f0.x, f0.y, f0.z, f0.w, f1.x, f1.y, f1.z, f1.w};
            *(uint4*)&xs[c][v * 8] = pack8(tmp);
        }
        __syncthreads();
        for (int tau = tid; tau < NTILE; tau += 256) {
            const int rq = tau % NRQ, co = tau / NRQ;
            float acc[4][8];
            #pragma unroll
            for (int r = 0; r < 4; ++r) {
                const float bv = biasL[4 * rq + r];
                #pragma unroll
                for (int cc = 0; cc < 8; ++cc) acc[r][cc] = bv;
            }
            for (int c = 0; c < 64; ++c) {
                const uint2 wv = *(const uint2*)&wT[c][4 * rq];
                const uint4 xv = *(const uint4*)&xs[c][8 * co];
                const float w0 = blo(wv.x), w1 = bhi(wv.x);
                const float w2 = blo(wv.y), w3 = bhi(wv.y);
                const float x0 = blo(xv.x), x1 = bhi(xv.x);
                const float x2 = blo(xv.y), x3 = bhi(xv.y);
                const float x4 = blo(xv.z), x5 = bhi(xv.z);
                const float x6 = blo(xv.w), x7 = bhi(xv.w);
                acc[0][0] += w0 * x0; acc[0][1] += w0 * x1;
                acc[0][2] += w0 * x2; acc[0][3] += w0 * x3;
                acc[0][4] += w0 * x4; acc[0][5] += w0 * x5;
                acc[0][6] += w0 * x6; acc[0][7] += w0 * x7;
                acc[1][0] += w1 * x0; acc[1][1] += w1 * x1;
                acc[1][2] += w1 * x2; acc[1][3] += w1 * x3;
                acc[1][4] += w1 * x4; acc[1][5] += w1 * x5;
                acc[1][6] += w1 * x6; acc[1][7] += w1 * x7;
                acc[2][0] += w2 * x0; acc[2][1] += w2 * x1;
                acc[2][2] += w2 * x2; acc[2][3] += w2 * x3;
                acc[2][4] += w2 * x4; acc[2][5] += w2 * x5;
                acc[2][6] += w2 * x6; acc[2][7] += w2 * x7;
                acc[3][0] += w3 * x0; acc[3][1] += w3 * x1;
                acc[3][2] += w3 * x2; acc[3][3] += w3 * x3;
                acc[3][4] += w3 * x4; acc[3][5] += w3 * x5;
                acc[3][6] += w3 * x6; acc[3][7] += w3 * x7;
            }
            #pragma unroll
            for (int r = 0; r < 4; ++r)
                *(uint4*)&ab[4 * rq + r][8 * co] = pack8(acc[r]);
        }
        __syncthreads();
        #pragma unroll
        for (int k = 0; k < NMI; ++k) {
            const int idx = tid + k * 256;
            if (idx < NM) {
                const int np = idx / (V * V), r = idx % (V * V);
                const int v = r / V, vp = r % V;
                const int ra = np * 32, rb = np * 32 + 16;
                float mm = 0.f;
                #pragma unroll
                for (int j = 0; j < 16; ++j) {
                    const uint4 av = *(const uint4*)&ab[ra + j][v * 8];
                    const uint4 bv = *(const uint4*)&ab[rb + j][vp * 8];
                    mm += blo(av.x) * blo(bv.x) + bhi(av.x) * bhi(bv.x)
                        + blo(av.y) * blo(bv.y) + bhi(av.y) * bhi(bv.y)
                        + blo(av.z) * blo(bv.z) + bhi(av.z) * bhi(bv.z)
                        + blo(av.w) * blo(bv.w) + bhi(av.w) * bhi(bv.w);
                }
                macc[k] += mm;
            }
        }
    }

    #pragma unroll
    for (int k = 0; k < NMI; ++k) {
        const int idx = tid + k * 256;
        if (idx < NM) M[idx] = macc[k];
    }
    __syncthreads();

    const float invIT = 1.0f / 640.0f;
    if (tid < NP * V) {
        const int np = tid / V, vp = tid % V;
        const float* Mn = &M[np * V * V];
        float mx = -1e30f;
        for (int v = 0; v < V; ++v) mx = fmaxf(mx, Mn[v * V + vp]);
        float sum = 0.f;
        for (int v = 0; v < V; ++v) sum += expf((Mn[v * V + vp] - mx) * invIT);
        const float rs = 1.f / sum;
        const float* PAn = (np == 0) ? PA0 : PA1;
        float* Sn = (np == 0) ? Sout0 : Sout1;
        for (int v = 0; v < V; ++v) {
            const float e_ = expf((Mn[v * V + vp] - mx) * invIT);
            Sn[((size_t)(b * 3 + s) * V + v) * V + vp] =
                e_ * rs + PAn[(s * V + v) * V + vp];
        }
    }
}

// ---------------------------------------------------------------------------
// gcn_apply3: register GEMM-1 + MFMA GEMM-2.
// MODE 0 (V=25): input = Xbf bf16 [b][v][t][c] (coalesced 128B rows),
//                output = bf16 same layout (coalesced uint4 writes).
// MODE 1 (V=10): input = X fp32 (b,v,c,t), output = fp32 + Obuf residual.
// ---------------------------------------------------------------------------
template<int V, int TC, int MODE>
__global__ __launch_bounds__(256) void gcn_apply3(const float* __restrict__ X,
                                                  const bf16* __restrict__ Xbf,
                                                  const float* __restrict__ Sbuf,
                                                  const float* __restrict__ Wd,
                                                  const float* __restrict__ bd,
                                                  const float* __restrict__ gamma,
                                                  const float* __restrict__ beta,
                                                  bf16* __restrict__ out_bf,
                                                  float* __restrict__ out_f,
                                                  const float* __restrict__ Obuf) {
    constexpr int VSLOT = 128 / TC;
    constexpr int ROWS = V * TC;
    constexpr int NT = (V == 25) ? 7 : 5;

    __shared__ ushort xsT[ROWS][72];
    __shared__ ushort zsT[128][72];
    __shared__ ushort wdT[64][72];
    __shared__ ushort Sl[3][VSLOT][34];
    __shared__ float bds[64], scl[64], bet[64];

    const int tid = threadIdx.x, b = blockIdx.x, chunk = blockIdx.y;
    const int ci = tid >> 4, pj = tid & 15;
    const int lane = tid & 63, w = tid >> 6;
    const int ln = lane & 15, lq = lane >> 4;
    const int t0 = chunk * TC;

    for (int e = tid; e < 3 * VSLOT * 17; e += 256) ((uint*)Sl)[e] = 0u;
    if (tid < 64) {
        bds[tid] = bd[tid] + bd[64 + tid] + bd[128 + tid];
        scl[tid] = gamma[tid] * rsqrtf(1.f + 1e-5f);
        bet[tid] = beta[tid];
    }
    __syncthreads();
    for (int e = tid; e < 3 * V * V; e += 256) {
        int s = e / (V * V), r = e % (V * V);
        Sl[s][r / V][r % V] = f2bb(Sbuf[(size_t)b * 3 * V * V + e]);
    }
    if constexpr (MODE == 0) {
        // coalesced bf16 staging: 128B rows per (v, t)
        for (int e = tid; e < ROWS * 8; e += 256) {
            const int p = e >> 3, c8 = e & 7;
            const int v = p / TC, tl = p % TC;
            *(uint4*)&xsT[p][c8 * 8] =
                *(const uint4*)(Xbf + (((size_t)b * V + v) * TT + t0 + tl) * 64 + c8 * 8);
        }
    } else {
        const float* Xb = X + (size_t)b * V * DD;
        for (int e = tid; e < V * 64 * TC; e += 256) {
            int v = e / (64 * TC), inner = e % (64 * TC);
            int c = inner / TC, tl = inner % TC;
            xsT[v * TC + tl][c] = f2bb(Xb[(size_t)v * DD + c * TT + t0 + tl]);
        }
    }
    __syncthreads();

    f32x4 acc[NT];
    #pragma unroll
    for (int tn = 0; tn < NT; ++tn) acc[tn] = (f32x4){0.f, 0.f, 0.f, 0.f};

    for (int s = 0; s < 3; ++s) {
        if (s) __syncthreads();
        for (int e = tid; e < 4096; e += 256)
            wdT[e >> 6][e & 63] = f2bb(Wd[s * 4096 + e]);

        float za[4][8];
        #pragma unroll
        for (int r = 0; r < 4; ++r)
            #pragma unroll
            for (int cc = 0; cc < 8; ++cc) za[r][cc] = 0.f;

        if constexpr (V == 25) {
            for (int v0 = 0; v0 < 25; ++v0) {
                const uint sv = *(const uint*)&Sl[s][v0][2 * pj];
                const float svx = blo(sv), svy = bhi(sv);
                #pragma unroll
                for (int tl = 0; tl < 4; ++tl) {
                    const uint2 u = *(const uint2*)&xsT[v0 * 4 + tl][ci * 4];
                    const float a0 = blo(u.x), a1 = bhi(u.x);
                    const float a2 = blo(u.y), a3 = bhi(u.y);
                    za[0][tl] += a0 * svx;  za[0][4 + tl] += a0 * svy;
                    za[1][tl] += a1 * svx;  za[1][4 + tl] += a1 * svy;
                    za[2][tl] += a2 * svx;  za[2][4 + tl] += a2 * svy;
                    za[3][tl] += a3 * svx;  za[3][4 + tl] += a3 * svy;
                }
            }
        } else {
            for (int v0 = 0; v0 < 10; ++v0) {
                const float sv = b2f_us(Sl[s][v0][pj]);
                #pragma unroll
                for (int tl = 0; tl < 8; ++tl) {
                    const uint2 u = *(const uint2*)&xsT[v0 * 8 + tl][ci * 4];
                    za[0][tl] += blo(u.x) * sv;
                    za[1][tl] += bhi(u.x) * sv;
                    za[2][tl] += blo(u.y) * sv;
                    za[3][tl] += bhi(u.y) * sv;
                }
            }
        }
        #pragma unroll
        for (int cc = 0; cc < 8; ++cc) {
            uint2 pk;
            pk.x = (uint)f2bb(za[0][cc]) | ((uint)f2bb(za[1][cc]) << 16);
            pk.y = (uint)f2bb(za[2][cc]) | ((uint)f2bb(za[3][cc]) << 16);
            *(uint2*)&zsT[pj * 8 + cc][ci * 4] = pk;
        }
        __syncthreads();

        const bf16x8 a0 = *(const bf16x8*)&wdT[w * 16 + ln][lq * 8];
        const bf16x8 a1 = *(const bf16x8*)&wdT[w * 16 + ln][lq * 8 + 32];
        #pragma unroll
        for (int tn = 0; tn < NT; ++tn) {
            const bf16x8 b0 = ldfrag8(&zsT[tn * 16 + ln][lq * 8]);
            const bf16x8 b1 = ldfrag8(&zsT[tn * 16 + ln][lq * 8 + 32]);
            acc[tn] = __builtin_amdgcn_mfma_f32_16x16x32_bf16(a0, b0, acc[tn], 0, 0, 0);
            acc[tn] = __builtin_amdgcn_mfma_f32_16x16x32_bf16(a1, b1, acc[tn], 0, 0, 0);
        }
    }

    __syncthreads();
    {
        const int c0 = w * 16 + lq * 4;
        float bb[4], ss[4], be[4];
        #pragma unroll
        for (int r = 0; r < 4; ++r) {
            bb[r] = bds[c0 + r]; ss[r] = scl[c0 + r]; be[r] = bet[c0 + r];
        }
        #pragma unroll
        for (int tn = 0; tn < NT; ++tn) {
            const int p = tn * 16 + ln;
            if (p < ROWS) {
                const uint2 u = *(const uint2*)&xsT[p][c0];
                const float rs[4] = {blo(u.x), bhi(u.x), blo(u.y), bhi(u.y)};
                float y[4];
                #pragma unroll
                for (int r = 0; r < 4; ++r)
                    y[r] = fmaxf((acc[tn][r] + bb[r]) * ss[r] + be[r] + rs[r], 0.f);
                uint2 pk;
                pk.x = (uint)f2bb(y[0]) | ((uint)f2bb(y[1]) << 16);
                pk.y = (uint)f2bb(y[2]) | ((uint)f2bb(y[3]) << 16);
                *(uint2*)&zsT[p][c0] = pk;
            }
        }
    }
    __syncthreads();

    if constexpr (MODE == 0) {
        // coalesced bf16 output in the same [b][v][t][c] layout
        for (int e = tid; e < ROWS * 8; e += 256) {
            const int p = e >> 3, c8 = e & 7;
            const int v = p / TC, tl = p % TC;
            *(uint4*)(out_bf + (((size_t)b * V + v) * TT + t0 + tl) * 64 + c8 * 8) =
                *(const uint4*)&zsT[p][c8 * 8];
        }
    } else {
        const int v = pj;
        if (v < V) {
            #pragma unroll
            for (int r = 0; r < 4; ++r) {
                const int c = ci * 4 + r;
                const size_t base = (size_t)b * V * DD + (size_t)v * DD + c * TT + t0;
                const float4 o0 = *(const float4*)&Obuf[base];
                const float4 o1 = *(const float4*)&Obuf[base + 4];
                float4 y0, y1;
                y0.x = o0.x + b2f_us(zsT[v * 8 + 0][c]);
                y0.y = o0.y + b2f_us(zsT[v * 8 + 1][c]);
                y0.z = o0.z + b2f_us(zsT[v * 8 + 2][c]);
                y0.w = o0.w + b2f_us(zsT[v * 8 + 3][c]);
                y1.x = o1.x + b2f_us(zsT[v * 8 + 4][c]);
                y1.y = o1.y + b2f_us(zsT[v * 8 + 5][c]);
                y1.z = o1.z + b2f_us(zsT[v * 8 + 6][c]);
                y1.w = o1.w + b2f_us(zsT[v * 8 + 7][c]);
                *(float4*)&out_f[base] = y0;
                *(float4*)&out_f[base + 4] = y1;
            }
        }
    }
}

// ---------------------------------------------------------------------------
// attention: Kg/Vg now in [b][v][t][c] layout; heads read 16B channel slices
// (all 8 heads of a b land on the same XCD since gridDim.x=256 ≡ 0 mod 8,
// so complementary slices hit L2). LDS layouts and compute unchanged.
// ---------------------------------------------------------------------------
__global__ __launch_bounds__(256) void attn_kernel(const float* __restrict__ Q,
                                                   const bf16* __restrict__ Kg,
                                                   const bf16* __restrict__ Vg,
                                                   float* __restrict__ O) {
    int b = blockIdx.x, h = blockIdx.y, tid = threadIdx.x;
    __shared__ float qs[10 * DSH];
    __shared__ float ks[V1 * 321];
    __shared__ float att[10 * V1];
    const float* Qb = Q + (size_t)b * 10 * DD + h * DSH;
    for (int e = tid; e < 10 * DSH; e += 256) {
        int q = e / DSH, d = e % DSH;
        qs[e] = Qb[(size_t)q * DD + d];
    }
    // stage K slice: ks[kk*321 + cl*40 + t] = Kg[((b*25+kk)*40+t)*64 + h*8+cl]
    const bf16* Kb = Kg + (size_t)b * V1 * DD;
    for (int e = tid; e < V1 * TT; e += 256) {
        const int kk = e / TT, t = e % TT;
        const uint4 u = *(const uint4*)(Kb + ((size_t)kk * TT + t) * 64 + h * 8);
        const ushort* us = (const ushort*)&u;
        float* dst = &ks[kk * 321 + t];
        #pragma unroll
        for (int cl = 0; cl < 8; ++cl) dst[cl * 40] = b2f_us(us[cl]);
    }
    __syncthreads();
    const float scale = 0.019764235376052370f;  // 1/sqrt(2560)
    for (int e = tid; e < 10 * V1; e += 256) {
        int q = e / V1, kk = e % V1;
        float acc = 0.f;
        #pragma unroll 8
        for (int d = 0; d < DSH; ++d) acc += qs[q * DSH + d] * ks[kk * 321 + d];
        att[e] = acc * scale;
    }
    __syncthreads();
    if (tid < 10) {
        float mx = -1e30f;
        for (int k = 0; k < V1; ++k) mx = fmaxf(mx, att[tid * V1 + k]);
        float sum = 0.f;
        for (int k = 0; k < V1; ++k) {
            float e_ = expf(att[tid * V1 + k] - mx);
            att[tid * V1 + k] = e_;
            sum += e_;
        }
        float r = 1.0f / sum;
        for (int k = 0; k < V1; ++k) att[tid * V1 + k] *= r;
    }
    __syncthreads();
    const bf16* Vb = Vg + (size_t)b * V1 * DD;
    float* Ob = O + (size_t)b * 10 * DD + h * DSH;
    for (int hh = 0; hh < 2; ++hh) {
        // stage V half-slice: ks[kk*321 + cl_l*40 + t] = Vg[...][h*8 + hh*4 + cl_l]
        for (int e = tid; e < V1 * TT; e += 256) {
            const int kk = e / TT, t = e % TT;
            const uint2 u = *(const uint2*)(Vb + ((size_t)kk * TT + t) * 64 + h * 8 + hh * 4);
            const ushort* us = (const ushort*)&u;
            float* dst = &ks[kk * 321 + t];
            #pragma unroll
            for (int cl = 0; cl < 4; ++cl) dst[cl * 40] = b2f_us(us[cl]);
        }
        __syncthreads();
        for (int e = tid; e < 10 * 160; e += 256) {
            int q = e / 160, dl = e % 160;
            float acc = 0.f;
            #pragma unroll
            for (int k = 0; k < V1; ++k) acc += att[q * V1 + k] * ks[k * 321 + dl];
            Ob[(size_t)q * DD + hh * 160 + dl] = qs[q * DSH + hh * 160 + dl] + acc;
        }
        __syncthreads();
    }
}

// ---------------------------------------------------------------------------
extern "C" void kernel_launch(void* const* d_in, const int* in_sizes, int n_in,
                              void* d_out, int out_size, void* d_ws, size_t ws_size,
                              hipStream_t stream) {
    const float* Q = (const float*)d_in[0];
    const float* K = (const float*)d_in[1];
    const float* fck_PA = (const float*)d_in[2];
    const float* fck_Wa = (const float*)d_in[3];
    const float* fck_ba = (const float*)d_in[4];
    const float* fck_Wb = (const float*)d_in[5];
    const float* fck_bb = (const float*)d_in[6];
    const float* fck_Wd = (const float*)d_in[7];
    const float* fck_bd = (const float*)d_in[8];
    const float* fck_gamma = (const float*)d_in[9];
    const float* fck_beta = (const float*)d_in[10];
    const float* fcv_PA = (const float*)d_in[11];
    const float* fcv_Wa = (const float*)d_in[12];
    const float* fcv_ba = (const float*)d_in[13];
    const float* fcv_Wb = (const float*)d_in[14];
    const float* fcv_bb = (const float*)d_in[15];
    const float* fcv_Wd = (const float*)d_in[16];
    const float* fcv_bd = (const float*)d_in[17];
    const float* fcv_gamma = (const float*)d_in[18];
    const float* fcv_beta = (const float*)d_in[19];
    const float* fco_PA = (const float*)d_in[20];
    const float* fco_Wa = (const float*)d_in[21];
    const float* fco_ba = (const float*)d_in[22];
    const float* fco_Wb = (const float*)d_in[23];
    const float* fco_bb = (const float*)d_in[24];
    const float* fco_Wd = (const float*)d_in[25];
    const float* fco_bd = (const float*)d_in[26];
    const float* fco_gamma = (const float*)d_in[27];
    const float* fco_beta = (const float*)d_in[28];

    // Workspace map (round-8):
    //   [0, 32.768 MB)      Xbf (bf16 transposed K, written by gcn_S3) — later
    //                       overwritten IN PLACE by apply3 #2 as Vg (each block
    //                       stages its rows before writing the same rows).
    //   [32.768, 65.536)    Kg
    //   [65.536, 91.750)    Mpart (S3→reduce), then O (attn→...) — disjoint lifetimes
    //   [91.750 ..]         S1, S2, S3
    char* wsb = (char*)d_ws;
    bf16* Xbf = (bf16*)(wsb);
    bf16* Vg = (bf16*)(wsb);                     // in-place over Xbf
    bf16* Kg = (bf16*)(wsb + 32768000);
    float* Mpart = (float*)(wsb + 65536000);     // [5][256][6][625] fp32 = 19.2 MB
    float* O = (float*)(wsb + 65536000);         // 26.2 MB, live after reduce
    float* S1 = (float*)(wsb + 91750400);
    float* S2 = (float*)(wsb + 93670400);
    float* S3 = (float*)(wsb + 95590400);

    gcn_S3<<<dim3(BB * 5), dim3(256), 0, stream>>>(
        K, fck_Wa, fck_ba, fck_Wb, fck_bb,
        fcv_Wa, fcv_ba, fcv_Wb, fcv_bb, Xbf, Mpart);

    reduce_softmax<<<dim3(BB, 6), dim3(128), 0, stream>>>(
        Mpart, fck_PA, fcv_PA, S1, S2);

    gcn_apply3<V1, 4, 0><<<dim3(BB, 10), dim3(256), 0, stream>>>(
        nullptr, Xbf, S1, fck_Wd, fck_bd, fck_gamma, fck_beta, Kg, nullptr, nullptr);
    gcn_apply3<V1, 4, 0><<<dim3(BB, 10), dim3(256), 0, stream>>>(
        nullptr, Xbf, S2, fcv_Wd, fcv_bd, fcv_gamma, fcv_beta, Vg, nullptr, nullptr);

    attn_kernel<<<dim3(BB, NH), dim3(256), 0, stream>>>(Q, Kg, Vg, O);

    gcn_S2<V2, 1><<<dim3(BB, 3), dim3(256), 0, stream>>>(
        O, fco_Wa, fco_ba, fco_Wb, fco_bb, fco_PA, S3,
        nullptr, nullptr, nullptr, nullptr, nullptr, nullptr);

    gcn_apply3<V2, 8, 1><<<dim3(BB, 5), dim3(256), 0, stream>>>(
        O, nullptr, S3, fco_Wd, fco_bd, fco_gamma, fco_beta, nullptr, (float*)d_out, O);
}

// Round 2
// 573.775 us; speedup vs baseline: 1.2657x; 1.1436x over previous
//
#include <hip/hip_runtime.h>
#include <hip/hip_bf16.h>

#define BB 256
#define CC 64
#define TT 40
#define DD 2560   // CC*TT
#define V1 25
#define V2 10
#define INTER 16
#define NH 8
#define DSH 320   // DD/NH

typedef __hip_bfloat16 bf16;
typedef unsigned int uint;
typedef unsigned short ushort;
typedef __attribute__((ext_vector_type(8))) short bf16x8;
typedef __attribute__((ext_vector_type(4))) float f32x4;

__device__ __forceinline__ float b2f(bf16 x) { return __bfloat162float(x); }

__device__ __forceinline__ ushort f2bb(float f) {
    uint x = __float_as_uint(f);
    uint r = x + 0x7fffu + ((x >> 16) & 1u);
    return (ushort)(r >> 16);
}
__device__ __forceinline__ float blo(uint u) { return __uint_as_float(u << 16); }
__device__ __forceinline__ float bhi(uint u) { return __uint_as_float(u & 0xffff0000u); }
__device__ __forceinline__ float b2f_us(ushort h) { return __uint_as_float(((uint)h) << 16); }
__device__ __forceinline__ uint4 pack8(const float* a) {
    uint4 pk;
    pk.x = (uint)f2bb(a[0]) | ((uint)f2bb(a[1]) << 16);
    pk.y = (uint)f2bb(a[2]) | ((uint)f2bb(a[3]) << 16);
    pk.z = (uint)f2bb(a[4]) | ((uint)f2bb(a[5]) << 16);
    pk.w = (uint)f2bb(a[6]) | ((uint)f2bb(a[7]) << 16);
    return pk;
}
__device__ __forceinline__ bf16x8 ldfrag8(const ushort* p) {
    union { bf16x8 v; uint2 u[2]; } t;
    t.u[0] = *(const uint2*)p;
    t.u[1] = *(const uint2*)(p + 4);
    return t.v;
}

// LDS swizzle helpers (ushort index). 64-ushort (128B) rows, 16B-granule XOR
// by low row bits -> every vectorized access pattern hits its bank floor.
__device__ __forceinline__ int swz64(int row, int col) {
    return row * 64 + ((((col >> 3) ^ row) & 7) << 3) + (col & 7);
}
// xsC: 128-ushort (256B) rows, granule XOR by (c&15)
__device__ __forceinline__ int swzC(int c, int col) {
    return c * 128 + ((((col >> 3) ^ c) & 15) << 3) + (col & 7);
}

// ---------------------------------------------------------------------------
// gcn_S3 (V=25, fck+fcv fused): grid = (tc*256 + b), 1280 blocks.
// Per block: stage x chunk (8 t's of all v,c) once; EXPORT it as bf16 in
// transposed layout Xbf[((b*25+v)*40+t)*64+c] (coalesced, read by applyKV);
// then for each subset s: proj MFMA + Gram MFMA -> Mpart.
// ---------------------------------------------------------------------------
__global__ __launch_bounds__(256) void gcn_S3(
    const float* __restrict__ X,
    const float* __restrict__ Wa0, const float* __restrict__ ba0,
    const float* __restrict__ Wb0, const float* __restrict__ bb0,
    const float* __restrict__ Wa1, const float* __restrict__ ba1,
    const float* __restrict__ Wb1, const float* __restrict__ bb1,
    bf16* __restrict__ Xw, float* __restrict__ Mpart) {
    __shared__ ushort xsT[208][72];    // [p=v*8+tl][c]; rows 200..207 garbage
    __shared__ ushort wT[64][72];      // [mat*16+j][c] for current s
    __shared__ ushort abT[4][32][136]; // [mat][v][j*8+tl]
    __shared__ float biasS[64];

    const int tid = threadIdx.x;
    const int b = blockIdx.x & 255, tc = blockIdx.x >> 8;
    const int t0 = tc * 8;
    const int lane = tid & 63, w = tid >> 6;
    const int ln = lane & 15, lq = lane >> 4;

    // stage x chunk: (v,c) -> 8 t's, bf16 into transposed rows p=v*8+tl
    const float* Xb = X + (size_t)b * V1 * DD;
    for (int e = tid; e < V1 * 64; e += 256) {
        const int v = e >> 6, c = e & 63;
        const float* src = Xb + (size_t)v * DD + c * TT + t0;
        const float4 f0 = *(const float4*)src;
        const float4 f1 = *(const float4*)(src + 4);
        const float tmp[8] = {f0.x, f0.y, f0.z, f0.w, f1.x, f1.y, f1.z, f1.w};
        #pragma unroll
        for (int tl = 0; tl < 8; ++tl) xsT[v * 8 + tl][c] = f2bb(tmp[tl]);
    }
    __syncthreads();                   // xsT complete

    // export bf16 transposed X: Xw[((b*25+v)*40 + t0+tl)*64 + c], uint4 rows
    for (int e = tid; e < 1600; e += 256) {
        const int p = e >> 3, c8 = e & 7;
        const int v = p >> 3, tl = p & 7;
        *(uint4*)(Xw + (((size_t)b * V1 + v) * TT + t0 + tl) * 64 + c8 * 8) =
            *(const uint4*)&xsT[p][c8 * 8];
    }

    for (int s = 0; s < 3; ++s) {
        if (s) __syncthreads();        // prev Gram done with abT, proj done with wT
        // stage W (4 mats x 16 x 64) + bias for this s
        for (int e = tid; e < 4096; e += 256) {
            const int mat = e >> 10, r = e & 1023;
            const float* Wp = (mat == 0) ? Wa0 : (mat == 1) ? Wb0 : (mat == 2) ? Wa1 : Wb1;
            wT[(mat << 4) + (r >> 6)][r & 63] = f2bb(Wp[s * 1024 + r]);
        }
        if (tid < 64) {
            const int mat = tid >> 4, j = tid & 15;
            const float* bp = (mat == 0) ? ba0 : (mat == 1) ? bb0 : (mat == 2) ? ba1 : bb1;
            biasS[tid] = bp[s * 16 + j];
        }
        __syncthreads();               // wT/xsT ready

        // ---- projection: wave w computes mat w over 13 n-tiles ----
        const bf16x8 a0 = *(const bf16x8*)&wT[w * 16 + ln][lq * 8];
        const bf16x8 a1 = *(const bf16x8*)&wT[w * 16 + ln][lq * 8 + 32];
        float br[4];
        #pragma unroll
        for (int r = 0; r < 4; ++r) br[r] = biasS[w * 16 + lq * 4 + r];
        for (int nt = 0; nt < 13; ++nt) {
            const bf16x8 b0 = *(const bf16x8*)&xsT[nt * 16 + ln][lq * 8];
            const bf16x8 b1 = *(const bf16x8*)&xsT[nt * 16 + ln][lq * 8 + 32];
            f32x4 acc = (f32x4){0.f, 0.f, 0.f, 0.f};
            acc = __builtin_amdgcn_mfma_f32_16x16x32_bf16(a0, b0, acc, 0, 0, 0);
            acc = __builtin_amdgcn_mfma_f32_16x16x32_bf16(a1, b1, acc, 0, 0, 0);
            const int p = nt * 16 + ln;
            if (p < 200) {
                const int v = p >> 3, tl = p & 7;
                #pragma unroll
                for (int r = 0; r < 4; ++r)
                    abT[w][v][(lq * 4 + r) * 8 + tl] = f2bb(acc[r] + br[r]);
            }
        }
        __syncthreads();               // abT ready

        // ---- Gram: 8 tile-units (np,mt,nt), wave w does units w and w+4 ----
        #pragma unroll
        for (int uu = 0; uu < 2; ++uu) {
            const int u = w + uu * 4;
            const int np = u >> 2, mt = (u >> 1) & 1, ntl = u & 1;
            const ushort* Ap = &abT[np * 2 + 0][mt * 16 + ln][lq * 8];
            const ushort* Bp = &abT[np * 2 + 1][ntl * 16 + ln][lq * 8];
            f32x4 g = (f32x4){0.f, 0.f, 0.f, 0.f};
            g = __builtin_amdgcn_mfma_f32_16x16x32_bf16(
                    *(const bf16x8*)Ap, *(const bf16x8*)Bp, g, 0, 0, 0);
            g = __builtin_amdgcn_mfma_f32_16x16x32_bf16(
                    *(const bf16x8*)(Ap + 32), *(const bf16x8*)(Bp + 32), g, 0, 0, 0);
            g = __builtin_amdgcn_mfma_f32_16x16x32_bf16(
                    *(const bf16x8*)(Ap + 64), *(const bf16x8*)(Bp + 64), g, 0, 0, 0);
            g = __builtin_amdgcn_mfma_f32_16x16x32_bf16(
                    *(const bf16x8*)(Ap + 96), *(const bf16x8*)(Bp + 96), g, 0, 0, 0);
            const int vp = ntl * 16 + ln;
            if (vp < V1) {
                float* Mb = Mpart + (((size_t)tc * 256 + b) * 6 + (s * 2 + np)) * 625;
                #pragma unroll
                for (int r = 0; r < 4; ++r) {
                    const int v = mt * 16 + lq * 4 + r;
                    if (v < V1) Mb[v * V1 + vp] = g[r];
                }
            }
        }
    }
}

// ---------------------------------------------------------------------------
// reduce_softmax: grid (b, snp=s*2+np). Sum 5 chunk-partials, column softmax
// over v (axis=-2), + PA, write S (B,3,25,25).
// ---------------------------------------------------------------------------
__global__ __launch_bounds__(128) void reduce_softmax(
    const float* __restrict__ Mpart,
    const float* __restrict__ PA0, const float* __restrict__ PA1,
    float* __restrict__ S1out, float* __restrict__ S2out) {
    __shared__ float Ms[625];
    const int tid = threadIdx.x, b = blockIdx.x, snp = blockIdx.y;
    const int s = snp >> 1, np = snp & 1;
    for (int e = tid; e < 625; e += 128) {
        float sum = 0.f;
        #pragma unroll
        for (int tcc = 0; tcc < 5; ++tcc)
            sum += Mpart[(((size_t)tcc * 256 + b) * 6 + snp) * 625 + e];
        Ms[e] = sum;
    }
    __syncthreads();
    if (tid < V1) {
        const int vp = tid;
        const float invIT = 1.0f / 640.0f;
        float mx = -1e30f;
        for (int v = 0; v < V1; ++v) mx = fmaxf(mx, Ms[v * V1 + vp]);
        float sum = 0.f;
        for (int v = 0; v < V1; ++v) sum += expf((Ms[v * V1 + vp] - mx) * invIT);
        const float rs = 1.f / sum;
        const float* PAn = np ? PA1 : PA0;
        float* Sn = np ? S2out : S1out;
        for (int v = 0; v < V1; ++v) {
            const float e_ = expf((Ms[v * V1 + vp] - mx) * invIT);
            Sn[((size_t)(b * 3 + s) * V1 + v) * V1 + vp] =
                e_ * rs + PAn[(s * V1 + v) * V1 + vp];
        }
    }
}

// ---------------------------------------------------------------------------
// gcn_S2 (VALU version, kept for the small V=10 fco case).
// ---------------------------------------------------------------------------
template<int V, int NP>
__global__ __launch_bounds__(256) void gcn_S2(
    const float* __restrict__ X,
    const float* __restrict__ Wa0, const float* __restrict__ ba0,
    const float* __restrict__ Wb0, const float* __restrict__ bb0,
    const float* __restrict__ PA0, float* __restrict__ Sout0,
    const float* __restrict__ Wa1, const float* __restrict__ ba1,
    const float* __restrict__ Wb1, const float* __restrict__ bb1,
    const float* __restrict__ PA1, float* __restrict__ Sout1) {
    constexpr int TC = 8;
    constexpr int NCH = TT / TC;
    constexpr int P = V * TC;
    constexpr int ROWS = NP * 32;
    constexpr int NRQ = ROWS / 4;
    constexpr int NC8 = P / 8;
    constexpr int NTILE = NRQ * NC8;
    constexpr int NM = NP * V * V;
    constexpr int NMI = (NM + 255) / 256;

    __shared__ ushort xs[64][P];
    __shared__ ushort ab[ROWS][P];
    __shared__ ushort wT[64][ROWS];
    __shared__ float biasL[ROWS];
    __shared__ float M[NM];

    const int tid = threadIdx.x, b = blockIdx.x, s = blockIdx.y;

    for (int e = tid; e < 16 * 64; e += 256) {
        int c = e & 63;
        int j = e >> 6;
        wT[c][j]      = f2bb(Wa0[s * 1024 + e]);
        wT[c][16 + j] = f2bb(Wb0[s * 1024 + e]);
        if constexpr (NP == 2) {
            wT[c][32 + j] = f2bb(Wa1[s * 1024 + e]);
            wT[c][48 + j] = f2bb(Wb1[s * 1024 + e]);
        }
    }
    if (tid < 16) {
        biasL[tid]      = ba0[s * 16 + tid];
        biasL[16 + tid] = bb0[s * 16 + tid];
        if constexpr (NP == 2) {
            biasL[32 + tid] = ba1[s * 16 + tid];
            biasL[48 + tid] = bb1[s * 16 + tid];
        }
    }

    float macc[NMI];
    #pragma unroll
    for (int k = 0; k < NMI; ++k) macc[k] = 0.f;

    const float* Xb = X + (size_t)b * V * DD;
    for (int tc = 0; tc < NCH; ++tc) {
        const int t0 = tc * TC;
        for (int e = tid; e < V * 64; e += 256) {
            const int v = e >> 6, c = e & 63;
            const float* src = Xb + (size_t)v * DD + c * TT + t0;
            const float4 f0 = *(const float4*)src;
            const float4 f1 = *(const float4*)(src + 4);
            const float tmp[8] = {f0.x, f0.y, f0.z, f0.w, f1.x, f1.y, f1.z, f1.w};
            *(uint4*)&xs[c][v * 8] = pack8(tmp);
        }
        __syncthreads();
        for (int tau = tid; tau < NTILE; tau += 256) {
            const int rq = tau % NRQ, co = tau / NRQ;
            float acc[4][8];
            #pragma unroll
            for (int r = 0; r < 4; ++r) {
                const float bv = biasL[4 * rq + r];
                #pragma unroll
                for (int cc = 0; cc < 8; ++cc) acc[r][cc] = bv;
            }
            for (int c = 0; c < 64; ++c) {
                const uint2 wv = *(const uint2*)&wT[c][4 * rq];
                const uint4 xv = *(const uint4*)&xs[c][8 * co];
                const float w0 = blo(wv.x), w1 = bhi(wv.x);
                const float w2 = blo(wv.y), w3 = bhi(wv.y);
                const float x0 = blo(xv.x), x1 = bhi(xv.x);
                const float x2 = blo(xv.y), x3 = bhi(xv.y);
                const float x4 = blo(xv.z), x5 = bhi(xv.z);
                const float x6 = blo(xv.w), x7 = bhi(xv.w);
                acc[0][0] += w0 * x0; acc[0][1] += w0 * x1;
                acc[0][2] += w0 * x2; acc[0][3] += w0 * x3;
                acc[0][4] += w0 * x4; acc[0][5] += w0 * x5;
                acc[0][6] += w0 * x6; acc[0][7] += w0 * x7;
                acc[1][0] += w1 * x0; acc[1][1] += w1 * x1;
                acc[1][2] += w1 * x2; acc[1][3] += w1 * x3;
                acc[1][4] += w1 * x4; acc[1][5] += w1 * x5;
                acc[1][6] += w1 * x6; acc[1][7] += w1 * x7;
                acc[2][0] += w2 * x0; acc[2][1] += w2 * x1;
                acc[2][2] += w2 * x2; acc[2][3] += w2 * x3;
                acc[2][4] += w2 * x4; acc[2][5] += w2 * x5;
                acc[2][6] += w2 * x6; acc[2][7] += w2 * x7;
                acc[3][0] += w3 * x0; acc[3][1] += w3 * x1;
                acc[3][2] += w3 * x2; acc[3][3] += w3 * x3;
                acc[3][4] += w3 * x4; acc[3][5] += w3 * x5;
                acc[3][6] += w3 * x6; acc[3][7] += w3 * x7;
            }
            #pragma unroll
            for (int r = 0; r < 4; ++r)
                *(uint4*)&ab[4 * rq + r][8 * co] = pack8(acc[r]);
        }
        __syncthreads();
        #pragma unroll
        for (int k = 0; k < NMI; ++k) {
            const int idx = tid + k * 256;
            if (idx < NM) {
                const int np = idx / (V * V), r = idx % (V * V);
                const int v = r / V, vp = r % V;
                const int ra = np * 32, rb = np * 32 + 16;
                float mm = 0.f;
                #pragma unroll
                for (int j = 0; j < 16; ++j) {
                    const uint4 av = *(const uint4*)&ab[ra + j][v * 8];
                    const uint4 bv = *(const uint4*)&ab[rb + j][vp * 8];
                    mm += blo(av.x) * blo(bv.x) + bhi(av.x) * bhi(bv.x)
                        + blo(av.y) * blo(bv.y) + bhi(av.y) * bhi(bv.y)
                        + blo(av.z) * blo(bv.z) + bhi(av.z) * bhi(bv.z)
                        + blo(av.w) * blo(bv.w) + bhi(av.w) * bhi(bv.w);
                }
                macc[k] += mm;
            }
        }
    }

    #pragma unroll
    for (int k = 0; k < NMI; ++k) {
        const int idx = tid + k * 256;
        if (idx < NM) M[idx] = macc[k];
    }
    __syncthreads();

    const float invIT = 1.0f / 640.0f;
    if (tid < NP * V) {
        const int np = tid / V, vp = tid % V;
        const float* Mn = &M[np * V * V];
        float mx = -1e30f;
        for (int v = 0; v < V; ++v) mx = fmaxf(mx, Mn[v * V + vp]);
        float sum = 0.f;
        for (int v = 0; v < V; ++v) sum += expf((Mn[v * V + vp] - mx) * invIT);
        const float rs = 1.f / sum;
        const float* PAn = (np == 0) ? PA0 : PA1;
        float* Sn = (np == 0) ? Sout0 : Sout1;
        for (int v = 0; v < V; ++v) {
            const float e_ = expf((Mn[v * V + vp] - mx) * invIT);
            Sn[((size_t)(b * 3 + s) * V + v) * V + vp] =
                e_ * rs + PAn[(s * V + v) * V + vp];
        }
    }
}

// ---------------------------------------------------------------------------
// gcn_applyKV: fused fck+fcv apply for V=25, all-MFMA.
//   GEMM-1 (z = X·S, K=25 padded to 32) via mfma: A = X^T (xsC, v0-contig),
//   B = S^T (SlT[v][v0], zero-padded). GEMM-2 (Wd·z) as before.
//   One block stages X once (xsT + LDS-transpose to xsC), runs both gcns.
// All hot LDS arrays use 128B rows + 16B-granule XOR swizzle (bank floors).
// MFMA recipe (proven by GEMM-2): A-frag = Arows[m][k-contig 8 @ lq*8],
//   B-frag = Brows[n][k-contig 8 @ lq*8], D: row=lq*4+r -> m, col=ln -> n.
// ---------------------------------------------------------------------------
__global__ __launch_bounds__(256) void gcn_applyKV(
    const bf16* __restrict__ Xbf,
    const float* __restrict__ S1, const float* __restrict__ S2,
    const float* __restrict__ WdK, const float* __restrict__ bdK,
    const float* __restrict__ gK, const float* __restrict__ beK,
    const float* __restrict__ WdV, const float* __restrict__ bdV,
    const float* __restrict__ gV, const float* __restrict__ beV,
    bf16* __restrict__ Kg, bf16* __restrict__ Vg) {

    __shared__ ushort xsT[100 * 64];       // [p=v*4+tl][c], swz64
    __shared__ ushort xsC[64 * 128];       // [c][tl*32+v0], swzC (v0 pad=0)
    __shared__ ushort zsT[112 * 64];       // [p][c], swz64; rows 100..111 = 0
    __shared__ ushort wdT[64 * 64];        // [o][c], swz64
    __shared__ ushort SlT[2][3][32][40];   // [g][s][v][v0], zero-padded
    __shared__ float bds[2][64], scl[2][64], bet[2][64];

    const int tid = threadIdx.x, b = blockIdx.x, chunk = blockIdx.y;
    const int lane = tid & 63, w = tid >> 6;
    const int ln = lane & 15, lq = lane >> 4;
    const int t0 = chunk * 4;

    // --- init: zero SlT (pads MUST be 0) + zsT tail rows; stage xsT ---
    for (int e = tid; e < 3840; e += 256) ((uint*)SlT)[e] = 0u;
    for (int e = tid; e < 384; e += 256) ((uint*)&zsT[100 * 64])[e] = 0u;
    if (tid < 64) {
        bds[0][tid] = bdK[tid] + bdK[64 + tid] + bdK[128 + tid];
        bds[1][tid] = bdV[tid] + bdV[64 + tid] + bdV[128 + tid];
        scl[0][tid] = gK[tid] * rsqrtf(1.f + 1e-5f);
        scl[1][tid] = gV[tid] * rsqrtf(1.f + 1e-5f);
        bet[0][tid] = beK[tid];
        bet[1][tid] = beV[tid];
    }
    const bf16* Xb = Xbf + (size_t)b * V1 * DD;
    for (int e = tid; e < 800; e += 256) {
        const int p = e >> 3, c8 = e & 7;
        const int v = p >> 2, tl = p & 3;
        const uint4 u = *(const uint4*)(Xb + ((size_t)v * TT + t0 + tl) * 64 + c8 * 8);
        *(uint4*)&xsT[swz64(p, c8 * 8)] = u;
    }
    __syncthreads();   // SlT zeroed + xsT staged

    // --- fill SlT[g][s][vp][v0] = S[s][v0][vp] (bf16) ---
    for (int e = tid; e < 3750; e += 256) {
        const int g = e / 1875, r = e - g * 1875;
        const int s = r / 625, rr = r % 625;
        const int vp = rr % 25;
        const float* Sp = g ? S2 : S1;
        SlT[g][s][vp][rr / 25] = f2bb(Sp[((size_t)b * 3 + s) * 625 + rr]);
    }
    // --- LDS transpose xsT -> xsC[c][tl*32+v0], zero-pad v0 >= 25 ---
    {
        const int c = tid & 63, q = tid >> 6;   // q = v0-octet
        #pragma unroll
        for (int j = 0; j < 4; ++j) {           // j = tl
            ushort vals[8];
            #pragma unroll
            for (int i = 0; i < 8; ++i) {
                const int v0 = q * 8 + i;
                vals[i] = (v0 < V1) ? xsT[swz64(v0 * 4 + j, c)] : (ushort)0;
            }
            uint4 pk;
            pk.x = (uint)vals[0] | ((uint)vals[1] << 16);
            pk.y = (uint)vals[2] | ((uint)vals[3] << 16);
            pk.z = (uint)vals[4] | ((uint)vals[5] << 16);
            pk.w = (uint)vals[6] | ((uint)vals[7] << 16);
            *(uint4*)&xsC[swzC(c, j * 32 + q * 8)] = pk;
        }
    }
    __syncthreads();   // xsC + SlT ready

    // A-frags for GEMM-1 (stable for whole kernel): wave w = c-tile
    bf16x8 aF[4];
    #pragma unroll
    for (int tl = 0; tl < 4; ++tl)
        aF[tl] = *(const bf16x8*)&xsC[swzC(w * 16 + ln, tl * 32 + lq * 8)];

    for (int g = 0; g < 2; ++g) {
        const float* Wd = g ? WdV : WdK;
        f32x4 acc[7];
        #pragma unroll
        for (int tn = 0; tn < 7; ++tn) acc[tn] = (f32x4){0.f, 0.f, 0.f, 0.f};

        for (int s = 0; s < 3; ++s) {
            if (g | s) __syncthreads();   // prior GEMM-2 / out-write done with wdT,zsT
            // stage wdT for (g,s)
            for (int e = tid; e < 4096; e += 256)
                wdT[swz64(e >> 6, e & 63)] = f2bb(Wd[s * 4096 + e]);

            // ---- GEMM-1 (MFMA): D[c][v] = sum_v0 X^T[c][v0] * S[v0][v] ----
            #pragma unroll
            for (int nt = 0; nt < 2; ++nt) {
                const bf16x8 bF = *(const bf16x8*)&SlT[g][s][nt * 16 + ln][lq * 8];
                const int v = nt * 16 + ln;
                #pragma unroll
                for (int tl = 0; tl < 4; ++tl) {
                    f32x4 d = (f32x4){0.f, 0.f, 0.f, 0.f};
                    d = __builtin_amdgcn_mfma_f32_16x16x32_bf16(aF[tl], bF, d, 0, 0, 0);
                    if (v < V1) {
                        uint2 pk;
                        pk.x = (uint)f2bb(d[0]) | ((uint)f2bb(d[1]) << 16);
                        pk.y = (uint)f2bb(d[2]) | ((uint)f2bb(d[3]) << 16);
                        *(uint2*)&zsT[swz64(v * 4 + tl, w * 16 + lq * 4)] = pk;
                    }
                }
            }
            __syncthreads();   // zsT + wdT ready

            // ---- GEMM-2 (MFMA): acc[o][p] += Wd[o][c] * z[p][c] ----
            const bf16x8 a0 = *(const bf16x8*)&wdT[swz64(w * 16 + ln, lq * 8)];
            const bf16x8 a1 = *(const bf16x8*)&wdT[swz64(w * 16 + ln, lq * 8 + 32)];
            #pragma unroll
            for (int tn = 0; tn < 7; ++tn) {
                const bf16x8 b0 = *(const bf16x8*)&zsT[swz64(tn * 16 + ln, lq * 8)];
                const bf16x8 b1 = *(const bf16x8*)&zsT[swz64(tn * 16 + ln, lq * 8 + 32)];
                acc[tn] = __builtin_amdgcn_mfma_f32_16x16x32_bf16(a0, b0, acc[tn], 0, 0, 0);
                acc[tn] = __builtin_amdgcn_mfma_f32_16x16x32_bf16(a1, b1, acc[tn], 0, 0, 0);
            }
        }
        __syncthreads();   // GEMM-2 done reading zsT

        // ---- epilogue: BN + residual + relu -> zsT (bf16) ----
        {
            const int c0 = w * 16 + lq * 4;
            float bb[4], ss[4], be[4];
            #pragma unroll
            for (int r = 0; r < 4; ++r) {
                bb[r] = bds[g][c0 + r]; ss[r] = scl[g][c0 + r]; be[r] = bet[g][c0 + r];
            }
            #pragma unroll
            for (int tn = 0; tn < 7; ++tn) {
                const int p = tn * 16 + ln;
                if (p < 100) {
                    const uint2 u = *(const uint2*)&xsT[swz64(p, c0)];
                    const float rs[4] = {blo(u.x), bhi(u.x), blo(u.y), bhi(u.y)};
                    float y[4];
                    #pragma unroll
                    for (int r = 0; r < 4; ++r)
                        y[r] = fmaxf((acc[tn][r] + bb[r]) * ss[r] + be[r] + rs[r], 0.f);
                    uint2 pk;
                    pk.x = (uint)f2bb(y[0]) | ((uint)f2bb(y[1]) << 16);
                    pk.y = (uint)f2bb(y[2]) | ((uint)f2bb(y[3]) << 16);
                    *(uint2*)&zsT[swz64(p, c0)] = pk;
                }
            }
        }
        __syncthreads();

        // ---- coalesced bf16 output, [b][v][t][c] layout ----
        bf16* outp = (g ? Vg : Kg) + (size_t)b * V1 * DD;
        for (int e = tid; e < 800; e += 256) {
            const int p = e >> 3, c8 = e & 7;
            const int v = p >> 2, tl = p & 3;
            *(uint4*)(outp + ((size_t)v * TT + t0 + tl) * 64 + c8 * 8) =
                *(const uint4*)&zsT[swz64(p, c8 * 8)];
        }
    }
}

// ---------------------------------------------------------------------------
// gcn_apply3 (old template, kept ONLY for the V=10 fco case, MODE 1).
// ---------------------------------------------------------------------------
template<int V, int TC, int MODE>
__global__ __launch_bounds__(256) void gcn_apply3(const float* __restrict__ X,
                                                  const bf16* __restrict__ Xbf,
                                                  const float* __restrict__ Sbuf,
                                                  const float* __restrict__ Wd,
                                                  const float* __restrict__ bd,
                                                  const float* __restrict__ gamma,
                                                  const float* __restrict__ beta,
                                                  bf16* __restrict__ out_bf,
                                                  float* __restrict__ out_f,
                                                  const float* __restrict__ Obuf) {
    constexpr int VSLOT = 128 / TC;
    constexpr int ROWS = V * TC;
    constexpr int NT = (V == 25) ? 7 : 5;

    __shared__ ushort xsT[ROWS][72];
    __shared__ ushort zsT[128][72];
    __shared__ ushort wdT[64][72];
    __shared__ ushort Sl[3][VSLOT][34];
    __shared__ float bds[64], scl[64], bet[64];

    const int tid = threadIdx.x, b = blockIdx.x, chunk = blockIdx.y;
    const int ci = tid >> 4, pj = tid & 15;
    const int lane = tid & 63, w = tid >> 6;
    const int ln = lane & 15, lq = lane >> 4;
    const int t0 = chunk * TC;

    for (int e = tid; e < 3 * VSLOT * 17; e += 256) ((uint*)Sl)[e] = 0u;
    if (tid < 64) {
        bds[tid] = bd[tid] + bd[64 + tid] + bd[128 + tid];
        scl[tid] = gamma[tid] * rsqrtf(1.f + 1e-5f);
        bet[tid] = beta[tid];
    }
    __syncthreads();
    for (int e = tid; e < 3 * V * V; e += 256) {
        int s = e / (V * V), r = e % (V * V);
        Sl[s][r / V][r % V] = f2bb(Sbuf[(size_t)b * 3 * V * V + e]);
    }
    if constexpr (MODE == 0) {
        for (int e = tid; e < ROWS * 8; e += 256) {
            const int p = e >> 3, c8 = e & 7;
            const int v = p / TC, tl = p % TC;
            *(uint4*)&xsT[p][c8 * 8] =
                *(const uint4*)(Xbf + (((size_t)b * V + v) * TT + t0 + tl) * 64 + c8 * 8);
        }
    } else {
        const float* Xb = X + (size_t)b * V * DD;
        for (int e = tid; e < V * 64 * TC; e += 256) {
            int v = e / (64 * TC), inner = e % (64 * TC);
            int c = inner / TC, tl = inner % TC;
            xsT[v * TC + tl][c] = f2bb(Xb[(size_t)v * DD + c * TT + t0 + tl]);
        }
    }
    __syncthreads();

    f32x4 acc[NT];
    #pragma unroll
    for (int tn = 0; tn < NT; ++tn) acc[tn] = (f32x4){0.f, 0.f, 0.f, 0.f};

    for (int s = 0; s < 3; ++s) {
        if (s) __syncthreads();
        for (int e = tid; e < 4096; e += 256)
            wdT[e >> 6][e & 63] = f2bb(Wd[s * 4096 + e]);

        float za[4][8];
        #pragma unroll
        for (int r = 0; r < 4; ++r)
            #pragma unroll
            for (int cc = 0; cc < 8; ++cc) za[r][cc] = 0.f;

        if constexpr (V == 25) {
            for (int v0 = 0; v0 < 25; ++v0) {
                const uint sv = *(const uint*)&Sl[s][v0][2 * pj];
                const float svx = blo(sv), svy = bhi(sv);
                #pragma unroll
                for (int tl = 0; tl < 4; ++tl) {
                    const uint2 u = *(const uint2*)&xsT[v0 * 4 + tl][ci * 4];
                    const float a0 = blo(u.x), a1 = bhi(u.x);
                    const float a2 = blo(u.y), a3 = bhi(u.y);
                    za[0][tl] += a0 * svx;  za[0][4 + tl] += a0 * svy;
                    za[1][tl] += a1 * svx;  za[1][4 + tl] += a1 * svy;
                    za[2][tl] += a2 * svx;  za[2][4 + tl] += a2 * svy;
                    za[3][tl] += a3 * svx;  za[3][4 + tl] += a3 * svy;
                }
            }
        } else {
            for (int v0 = 0; v0 < 10; ++v0) {
                const float sv = b2f_us(Sl[s][v0][pj]);
                #pragma unroll
                for (int tl = 0; tl < 8; ++tl) {
                    const uint2 u = *(const uint2*)&xsT[v0 * 8 + tl][ci * 4];
                    za[0][tl] += blo(u.x) * sv;
                    za[1][tl] += bhi(u.x) * sv;
                    za[2][tl] += blo(u.y) * sv;
                    za[3][tl] += bhi(u.y) * sv;
                }
            }
        }
        #pragma unroll
        for (int cc = 0; cc < 8; ++cc) {
            uint2 pk;
            pk.x = (uint)f2bb(za[0][cc]) | ((uint)f2bb(za[1][cc]) << 16);
            pk.y = (uint)f2bb(za[2][cc]) | ((uint)f2bb(za[3][cc]) << 16);
            *(uint2*)&zsT[pj * 8 + cc][ci * 4] = pk;
        }
        __syncthreads();

        const bf16x8 a0 = *(const bf16x8*)&wdT[w * 16 + ln][lq * 8];
        const bf16x8 a1 = *(const bf16x8*)&wdT[w * 16 + ln][lq * 8 + 32];
        #pragma unroll
        for (int tn = 0; tn < NT; ++tn) {
            const bf16x8 b0 = ldfrag8(&zsT[tn * 16 + ln][lq * 8]);
            const bf16x8 b1 = ldfrag8(&zsT[tn * 16 + ln][lq * 8 + 32]);
            acc[tn] = __builtin_amdgcn_mfma_f32_16x16x32_bf16(a0, b0, acc[tn], 0, 0, 0);
            acc[tn] = __builtin_amdgcn_mfma_f32_16x16x32_bf16(a1, b1, acc[tn], 0, 0, 0);
        }
    }

    __syncthreads();
    {
        const int c0 = w * 16 + lq * 4;
        float bb[4], ss[4], be[4];
        #pragma unroll
        for (int r = 0; r < 4; ++r) {
            bb[r] = bds[c0 + r]; ss[r] = scl[c0 + r]; be[r] = bet[c0 + r];
        }
        #pragma unroll
        for (int tn = 0; tn < NT; ++tn) {
            const int p = tn * 16 + ln;
            if (p < ROWS) {
                const uint2 u = *(const uint2*)&xsT[p][c0];
                const float rs[4] = {blo(u.x), bhi(u.x), blo(u.y), bhi(u.y)};
                float y[4];
                #pragma unroll
                for (int r = 0; r < 4; ++r)
                    y[r] = fmaxf((acc[tn][r] + bb[r]) * ss[r] + be[r] + rs[r], 0.f);
                uint2 pk;
                pk.x = (uint)f2bb(y[0]) | ((uint)f2bb(y[1]) << 16);
                pk.y = (uint)f2bb(y[2]) | ((uint)f2bb(y[3]) << 16);
                *(uint2*)&zsT[p][c0] = pk;
            }
        }
    }
    __syncthreads();

    if constexpr (MODE == 0) {
        for (int e = tid; e < ROWS * 8; e += 256) {
            const int p = e >> 3, c8 = e & 7;
            const int v = p / TC, tl = p % TC;
            *(uint4*)(out_bf + (((size_t)b * V + v) * TT + t0 + tl) * 64 + c8 * 8) =
                *(const uint4*)&zsT[p][c8 * 8];
        }
    } else {
        const int v = pj;
        if (v < V) {
            #pragma unroll
            for (int r = 0; r < 4; ++r) {
                const int c = ci * 4 + r;
                const size_t base = (size_t)b * V * DD + (size_t)v * DD + c * TT + t0;
                const float4 o0 = *(const float4*)&Obuf[base];
                const float4 o1 = *(const float4*)&Obuf[base + 4];
                float4 y0, y1;
                y0.x = o0.x + b2f_us(zsT[v * 8 + 0][c]);
                y0.y = o0.y + b2f_us(zsT[v * 8 + 1][c]);
                y0.z = o0.z + b2f_us(zsT[v * 8 + 2][c]);
                y0.w = o0.w + b2f_us(zsT[v * 8 + 3][c]);
                y1.x = o1.x + b2f_us(zsT[v * 8 + 4][c]);
                y1.y = o1.y + b2f_us(zsT[v * 8 + 5][c]);
                y1.z = o1.z + b2f_us(zsT[v * 8 + 6][c]);
                y1.w = o1.w + b2f_us(zsT[v * 8 + 7][c]);
                *(float4*)&out_f[base] = y0;
                *(float4*)&out_f[base + 4] = y1;
            }
        }
    }
}

// ---------------------------------------------------------------------------
// attention: Kg/Vg in [b][v][t][c] layout; heads read 16B channel slices.
// ---------------------------------------------------------------------------
__global__ __launch_bounds__(256) void attn_kernel(const float* __restrict__ Q,
                                                   const bf16* __restrict__ Kg,
                                                   const bf16* __restrict__ Vg,
                                                   float* __restrict__ O) {
    int b = blockIdx.x, h = blockIdx.y, tid = threadIdx.x;
    __shared__ float qs[10 * DSH];
    __shared__ float ks[V1 * 321];
    __shared__ float att[10 * V1];
    const float* Qb = Q + (size_t)b * 10 * DD + h * DSH;
    for (int e = tid; e < 10 * DSH; e += 256) {
        int q = e / DSH, d = e % DSH;
        qs[e] = Qb[(size_t)q * DD + d];
    }
    // stage K slice: ks[kk*321 + cl*40 + t] = Kg[((b*25+kk)*40+t)*64 + h*8+cl]
    const bf16* Kb = Kg + (size_t)b * V1 * DD;
    for (int e = tid; e < V1 * TT; e += 256) {
        const int kk = e / TT, t = e % TT;
        const uint4 u = *(const uint4*)(Kb + ((size_t)kk * TT + t) * 64 + h * 8);
        const ushort* us = (const ushort*)&u;
        float* dst = &ks[kk * 321 + t];
        #pragma unroll
        for (int cl = 0; cl < 8; ++cl) dst[cl * 40] = b2f_us(us[cl]);
    }
    __syncthreads();
    const float scale = 0.019764235376052370f;  // 1/sqrt(2560)
    for (int e = tid; e < 10 * V1; e += 256) {
        int q = e / V1, kk = e % V1;
        float acc = 0.f;
        #pragma unroll 8
        for (int d = 0; d < DSH; ++d) acc += qs[q * DSH + d] * ks[kk * 321 + d];
        att[e] = acc * scale;
    }
    __syncthreads();
    if (tid < 10) {
        float mx = -1e30f;
        for (int k = 0; k < V1; ++k) mx = fmaxf(mx, att[tid * V1 + k]);
        float sum = 0.f;
        for (int k = 0; k < V1; ++k) {
            float e_ = expf(att[tid * V1 + k] - mx);
            att[tid * V1 + k] = e_;
            sum += e_;
        }
        float r = 1.0f / sum;
        for (int k = 0; k < V1; ++k) att[tid * V1 + k] *= r;
    }
    __syncthreads();
    const bf16* Vb = Vg + (size_t)b * V1 * DD;
    float* Ob = O + (size_t)b * 10 * DD + h * DSH;
    for (int hh = 0; hh < 2; ++hh) {
        for (int e = tid; e < V1 * TT; e += 256) {
            const int kk = e / TT, t = e % TT;
            const uint2 u = *(const uint2*)(Vb + ((size_t)kk * TT + t) * 64 + h * 8 + hh * 4);
            const ushort* us = (const ushort*)&u;
            float* dst = &ks[kk * 321 + t];
            #pragma unroll
            for (int cl = 0; cl < 4; ++cl) dst[cl * 40] = b2f_us(us[cl]);
        }
        __syncthreads();
        for (int e = tid; e < 10 * 160; e += 256) {
            int q = e / 160, dl = e % 160;
            float acc = 0.f;
            #pragma unroll
            for (int k = 0; k < V1; ++k) acc += att[q * V1 + k] * ks[k * 321 + dl];
            Ob[(size_t)q * DD + hh * 160 + dl] = qs[q * DSH + hh * 160 + dl] + acc;
        }
        __syncthreads();
    }
}

// ---------------------------------------------------------------------------
extern "C" void kernel_launch(void* const* d_in, const int* in_sizes, int n_in,
                              void* d_out, int out_size, void* d_ws, size_t ws_size,
                              hipStream_t stream) {
    const float* Q = (const float*)d_in[0];
    const float* K = (const float*)d_in[1];
    const float* fck_PA = (const float*)d_in[2];
    const float* fck_Wa = (const float*)d_in[3];
    const float* fck_ba = (const float*)d_in[4];
    const float* fck_Wb = (const float*)d_in[5];
    const float* fck_bb = (const float*)d_in[6];
    const float* fck_Wd = (const float*)d_in[7];
    const float* fck_bd = (const float*)d_in[8];
    const float* fck_gamma = (const float*)d_in[9];
    const float* fck_beta = (const float*)d_in[10];
    const float* fcv_PA = (const float*)d_in[11];
    const float* fcv_Wa = (const float*)d_in[12];
    const float* fcv_ba = (const float*)d_in[13];
    const float* fcv_Wb = (const float*)d_in[14];
    const float* fcv_bb = (const float*)d_in[15];
    const float* fcv_Wd = (const float*)d_in[16];
    const float* fcv_bd = (const float*)d_in[17];
    const float* fcv_gamma = (const float*)d_in[18];
    const float* fcv_beta = (const float*)d_in[19];
    const float* fco_PA = (const float*)d_in[20];
    const float* fco_Wa = (const float*)d_in[21];
    const float* fco_ba = (const float*)d_in[22];
    const float* fco_Wb = (const float*)d_in[23];
    const float* fco_bb = (const float*)d_in[24];
    const float* fco_Wd = (const float*)d_in[25];
    const float* fco_bd = (const float*)d_in[26];
    const float* fco_gamma = (const float*)d_in[27];
    const float* fco_beta = (const float*)d_in[28];

    // Workspace map:
    //   [0, 32.768 MB)      Xbf (bf16 transposed K, written by gcn_S3) — later
    //                       overwritten IN PLACE by gcn_applyKV as Vg (each
    //                       block stages its rows before writing them back).
    //   [32.768, 65.536)    Kg
    //   [65.536, 91.750)    Mpart (S3->reduce), then O (attn->...) — disjoint
    //   [91.750 ..]         S1, S2, S3
    char* wsb = (char*)d_ws;
    bf16* Xbf = (bf16*)(wsb);
    bf16* Vg = (bf16*)(wsb);                     // in-place over Xbf
    bf16* Kg = (bf16*)(wsb + 32768000);
    float* Mpart = (float*)(wsb + 65536000);     // [5][256][6][625] fp32 = 19.2 MB
    float* O = (float*)(wsb + 65536000);         // 26.2 MB, live after reduce
    float* S1 = (float*)(wsb + 91750400);
    float* S2 = (float*)(wsb + 93670400);
    float* S3 = (float*)(wsb + 95590400);

    gcn_S3<<<dim3(BB * 5), dim3(256), 0, stream>>>(
        K, fck_Wa, fck_ba, fck_Wb, fck_bb,
        fcv_Wa, fcv_ba, fcv_Wb, fcv_bb, Xbf, Mpart);

    reduce_softmax<<<dim3(BB, 6), dim3(128), 0, stream>>>(
        Mpart, fck_PA, fcv_PA, S1, S2);

    gcn_applyKV<<<dim3(BB, 10), dim3(256), 0, stream>>>(
        Xbf, S1, S2,
        fck_Wd, fck_bd, fck_gamma, fck_beta,
        fcv_Wd, fcv_bd, fcv_gamma, fcv_beta, Kg, Vg);

    attn_kernel<<<dim3(BB, NH), dim3(256), 0, stream>>>(Q, Kg, Vg, O);

    gcn_S2<V2, 1><<<dim3(BB, 3), dim3(256), 0, stream>>>(
        O, fco_Wa, fco_ba, fco_Wb, fco_bb, fco_PA, S3,
        nullptr, nullptr, nullptr, nullptr, nullptr, nullptr);

    gcn_apply3<V2, 8, 1><<<dim3(BB, 5), dim3(256), 0, stream>>>(
        O, nullptr, S3, fco_Wd, fco_bd, fco_gamma, fco_beta, nullptr, (float*)d_out, O);
}

// Round 3
// 508.777 us; speedup vs baseline: 1.4274x; 1.1278x over previous
//
#include <hip/hip_runtime.h>
#include <hip/hip_bf16.h>

#define BB 256
#define CC 64
#define TT 40
#define DD 2560   // CC*TT
#define V1 25
#define V2 10
#define INTER 16
#define NH 8
#define DSH 320   // DD/NH

typedef __hip_bfloat16 bf16;
typedef unsigned int uint;
typedef unsigned short ushort;
typedef __attribute__((ext_vector_type(8))) short bf16x8;
typedef __attribute__((ext_vector_type(4))) float f32x4;

__device__ __forceinline__ float b2f(bf16 x) { return __bfloat162float(x); }

__device__ __forceinline__ ushort f2bb(float f) {
    uint x = __float_as_uint(f);
    uint r = x + 0x7fffu + ((x >> 16) & 1u);
    return (ushort)(r >> 16);
}
__device__ __forceinline__ float blo(uint u) { return __uint_as_float(u << 16); }
__device__ __forceinline__ float bhi(uint u) { return __uint_as_float(u & 0xffff0000u); }
__device__ __forceinline__ float b2f_us(ushort h) { return __uint_as_float(((uint)h) << 16); }
__device__ __forceinline__ uint4 pack8(const float* a) {
    uint4 pk;
    pk.x = (uint)f2bb(a[0]) | ((uint)f2bb(a[1]) << 16);
    pk.y = (uint)f2bb(a[2]) | ((uint)f2bb(a[3]) << 16);
    pk.z = (uint)f2bb(a[4]) | ((uint)f2bb(a[5]) << 16);
    pk.w = (uint)f2bb(a[6]) | ((uint)f2bb(a[7]) << 16);
    return pk;
}
__device__ __forceinline__ bf16x8 ldfrag8(const ushort* p) {
    union { bf16x8 v; uint2 u[2]; } t;
    t.u[0] = *(const uint2*)p;
    t.u[1] = *(const uint2*)(p + 4);
    return t.v;
}

// LDS swizzle helpers (ushort index). 64-ushort (128B) rows, 16B-granule XOR
// by low row bits -> every vectorized access pattern hits its bank floor.
__device__ __forceinline__ int swz64(int row, int col) {
    return row * 64 + ((((col >> 3) ^ row) & 7) << 3) + (col & 7);
}
// xsC: 128-ushort (256B) rows, granule XOR by (c&15)
__device__ __forceinline__ int swzC(int c, int col) {
    return c * 128 + ((((col >> 3) ^ c) & 15) << 3) + (col & 7);
}

// ---------------------------------------------------------------------------
// gcn_S3 (V=25, fck+fcv fused): grid = (tc*256 + b), 1280 blocks.
// Per block: stage x chunk (8 t's of all v,c) once; EXPORT it as bf16 in
// transposed layout Xbf[((b*25+v)*40+t)*64+c] (coalesced, read by applyKV);
// then for each subset s: proj MFMA + Gram MFMA -> Mpart.
// ---------------------------------------------------------------------------
__global__ __launch_bounds__(256) void gcn_S3(
    const float* __restrict__ X,
    const float* __restrict__ Wa0, const float* __restrict__ ba0,
    const float* __restrict__ Wb0, const float* __restrict__ bb0,
    const float* __restrict__ Wa1, const float* __restrict__ ba1,
    const float* __restrict__ Wb1, const float* __restrict__ bb1,
    bf16* __restrict__ Xw, float* __restrict__ Mpart) {
    __shared__ ushort xsT[208][72];    // [p=v*8+tl][c]; rows 200..207 garbage
    __shared__ ushort wT[64][72];      // [mat*16+j][c] for current s
    __shared__ ushort abT[4][32][136]; // [mat][v][j*8+tl]
    __shared__ float biasS[64];

    const int tid = threadIdx.x;
    const int b = blockIdx.x & 255, tc = blockIdx.x >> 8;
    const int t0 = tc * 8;
    const int lane = tid & 63, w = tid >> 6;
    const int ln = lane & 15, lq = lane >> 4;

    // stage x chunk: (v,c) -> 8 t's, bf16 into transposed rows p=v*8+tl
    const float* Xb = X + (size_t)b * V1 * DD;
    for (int e = tid; e < V1 * 64; e += 256) {
        const int v = e >> 6, c = e & 63;
        const float* src = Xb + (size_t)v * DD + c * TT + t0;
        const float4 f0 = *(const float4*)src;
        const float4 f1 = *(const float4*)(src + 4);
        const float tmp[8] = {f0.x, f0.y, f0.z, f0.w, f1.x, f1.y, f1.z, f1.w};
        #pragma unroll
        for (int tl = 0; tl < 8; ++tl) xsT[v * 8 + tl][c] = f2bb(tmp[tl]);
    }
    __syncthreads();                   // xsT complete

    // export bf16 transposed X: Xw[((b*25+v)*40 + t0+tl)*64 + c], uint4 rows
    for (int e = tid; e < 1600; e += 256) {
        const int p = e >> 3, c8 = e & 7;
        const int v = p >> 3, tl = p & 7;
        *(uint4*)(Xw + (((size_t)b * V1 + v) * TT + t0 + tl) * 64 + c8 * 8) =
            *(const uint4*)&xsT[p][c8 * 8];
    }

    for (int s = 0; s < 3; ++s) {
        if (s) __syncthreads();        // prev Gram done with abT, proj done with wT
        // stage W (4 mats x 16 x 64) + bias for this s
        for (int e = tid; e < 4096; e += 256) {
            const int mat = e >> 10, r = e & 1023;
            const float* Wp = (mat == 0) ? Wa0 : (mat == 1) ? Wb0 : (mat == 2) ? Wa1 : Wb1;
            wT[(mat << 4) + (r >> 6)][r & 63] = f2bb(Wp[s * 1024 + r]);
        }
        if (tid < 64) {
            const int mat = tid >> 4, j = tid & 15;
            const float* bp = (mat == 0) ? ba0 : (mat == 1) ? bb0 : (mat == 2) ? ba1 : bb1;
            biasS[tid] = bp[s * 16 + j];
        }
        __syncthreads();               // wT/xsT ready

        // ---- projection: wave w computes mat w over 13 n-tiles ----
        const bf16x8 a0 = *(const bf16x8*)&wT[w * 16 + ln][lq * 8];
        const bf16x8 a1 = *(const bf16x8*)&wT[w * 16 + ln][lq * 8 + 32];
        float br[4];
        #pragma unroll
        for (int r = 0; r < 4; ++r) br[r] = biasS[w * 16 + lq * 4 + r];
        for (int nt = 0; nt < 13; ++nt) {
            const bf16x8 b0 = *(const bf16x8*)&xsT[nt * 16 + ln][lq * 8];
            const bf16x8 b1 = *(const bf16x8*)&xsT[nt * 16 + ln][lq * 8 + 32];
            f32x4 acc = (f32x4){0.f, 0.f, 0.f, 0.f};
            acc = __builtin_amdgcn_mfma_f32_16x16x32_bf16(a0, b0, acc, 0, 0, 0);
            acc = __builtin_amdgcn_mfma_f32_16x16x32_bf16(a1, b1, acc, 0, 0, 0);
            const int p = nt * 16 + ln;
            if (p < 200) {
                const int v = p >> 3, tl = p & 7;
                #pragma unroll
                for (int r = 0; r < 4; ++r)
                    abT[w][v][(lq * 4 + r) * 8 + tl] = f2bb(acc[r] + br[r]);
            }
        }
        __syncthreads();               // abT ready

        // ---- Gram: 8 tile-units (np,mt,nt), wave w does units w and w+4 ----
        #pragma unroll
        for (int uu = 0; uu < 2; ++uu) {
            const int u = w + uu * 4;
            const int np = u >> 2, mt = (u >> 1) & 1, ntl = u & 1;
            const ushort* Ap = &abT[np * 2 + 0][mt * 16 + ln][lq * 8];
            const ushort* Bp = &abT[np * 2 + 1][ntl * 16 + ln][lq * 8];
            f32x4 g = (f32x4){0.f, 0.f, 0.f, 0.f};
            g = __builtin_amdgcn_mfma_f32_16x16x32_bf16(
                    *(const bf16x8*)Ap, *(const bf16x8*)Bp, g, 0, 0, 0);
            g = __builtin_amdgcn_mfma_f32_16x16x32_bf16(
                    *(const bf16x8*)(Ap + 32), *(const bf16x8*)(Bp + 32), g, 0, 0, 0);
            g = __builtin_amdgcn_mfma_f32_16x16x32_bf16(
                    *(const bf16x8*)(Ap + 64), *(const bf16x8*)(Bp + 64), g, 0, 0, 0);
            g = __builtin_amdgcn_mfma_f32_16x16x32_bf16(
                    *(const bf16x8*)(Ap + 96), *(const bf16x8*)(Bp + 96), g, 0, 0, 0);
            const int vp = ntl * 16 + ln;
            if (vp < V1) {
                float* Mb = Mpart + (((size_t)tc * 256 + b) * 6 + (s * 2 + np)) * 625;
                #pragma unroll
                for (int r = 0; r < 4; ++r) {
                    const int v = mt * 16 + lq * 4 + r;
                    if (v < V1) Mb[v * V1 + vp] = g[r];
                }
            }
        }
    }
}

// ---------------------------------------------------------------------------
// reduce_softmax: grid (b, snp=s*2+np), 128 threads. Sum 5 chunk-partials,
// column softmax over v (axis=-2), + PA, write Sbf (bf16 S^T, zero-padded
// to [b][g][s][32][32] -- exactly applyKV's SlT layout). Blocks with b==0
// additionally emit Wdf: Wd pre-converted bf16 in MFMA fragment order
// [g][s][w][lane][16] so applyKV reads A-frags straight from L2.
// ---------------------------------------------------------------------------
__global__ __launch_bounds__(128) void reduce_softmax(
    const float* __restrict__ Mpart,
    const float* __restrict__ PA0, const float* __restrict__ PA1,
    const float* __restrict__ WdK, const float* __restrict__ WdV,
    ushort* __restrict__ Sbf, ushort* __restrict__ Wdf) {
    __shared__ float Ms[625];
    const int tid = threadIdx.x, b = blockIdx.x, snp = blockIdx.y;
    const int s = snp >> 1, np = snp & 1;

    // Wdf prep (6 blocks only): fragment (w,lane) = rows w*16+ln, cols lq*8(+32)
    if (b == 0) {
        for (int e = tid; e < 256; e += 128) {
            const int wv = e >> 6, l = e & 63;
            const int lnn = l & 15, lqq = l >> 4;
            const float* Wp = (np ? WdV : WdK) + s * 4096 + (wv * 16 + lnn) * 64 + lqq * 8;
            ushort* dst = Wdf + (((np * 3 + s) * 4 + wv) * 64 + l) * 16;
            #pragma unroll
            for (int j = 0; j < 8; ++j) {
                dst[j] = f2bb(Wp[j]);
                dst[8 + j] = f2bb(Wp[32 + j]);
            }
        }
    }

    for (int e = tid; e < 625; e += 128) {
        float sum = 0.f;
        #pragma unroll
        for (int tcc = 0; tcc < 5; ++tcc)
            sum += Mpart[(((size_t)tcc * 256 + b) * 6 + snp) * 625 + e];
        Ms[e] = sum;
    }
    __syncthreads();
    if (tid < 32) {
        ushort* SbfRow = Sbf + ((((size_t)b * 2 + np) * 3 + s) << 10) + tid * 32;
        if (tid < V1) {
            const int vp = tid;
            const float invIT = 1.0f / 640.0f;
            float mx = -1e30f;
            for (int v = 0; v < V1; ++v) mx = fmaxf(mx, Ms[v * V1 + vp]);
            float sum = 0.f;
            for (int v = 0; v < V1; ++v) sum += expf((Ms[v * V1 + vp] - mx) * invIT);
            const float rs = 1.f / sum;
            const float* PAn = np ? PA1 : PA0;
            for (int v = 0; v < V1; ++v) {
                const float e_ = expf((Ms[v * V1 + vp] - mx) * invIT);
                SbfRow[v] = f2bb(e_ * rs + PAn[(s * V1 + v) * V1 + vp]);
            }
            for (int v = V1; v < 32; ++v) SbfRow[v] = 0;
        } else {
            for (int v = 0; v < 32; ++v) SbfRow[v] = 0;
        }
    }
}

// ---------------------------------------------------------------------------
// gcn_S2 (VALU version, kept for the small V=10 fco case).
// ---------------------------------------------------------------------------
template<int V, int NP>
__global__ __launch_bounds__(256) void gcn_S2(
    const float* __restrict__ X,
    const float* __restrict__ Wa0, const float* __restrict__ ba0,
    const float* __restrict__ Wb0, const float* __restrict__ bb0,
    const float* __restrict__ PA0, float* __restrict__ Sout0,
    const float* __restrict__ Wa1, const float* __restrict__ ba1,
    const float* __restrict__ Wb1, const float* __restrict__ bb1,
    const float* __restrict__ PA1, float* __restrict__ Sout1) {
    constexpr int TC = 8;
    constexpr int NCH = TT / TC;
    constexpr int P = V * TC;
    constexpr int ROWS = NP * 32;
    constexpr int NRQ = ROWS / 4;
    constexpr int NC8 = P / 8;
    constexpr int NTILE = NRQ * NC8;
    constexpr int NM = NP * V * V;
    constexpr int NMI = (NM + 255) / 256;

    __shared__ ushort xs[64][P];
    __shared__ ushort ab[ROWS][P];
    __shared__ ushort wT[64][ROWS];
    __shared__ float biasL[ROWS];
    __shared__ float M[NM];

    const int tid = threadIdx.x, b = blockIdx.x, s = blockIdx.y;

    for (int e = tid; e < 16 * 64; e += 256) {
        int c = e & 63;
        int j = e >> 6;
        wT[c][j]      = f2bb(Wa0[s * 1024 + e]);
        wT[c][16 + j] = f2bb(Wb0[s * 1024 + e]);
        if constexpr (NP == 2) {
            wT[c][32 + j] = f2bb(Wa1[s * 1024 + e]);
            wT[c][48 + j] = f2bb(Wb1[s * 1024 + e]);
        }
    }
    if (tid < 16) {
        biasL[tid]      = ba0[s * 16 + tid];
        biasL[16 + tid] = bb0[s * 16 + tid];
        if constexpr (NP == 2) {
            biasL[32 + tid] = ba1[s * 16 + tid];
            biasL[48 + tid] = bb1[s * 16 + tid];
        }
    }

    float macc[NMI];
    #pragma unroll
    for (int k = 0; k < NMI; ++k) macc[k] = 0.f;

    const float* Xb = X + (size_t)b * V * DD;
    for (int tc = 0; tc < NCH; ++tc) {
        const int t0 = tc * TC;
        for (int e = tid; e < V * 64; e += 256) {
            const int v = e >> 6, c = e & 63;
            const float* src = Xb + (size_t)v * DD + c * TT + t0;
            const float4 f0 = *(const float4*)src;
            const float4 f1 = *(const float4*)(src + 4);
            const float tmp[8] = {f0.x, f0.y, f0.z, f0.w, f1.x, f1.y, f1.z, f1.w};
            *(uint4*)&xs[c][v * 8] = pack8(tmp);
        }
        __syncthreads();
        for (int tau = tid; tau < NTILE; tau += 256) {
            const int rq = tau % NRQ, co = tau / NRQ;
            float acc[4][8];
            #pragma unroll
            for (int r = 0; r < 4; ++r) {
                const float bv = biasL[4 * rq + r];
                #pragma unroll
                for (int cc = 0; cc < 8; ++cc) acc[r][cc] = bv;
            }
            for (int c = 0; c < 64; ++c) {
                const uint2 wv = *(const uint2*)&wT[c][4 * rq];
                const uint4 xv = *(const uint4*)&xs[c][8 * co];
                const float w0 = blo(wv.x), w1 = bhi(wv.x);
                const float w2 = blo(wv.y), w3 = bhi(wv.y);
                const float x0 = blo(xv.x), x1 = bhi(xv.x);
                const float x2 = blo(xv.y), x3 = bhi(xv.y);
                const float x4 = blo(xv.z), x5 = bhi(xv.z);
                const float x6 = blo(xv.w), x7 = bhi(xv.w);
                acc[0][0] += w0 * x0; acc[0][1] += w0 * x1;
                acc[0][2] += w0 * x2; acc[0][3] += w0 * x3;
                acc[0][4] += w0 * x4; acc[0][5] += w0 * x5;
                acc[0][6] += w0 * x6; acc[0][7] += w0 * x7;
                acc[1][0] += w1 * x0; acc[1][1] += w1 * x1;
                acc[1][2] += w1 * x2; acc[1][3] += w1 * x3;
                acc[1][4] += w1 * x4; acc[1][5] += w1 * x5;
                acc[1][6] += w1 * x6; acc[1][7] += w1 * x7;
                acc[2][0] += w2 * x0; acc[2][1] += w2 * x1;
                acc[2][2] += w2 * x2; acc[2][3] += w2 * x3;
                acc[2][4] += w2 * x4; acc[2][5] += w2 * x5;
                acc[2][6] += w2 * x6; acc[2][7] += w2 * x7;
                acc[3][0] += w3 * x0; acc[3][1] += w3 * x1;
                acc[3][2] += w3 * x2; acc[3][3] += w3 * x3;
                acc[3][4] += w3 * x4; acc[3][5] += w3 * x5;
                acc[3][6] += w3 * x6; acc[3][7] += w3 * x7;
            }
            #pragma unroll
            for (int r = 0; r < 4; ++r)
                *(uint4*)&ab[4 * rq + r][8 * co] = pack8(acc[r]);
        }
        __syncthreads();
        #pragma unroll
        for (int k = 0; k < NMI; ++k) {
            const int idx = tid + k * 256;
            if (idx < NM) {
                const int np = idx / (V * V), r = idx % (V * V);
                const int v = r / V, vp = r % V;
                const int ra = np * 32, rb = np * 32 + 16;
                float mm = 0.f;
                #pragma unroll
                for (int j = 0; j < 16; ++j) {
                    const uint4 av = *(const uint4*)&ab[ra + j][v * 8];
                    const uint4 bv = *(const uint4*)&ab[rb + j][vp * 8];
                    mm += blo(av.x) * blo(bv.x) + bhi(av.x) * bhi(bv.x)
                        + blo(av.y) * blo(bv.y) + bhi(av.y) * bhi(bv.y)
                        + blo(av.z) * blo(bv.z) + bhi(av.z) * bhi(bv.z)
                        + blo(av.w) * blo(bv.w) + bhi(av.w) * bhi(bv.w);
                }
                macc[k] += mm;
            }
        }
    }

    #pragma unroll
    for (int k = 0; k < NMI; ++k) {
        const int idx = tid + k * 256;
        if (idx < NM) M[idx] = macc[k];
    }
    __syncthreads();

    const float invIT = 1.0f / 640.0f;
    if (tid < NP * V) {
        const int np = tid / V, vp = tid % V;
        const float* Mn = &M[np * V * V];
        float mx = -1e30f;
        for (int v = 0; v < V; ++v) mx = fmaxf(mx, Mn[v * V + vp]);
        float sum = 0.f;
        for (int v = 0; v < V; ++v) sum += expf((Mn[v * V + vp] - mx) * invIT);
        const float rs = 1.f / sum;
        const float* PAn = (np == 0) ? PA0 : PA1;
        float* Sn = (np == 0) ? Sout0 : Sout1;
        for (int v = 0; v < V; ++v) {
            const float e_ = expf((Mn[v * V + vp] - mx) * invIT);
            Sn[((size_t)(b * 3 + s) * V + v) * V + vp] =
                e_ * rs + PAn[(s * V + v) * V + vp];
        }
    }
}

// ---------------------------------------------------------------------------
// gcn_applyKV: fused fck+fcv apply for V=25, all-MFMA, minimal staging:
//   - S comes pre-transposed/pre-converted from Sbf (uint4 copies)
//   - Wd A-frags come pre-laid-out from Wdf (two 16B L2-hit loads/(g,s))
//   - xsC is transient (read once into aF regs) -> shares LDS with zsT
// LDS 43KB -> 3 blocks/CU. zsT rows 100.. are stale-but-finite garbage whose
// products land only in discarded D columns (p>=100).
// ---------------------------------------------------------------------------
__global__ __launch_bounds__(256) void gcn_applyKV(
    const bf16* __restrict__ Xbf,
    const ushort* __restrict__ Sbf, const ushort* __restrict__ Wdf,
    const float* __restrict__ bdK, const float* __restrict__ gK, const float* __restrict__ beK,
    const float* __restrict__ bdV, const float* __restrict__ gV, const float* __restrict__ beV,
    bf16* __restrict__ Kg, bf16* __restrict__ Vg) {

    __shared__ ushort xsT[100 * 64];   // [p=v*4+tl][c], swz64 (persist)
    __shared__ ushort SlTs[6144];      // [(g*3+s)*1024 + vp*32 + v0] (persist)
    __shared__ ushort uC[8192];        // xsC [c][tl*32+v0] swzC, then zsT [p][c] swz64
    __shared__ float bias6[6 * 64];    // bdsK,bdsV, sclK,sclV, betK,betV

    const int tid = threadIdx.x, b = blockIdx.x, chunk = blockIdx.y;
    const int lane = tid & 63, w = tid >> 6;
    const int ln = lane & 15, lq = lane >> 4;
    const int t0 = chunk * 4;

    if (tid < 64) {
        bias6[tid]       = bdK[tid] + bdK[64 + tid] + bdK[128 + tid];
        bias6[64 + tid]  = bdV[tid] + bdV[64 + tid] + bdV[128 + tid];
        bias6[128 + tid] = gK[tid] * rsqrtf(1.f + 1e-5f);
        bias6[192 + tid] = gV[tid] * rsqrtf(1.f + 1e-5f);
        bias6[256 + tid] = beK[tid];
        bias6[320 + tid] = beV[tid];
    }
    // stage xsT (coalesced 16B rows)
    const bf16* Xb = Xbf + (size_t)b * V1 * DD;
    for (int e = tid; e < 800; e += 256) {
        const int p = e >> 3, c8 = e & 7;
        const int v = p >> 2, tl = p & 3;
        *(uint4*)&xsT[swz64(p, c8 * 8)] =
            *(const uint4*)(Xb + ((size_t)v * TT + t0 + tl) * 64 + c8 * 8);
    }
    // stage SlTs: straight uint4 copy of precomputed bf16 S^T
    {
        const ushort* Sb = Sbf + (size_t)b * 6144;
        for (int e = tid; e < 768; e += 256)
            ((uint4*)SlTs)[e] = ((const uint4*)Sb)[e];
    }
    __syncthreads();   // xsT + SlTs staged

    // LDS transpose xsT -> xsC[c][tl*32+v0] (zero-pad v0>=25)
    {
        const int c = lane, q = w;   // 64 lanes = one row each, conflict-free
        #pragma unroll
        for (int j = 0; j < 4; ++j) {
            ushort vals[8];
            #pragma unroll
            for (int i = 0; i < 8; ++i) {
                const int v0 = q * 8 + i;
                vals[i] = (v0 < V1) ? xsT[swz64(v0 * 4 + j, c)] : (ushort)0;
            }
            uint4 pk;
            pk.x = (uint)vals[0] | ((uint)vals[1] << 16);
            pk.y = (uint)vals[2] | ((uint)vals[3] << 16);
            pk.z = (uint)vals[4] | ((uint)vals[5] << 16);
            pk.w = (uint)vals[6] | ((uint)vals[7] << 16);
            *(uint4*)&uC[swzC(c, j * 32 + q * 8)] = pk;
        }
    }
    __syncthreads();   // xsC ready

    // A-frags for GEMM-1 (held in regs all kernel): wave w = c-tile
    bf16x8 aF[4];
    #pragma unroll
    for (int tl = 0; tl < 4; ++tl)
        aF[tl] = *(const bf16x8*)&uC[swzC(w * 16 + ln, tl * 32 + lq * 8)];
    __syncthreads();   // aF reads done -> uC becomes zsT

    for (int g = 0; g < 2; ++g) {
        f32x4 acc[7];
        #pragma unroll
        for (int tn = 0; tn < 7; ++tn) acc[tn] = (f32x4){0.f, 0.f, 0.f, 0.f};

        for (int s = 0; s < 3; ++s) {
            // prefetch Wd A-frags (L2-hit; latency hides under GEMM-1)
            const ushort* wp = Wdf + ((((g * 3 + s) * 4 + w) * 64 + lane) << 4);
            union { uint4 u; bf16x8 v; } ua, ub;
            ua.u = *(const uint4*)wp;
            ub.u = *(const uint4*)(wp + 8);

            if (g | s) __syncthreads();   // prior GEMM-2 / out-copy done with zsT

            // ---- GEMM-1 (MFMA): D[c][v] = sum_v0 X^T[c][v0] * S[v0][v] ----
            #pragma unroll
            for (int nt = 0; nt < 2; ++nt) {
                const bf16x8 bF =
                    *(const bf16x8*)&SlTs[((g * 3 + s) << 10) + (nt * 16 + ln) * 32 + lq * 8];
                const int v = nt * 16 + ln;
                #pragma unroll
                for (int tl = 0; tl < 4; ++tl) {
                    f32x4 d = (f32x4){0.f, 0.f, 0.f, 0.f};
                    d = __builtin_amdgcn_mfma_f32_16x16x32_bf16(aF[tl], bF, d, 0, 0, 0);
                    if (v < V1) {
                        uint2 pk;
                        pk.x = (uint)f2bb(d[0]) | ((uint)f2bb(d[1]) << 16);
                        pk.y = (uint)f2bb(d[2]) | ((uint)f2bb(d[3]) << 16);
                        *(uint2*)&uC[swz64(v * 4 + tl, w * 16 + lq * 4)] = pk;
                    }
                }
            }
            __syncthreads();   // zsT ready

            // ---- GEMM-2 (MFMA): acc[o][p] += Wd[o][c] * z[p][c] ----
            #pragma unroll
            for (int tn = 0; tn < 7; ++tn) {
                const bf16x8 b0 = *(const bf16x8*)&uC[swz64(tn * 16 + ln, lq * 8)];
                const bf16x8 b1 = *(const bf16x8*)&uC[swz64(tn * 16 + ln, lq * 8 + 32)];
                acc[tn] = __builtin_amdgcn_mfma_f32_16x16x32_bf16(ua.v, b0, acc[tn], 0, 0, 0);
                acc[tn] = __builtin_amdgcn_mfma_f32_16x16x32_bf16(ub.v, b1, acc[tn], 0, 0, 0);
            }
        }
        __syncthreads();   // GEMM-2 done reading zsT

        // ---- epilogue: BN + residual + relu -> zsT (bf16) ----
        {
            const int c0 = w * 16 + lq * 4;
            float bb[4], ss[4], be[4];
            #pragma unroll
            for (int r = 0; r < 4; ++r) {
                bb[r] = bias6[g * 64 + c0 + r];
                ss[r] = bias6[128 + g * 64 + c0 + r];
                be[r] = bias6[256 + g * 64 + c0 + r];
            }
            #pragma unroll
            for (int tn = 0; tn < 7; ++tn) {
                const int p = tn * 16 + ln;
                if (p < 100) {
                    const uint2 u = *(const uint2*)&xsT[swz64(p, c0)];
                    const float rs[4] = {blo(u.x), bhi(u.x), blo(u.y), bhi(u.y)};
                    float y[4];
                    #pragma unroll
                    for (int r = 0; r < 4; ++r)
                        y[r] = fmaxf((acc[tn][r] + bb[r]) * ss[r] + be[r] + rs[r], 0.f);
                    uint2 pk;
                    pk.x = (uint)f2bb(y[0]) | ((uint)f2bb(y[1]) << 16);
                    pk.y = (uint)f2bb(y[2]) | ((uint)f2bb(y[3]) << 16);
                    *(uint2*)&uC[swz64(p, c0)] = pk;
                }
            }
        }
        __syncthreads();

        // ---- coalesced bf16 output, [b][v][t][c] layout ----
        bf16* outp = (g ? Vg : Kg) + (size_t)b * V1 * DD;
        for (int e = tid; e < 800; e += 256) {
            const int p = e >> 3, c8 = e & 7;
            const int v = p >> 2, tl = p & 3;
            *(uint4*)(outp + ((size_t)v * TT + t0 + tl) * 64 + c8 * 8) =
                *(const uint4*)&uC[swz64(p, c8 * 8)];
        }
    }
}

// ---------------------------------------------------------------------------
// gcn_apply3 (old template, kept ONLY for the V=10 fco case, MODE 1).
// ---------------------------------------------------------------------------
template<int V, int TC, int MODE>
__global__ __launch_bounds__(256) void gcn_apply3(const float* __restrict__ X,
                                                  const bf16* __restrict__ Xbf,
                                                  const float* __restrict__ Sbuf,
                                                  const float* __restrict__ Wd,
                                                  const float* __restrict__ bd,
                                                  const float* __restrict__ gamma,
                                                  const float* __restrict__ beta,
                                                  bf16* __restrict__ out_bf,
                                                  float* __restrict__ out_f,
                                                  const float* __restrict__ Obuf) {
    constexpr int VSLOT = 128 / TC;
    constexpr int ROWS = V * TC;
    constexpr int NT = (V == 25) ? 7 : 5;

    __shared__ ushort xsT[ROWS][72];
    __shared__ ushort zsT[128][72];
    __shared__ ushort wdT[64][72];
    __shared__ ushort Sl[3][VSLOT][34];
    __shared__ float bds[64], scl[64], bet[64];

    const int tid = threadIdx.x, b = blockIdx.x, chunk = blockIdx.y;
    const int ci = tid >> 4, pj = tid & 15;
    const int lane = tid & 63, w = tid >> 6;
    const int ln = lane & 15, lq = lane >> 4;
    const int t0 = chunk * TC;

    for (int e = tid; e < 3 * VSLOT * 17; e += 256) ((uint*)Sl)[e] = 0u;
    if (tid < 64) {
        bds[tid] = bd[tid] + bd[64 + tid] + bd[128 + tid];
        scl[tid] = gamma[tid] * rsqrtf(1.f + 1e-5f);
        bet[tid] = beta[tid];
    }
    __syncthreads();
    for (int e = tid; e < 3 * V * V; e += 256) {
        int s = e / (V * V), r = e % (V * V);
        Sl[s][r / V][r % V] = f2bb(Sbuf[(size_t)b * 3 * V * V + e]);
    }
    if constexpr (MODE == 0) {
        for (int e = tid; e < ROWS * 8; e += 256) {
            const int p = e >> 3, c8 = e & 7;
            const int v = p / TC, tl = p % TC;
            *(uint4*)&xsT[p][c8 * 8] =
                *(const uint4*)(Xbf + (((size_t)b * V + v) * TT + t0 + tl) * 64 + c8 * 8);
        }
    } else {
        const float* Xb = X + (size_t)b * V * DD;
        for (int e = tid; e < V * 64 * TC; e += 256) {
            int v = e / (64 * TC), inner = e % (64 * TC);
            int c = inner / TC, tl = inner % TC;
            xsT[v * TC + tl][c] = f2bb(Xb[(size_t)v * DD + c * TT + t0 + tl]);
        }
    }
    __syncthreads();

    f32x4 acc[NT];
    #pragma unroll
    for (int tn = 0; tn < NT; ++tn) acc[tn] = (f32x4){0.f, 0.f, 0.f, 0.f};

    for (int s = 0; s < 3; ++s) {
        if (s) __syncthreads();
        for (int e = tid; e < 4096; e += 256)
            wdT[e >> 6][e & 63] = f2bb(Wd[s * 4096 + e]);

        float za[4][8];
        #pragma unroll
        for (int r = 0; r < 4; ++r)
            #pragma unroll
            for (int cc = 0; cc < 8; ++cc) za[r][cc] = 0.f;

        if constexpr (V == 25) {
            for (int v0 = 0; v0 < 25; ++v0) {
                const uint sv = *(const uint*)&Sl[s][v0][2 * pj];
                const float svx = blo(sv), svy = bhi(sv);
                #pragma unroll
                for (int tl = 0; tl < 4; ++tl) {
                    const uint2 u = *(const uint2*)&xsT[v0 * 4 + tl][ci * 4];
                    const float a0 = blo(u.x), a1 = bhi(u.x);
                    const float a2 = blo(u.y), a3 = bhi(u.y);
                    za[0][tl] += a0 * svx;  za[0][4 + tl] += a0 * svy;
                    za[1][tl] += a1 * svx;  za[1][4 + tl] += a1 * svy;
                    za[2][tl] += a2 * svx;  za[2][4 + tl] += a2 * svy;
                    za[3][tl] += a3 * svx;  za[3][4 + tl] += a3 * svy;
                }
            }
        } else {
            for (int v0 = 0; v0 < 10; ++v0) {
                const float sv = b2f_us(Sl[s][v0][pj]);
                #pragma unroll
                for (int tl = 0; tl < 8; ++tl) {
                    const uint2 u = *(const uint2*)&xsT[v0 * 8 + tl][ci * 4];
                    za[0][tl] += blo(u.x) * sv;
                    za[1][tl] += bhi(u.x) * sv;
                    za[2][tl] += blo(u.y) * sv;
                    za[3][tl] += bhi(u.y) * sv;
                }
            }
        }
        #pragma unroll
        for (int cc = 0; cc < 8; ++cc) {
            uint2 pk;
            pk.x = (uint)f2bb(za[0][cc]) | ((uint)f2bb(za[1][cc]) << 16);
            pk.y = (uint)f2bb(za[2][cc]) | ((uint)f2bb(za[3][cc]) << 16);
            *(uint2*)&zsT[pj * 8 + cc][ci * 4] = pk;
        }
        __syncthreads();

        const bf16x8 a0 = *(const bf16x8*)&wdT[w * 16 + ln][lq * 8];
        const bf16x8 a1 = *(const bf16x8*)&wdT[w * 16 + ln][lq * 8 + 32];
        #pragma unroll
        for (int tn = 0; tn < NT; ++tn) {
            const bf16x8 b0 = ldfrag8(&zsT[tn * 16 + ln][lq * 8]);
            const bf16x8 b1 = ldfrag8(&zsT[tn * 16 + ln][lq * 8 + 32]);
            acc[tn] = __builtin_amdgcn_mfma_f32_16x16x32_bf16(a0, b0, acc[tn], 0, 0, 0);
            acc[tn] = __builtin_amdgcn_mfma_f32_16x16x32_bf16(a1, b1, acc[tn], 0, 0, 0);
        }
    }

    __syncthreads();
    {
        const int c0 = w * 16 + lq * 4;
        float bb[4], ss[4], be[4];
        #pragma unroll
        for (int r = 0; r < 4; ++r) {
            bb[r] = bds[c0 + r]; ss[r] = scl[c0 + r]; be[r] = bet[c0 + r];
        }
        #pragma unroll
        for (int tn = 0; tn < NT; ++tn) {
            const int p = tn * 16 + ln;
            if (p < ROWS) {
                const uint2 u = *(const uint2*)&xsT[p][c0];
                const float rs[4] = {blo(u.x), bhi(u.x), blo(u.y), bhi(u.y)};
                float y[4];
                #pragma unroll
                for (int r = 0; r < 4; ++r)
                    y[r] = fmaxf((acc[tn][r] + bb[r]) * ss[r] + be[r] + rs[r], 0.f);
                uint2 pk;
                pk.x = (uint)f2bb(y[0]) | ((uint)f2bb(y[1]) << 16);
                pk.y = (uint)f2bb(y[2]) | ((uint)f2bb(y[3]) << 16);
                *(uint2*)&zsT[p][c0] = pk;
            }
        }
    }
    __syncthreads();

    if constexpr (MODE == 0) {
        for (int e = tid; e < ROWS * 8; e += 256) {
            const int p = e >> 3, c8 = e & 7;
            const int v = p / TC, tl = p % TC;
            *(uint4*)(out_bf + (((size_t)b * V + v) * TT + t0 + tl) * 64 + c8 * 8) =
                *(const uint4*)&zsT[p][c8 * 8];
        }
    } else {
        const int v = pj;
        if (v < V) {
            #pragma unroll
            for (int r = 0; r < 4; ++r) {
                const int c = ci * 4 + r;
                const size_t base = (size_t)b * V * DD + (size_t)v * DD + c * TT + t0;
                const float4 o0 = *(const float4*)&Obuf[base];
                const float4 o1 = *(const float4*)&Obuf[base + 4];
                float4 y0, y1;
                y0.x = o0.x + b2f_us(zsT[v * 8 + 0][c]);
                y0.y = o0.y + b2f_us(zsT[v * 8 + 1][c]);
                y0.z = o0.z + b2f_us(zsT[v * 8 + 2][c]);
                y0.w = o0.w + b2f_us(zsT[v * 8 + 3][c]);
                y1.x = o1.x + b2f_us(zsT[v * 8 + 4][c]);
                y1.y = o1.y + b2f_us(zsT[v * 8 + 5][c]);
                y1.z = o1.z + b2f_us(zsT[v * 8 + 6][c]);
                y1.w = o1.w + b2f_us(zsT[v * 8 + 7][c]);
                *(float4*)&out_f[base] = y0;
                *(float4*)&out_f[base + 4] = y1;
            }
        }
    }
}

// ---------------------------------------------------------------------------
// attention: Kg/Vg in [b][v][t][c] layout; heads read 16B channel slices.
// ---------------------------------------------------------------------------
__global__ __launch_bounds__(256) void attn_kernel(const float* __restrict__ Q,
                                                   const bf16* __restrict__ Kg,
                                                   const bf16* __restrict__ Vg,
                                                   float* __restrict__ O) {
    int b = blockIdx.x, h = blockIdx.y, tid = threadIdx.x;
    __shared__ float qs[10 * DSH];
    __shared__ float ks[V1 * 321];
    __shared__ float att[10 * V1];
    const float* Qb = Q + (size_t)b * 10 * DD + h * DSH;
    for (int e = tid; e < 10 * DSH; e += 256) {
        int q = e / DSH, d = e % DSH;
        qs[e] = Qb[(size_t)q * DD + d];
    }
    // stage K slice: ks[kk*321 + cl*40 + t] = Kg[((b*25+kk)*40+t)*64 + h*8+cl]
    const bf16* Kb = Kg + (size_t)b * V1 * DD;
    for (int e = tid; e < V1 * TT; e += 256) {
        const int kk = e / TT, t = e % TT;
        const uint4 u = *(const uint4*)(Kb + ((size_t)kk * TT + t) * 64 + h * 8);
        const ushort* us = (const ushort*)&u;
        float* dst = &ks[kk * 321 + t];
        #pragma unroll
        for (int cl = 0; cl < 8; ++cl) dst[cl * 40] = b2f_us(us[cl]);
    }
    __syncthreads();
    const float scale = 0.019764235376052370f;  // 1/sqrt(2560)
    for (int e = tid; e < 10 * V1; e += 256) {
        int q = e / V1, kk = e % V1;
        float acc = 0.f;
        #pragma unroll 8
        for (int d = 0; d < DSH; ++d) acc += qs[q * DSH + d] * ks[kk * 321 + d];
        att[e] = acc * scale;
    }
    __syncthreads();
    if (tid < 10) {
        float mx = -1e30f;
        for (int k = 0; k < V1; ++k) mx = fmaxf(mx, att[tid * V1 + k]);
        float sum = 0.f;
        for (int k = 0; k < V1; ++k) {
            float e_ = expf(att[tid * V1 + k] - mx);
            att[tid * V1 + k] = e_;
            sum += e_;
        }
        float r = 1.0f / sum;
        for (int k = 0; k < V1; ++k) att[tid * V1 + k] *= r;
    }
    __syncthreads();
    const bf16* Vb = Vg + (size_t)b * V1 * DD;
    float* Ob = O + (size_t)b * 10 * DD + h * DSH;
    for (int hh = 0; hh < 2; ++hh) {
        for (int e = tid; e < V1 * TT; e += 256) {
            const int kk = e / TT, t = e % TT;
            const uint2 u = *(const uint2*)(Vb + ((size_t)kk * TT + t) * 64 + h * 8 + hh * 4);
            const ushort* us = (const ushort*)&u;
            float* dst = &ks[kk * 321 + t];
            #pragma unroll
            for (int cl = 0; cl < 4; ++cl) dst[cl * 40] = b2f_us(us[cl]);
        }
        __syncthreads();
        for (int e = tid; e < 10 * 160; e += 256) {
            int q = e / 160, dl = e % 160;
            float acc = 0.f;
            #pragma unroll
            for (int k = 0; k < V1; ++k) acc += att[q * V1 + k] * ks[k * 321 + dl];
            Ob[(size_t)q * DD + hh * 160 + dl] = qs[q * DSH + hh * 160 + dl] + acc;
        }
        __syncthreads();
    }
}

// ---------------------------------------------------------------------------
extern "C" void kernel_launch(void* const* d_in, const int* in_sizes, int n_in,
                              void* d_out, int out_size, void* d_ws, size_t ws_size,
                              hipStream_t stream) {
    const float* Q = (const float*)d_in[0];
    const float* K = (const float*)d_in[1];
    const float* fck_PA = (const float*)d_in[2];
    const float* fck_Wa = (const float*)d_in[3];
    const float* fck_ba = (const float*)d_in[4];
    const float* fck_Wb = (const float*)d_in[5];
    const float* fck_bb = (const float*)d_in[6];
    const float* fck_Wd = (const float*)d_in[7];
    const float* fck_bd = (const float*)d_in[8];
    const float* fck_gamma = (const float*)d_in[9];
    const float* fck_beta = (const float*)d_in[10];
    const float* fcv_PA = (const float*)d_in[11];
    const float* fcv_Wa = (const float*)d_in[12];
    const float* fcv_ba = (const float*)d_in[13];
    const float* fcv_Wb = (const float*)d_in[14];
    const float* fcv_bb = (const float*)d_in[15];
    const float* fcv_Wd = (const float*)d_in[16];
    const float* fcv_bd = (const float*)d_in[17];
    const float* fcv_gamma = (const float*)d_in[18];
    const float* fcv_beta = (const float*)d_in[19];
    const float* fco_PA = (const float*)d_in[20];
    const float* fco_Wa = (const float*)d_in[21];
    const float* fco_ba = (const float*)d_in[22];
    const float* fco_Wb = (const float*)d_in[23];
    const float* fco_bb = (const float*)d_in[24];
    const float* fco_Wd = (const float*)d_in[25];
    const float* fco_bd = (const float*)d_in[26];
    const float* fco_gamma = (const float*)d_in[27];
    const float* fco_beta = (const float*)d_in[28];

    // Workspace map:
    //   [0, 32.768 MB)        Xbf (bf16 transposed K, by gcn_S3) — overwritten
    //                         IN PLACE by gcn_applyKV as Vg (stage-then-write).
    //   [32.768, 65.536)      Kg
    //   [65.536, 84.736)      Mpart (S3->reduce);  then O (attn->...) since O
    //   [65.536, 91.750)        spans this whole region; Sbf/Wdf below are
    //   [84.736, 87.882)      Sbf  (reduce->applyKV, dead before attn)
    //   [88.000, 88.197)      Wdf  (reduce->applyKV, dead before attn)
    //   [95.590 ..]           S3 (fco adjacency, fp32)
    char* wsb = (char*)d_ws;
    bf16* Xbf = (bf16*)(wsb);
    bf16* Vg = (bf16*)(wsb);                     // in-place over Xbf
    bf16* Kg = (bf16*)(wsb + 32768000);
    float* Mpart = (float*)(wsb + 65536000);     // [5][256][6][625] fp32 = 19.2 MB
    float* O = (float*)(wsb + 65536000);         // 26.2 MB, live after applyKV
    ushort* Sbf = (ushort*)(wsb + 84736000);     // [256][2][3][32][32] bf16 = 3.1 MB
    ushort* Wdf = (ushort*)(wsb + 88000000);     // [2][3][4][64][16] bf16 = 192 KB
    float* S3 = (float*)(wsb + 95590400);

    gcn_S3<<<dim3(BB * 5), dim3(256), 0, stream>>>(
        K, fck_Wa, fck_ba, fck_Wb, fck_bb,
        fcv_Wa, fcv_ba, fcv_Wb, fcv_bb, Xbf, Mpart);

    reduce_softmax<<<dim3(BB, 6), dim3(128), 0, stream>>>(
        Mpart, fck_PA, fcv_PA, fck_Wd, fcv_Wd, Sbf, Wdf);

    gcn_applyKV<<<dim3(BB, 10), dim3(256), 0, stream>>>(
        Xbf, Sbf, Wdf,
        fck_bd, fck_gamma, fck_beta,
        fcv_bd, fcv_gamma, fcv_beta, Kg, Vg);

    attn_kernel<<<dim3(BB, NH), dim3(256), 0, stream>>>(Q, Kg, Vg, O);

    gcn_S2<V2, 1><<<dim3(BB, 3), dim3(256), 0, stream>>>(
        O, fco_Wa, fco_ba, fco_Wb, fco_bb, fco_PA, S3,
        nullptr, nullptr, nullptr, nullptr, nullptr, nullptr);

    gcn_apply3<V2, 8, 1><<<dim3(BB, 5), dim3(256), 0, stream>>>(
        O, nullptr, S3, fco_Wd, fco_bd, fco_gamma, fco_beta, nullptr, (float*)d_out, O);
}

// Round 5
// 491.674 us; speedup vs baseline: 1.4770x; 1.0348x over previous
//
#include <hip/hip_runtime.h>
#include <hip/hip_bf16.h>

#define BB 256
#define CC 64
#define TT 40
#define DD 2560   // CC*TT
#define V1 25
#define V2 10
#define INTER 16
#define NH 8
#define DSH 320   // DD/NH
#define HSLAB 8000  // V1*TT*8 elems per (b,h) slab in head-major layout

typedef __hip_bfloat16 bf16;
typedef unsigned int uint;
typedef unsigned short ushort;
typedef __attribute__((ext_vector_type(8))) short bf16x8;
typedef __attribute__((ext_vector_type(4))) float f32x4;

__device__ __forceinline__ float b2f(bf16 x) { return __bfloat162float(x); }

__device__ __forceinline__ ushort f2bb(float f) {
    uint x = __float_as_uint(f);
    uint r = x + 0x7fffu + ((x >> 16) & 1u);
    return (ushort)(r >> 16);
}
__device__ __forceinline__ float blo(uint u) { return __uint_as_float(u << 16); }
__device__ __forceinline__ float bhi(uint u) { return __uint_as_float(u & 0xffff0000u); }
__device__ __forceinline__ float b2f_us(ushort h) { return __uint_as_float(((uint)h) << 16); }
__device__ __forceinline__ uint4 pack8(const float* a) {
    uint4 pk;
    pk.x = (uint)f2bb(a[0]) | ((uint)f2bb(a[1]) << 16);
    pk.y = (uint)f2bb(a[2]) | ((uint)f2bb(a[3]) << 16);
    pk.z = (uint)f2bb(a[4]) | ((uint)f2bb(a[5]) << 16);
    pk.w = (uint)f2bb(a[6]) | ((uint)f2bb(a[7]) << 16);
    return pk;
}
__device__ __forceinline__ bf16x8 ldfrag8(const ushort* p) {
    union { bf16x8 v; uint2 u[2]; } t;
    t.u[0] = *(const uint2*)p;
    t.u[1] = *(const uint2*)(p + 4);
    return t.v;
}

// LDS swizzle helpers (ushort index). 64-ushort (128B) rows, 16B-granule XOR
// by low row bits -> every vectorized access pattern hits its bank floor.
__device__ __forceinline__ int swz64(int row, int col) {
    return row * 64 + ((((col >> 3) ^ row) & 7) << 3) + (col & 7);
}
// xsC: 128-ushort (256B) rows, granule XOR by (c&15)
__device__ __forceinline__ int swzC(int c, int col) {
    return c * 128 + ((((col >> 3) ^ c) & 15) << 3) + (col & 7);
}

// ---------------------------------------------------------------------------
// gcn_S3 (V=25, fck+fcv fused): grid = (tc*256 + b), 1280 blocks.
// Per block: stage x chunk (8 t's of all v,c) once; EXPORT it as bf16 in
// HEAD-MAJOR layout Xbf[(b*8+h)*8000 + v*320 + t*8 + cl] (16B per (v,t,h),
// read/written at full-sector granularity by applyKV and attn);
// then for each subset s: proj MFMA + Gram MFMA -> Mpart.
// ---------------------------------------------------------------------------
__global__ __launch_bounds__(256) void gcn_S3(
    const float* __restrict__ X,
    const float* __restrict__ Wa0, const float* __restrict__ ba0,
    const float* __restrict__ Wb0, const float* __restrict__ bb0,
    const float* __restrict__ Wa1, const float* __restrict__ ba1,
    const float* __restrict__ Wb1, const float* __restrict__ bb1,
    bf16* __restrict__ Xw, float* __restrict__ Mpart) {
    __shared__ ushort xsT[208][72];    // [p=v*8+tl][c]; rows 200..207 garbage
    __shared__ ushort wT[64][72];      // [mat*16+j][c] for current s
    __shared__ ushort abT[4][32][136]; // [mat][v][j*8+tl]
    __shared__ float biasS[64];

    const int tid = threadIdx.x;
    const int b = blockIdx.x & 255, tc = blockIdx.x >> 8;
    const int t0 = tc * 8;
    const int lane = tid & 63, w = tid >> 6;
    const int ln = lane & 15, lq = lane >> 4;

    // stage x chunk: (v,c) -> 8 t's, bf16 into transposed rows p=v*8+tl
    const float* Xb = X + (size_t)b * V1 * DD;
    for (int e = tid; e < V1 * 64; e += 256) {
        const int v = e >> 6, c = e & 63;
        const float* src = Xb + (size_t)v * DD + c * TT + t0;
        const float4 f0 = *(const float4*)src;
        const float4 f1 = *(const float4*)(src + 4);
        const float tmp[8] = {f0.x, f0.y, f0.z, f0.w, f1.x, f1.y, f1.z, f1.w};
        #pragma unroll
        for (int tl = 0; tl < 8; ++tl) xsT[v * 8 + tl][c] = f2bb(tmp[tl]);
    }
    __syncthreads();                   // xsT complete

    // export head-major bf16 X: e -> (v, h, tl); lanes 0..7 cover tl=0..7
    // -> 128B contiguous global runs per (h,v). LDS reads conflict-free.
    for (int e = tid; e < 1600; e += 256) {
        const int v = e >> 6, h = (e >> 3) & 7, tl = e & 7;
        *(uint4*)(Xw + (size_t)(b * NH + h) * HSLAB + v * 320 + (t0 + tl) * 8) =
            *(const uint4*)&xsT[v * 8 + tl][h * 8];
    }

    for (int s = 0; s < 3; ++s) {
        if (s) __syncthreads();        // prev Gram done with abT, proj done with wT
        // stage W (4 mats x 16 x 64) + bias for this s
        for (int e = tid; e < 4096; e += 256) {
            const int mat = e >> 10, r = e & 1023;
            const float* Wp = (mat == 0) ? Wa0 : (mat == 1) ? Wb0 : (mat == 2) ? Wa1 : Wb1;
            wT[(mat << 4) + (r >> 6)][r & 63] = f2bb(Wp[s * 1024 + r]);
        }
        if (tid < 64) {
            const int mat = tid >> 4, j = tid & 15;
            const float* bp = (mat == 0) ? ba0 : (mat == 1) ? bb0 : (mat == 2) ? ba1 : bb1;
            biasS[tid] = bp[s * 16 + j];
        }
        __syncthreads();               // wT/xsT ready

        // ---- projection: wave w computes mat w over 13 n-tiles ----
        const bf16x8 a0 = *(const bf16x8*)&wT[w * 16 + ln][lq * 8];
        const bf16x8 a1 = *(const bf16x8*)&wT[w * 16 + ln][lq * 8 + 32];
        float br[4];
        #pragma unroll
        for (int r = 0; r < 4; ++r) br[r] = biasS[w * 16 + lq * 4 + r];
        for (int nt = 0; nt < 13; ++nt) {
            const bf16x8 b0 = *(const bf16x8*)&xsT[nt * 16 + ln][lq * 8];
            const bf16x8 b1 = *(const bf16x8*)&xsT[nt * 16 + ln][lq * 8 + 32];
            f32x4 acc = (f32x4){0.f, 0.f, 0.f, 0.f};
            acc = __builtin_amdgcn_mfma_f32_16x16x32_bf16(a0, b0, acc, 0, 0, 0);
            acc = __builtin_amdgcn_mfma_f32_16x16x32_bf16(a1, b1, acc, 0, 0, 0);
            const int p = nt * 16 + ln;
            if (p < 200) {
                const int v = p >> 3, tl = p & 7;
                #pragma unroll
                for (int r = 0; r < 4; ++r)
                    abT[w][v][(lq * 4 + r) * 8 + tl] = f2bb(acc[r] + br[r]);
            }
        }
        __syncthreads();               // abT ready

        // ---- Gram: 8 tile-units (np,mt,nt), wave w does units w and w+4 ----
        #pragma unroll
        for (int uu = 0; uu < 2; ++uu) {
            const int u = w + uu * 4;
            const int np = u >> 2, mt = (u >> 1) & 1, ntl = u & 1;
            const ushort* Ap = &abT[np * 2 + 0][mt * 16 + ln][lq * 8];
            const ushort* Bp = &abT[np * 2 + 1][ntl * 16 + ln][lq * 8];
            f32x4 g = (f32x4){0.f, 0.f, 0.f, 0.f};
            g = __builtin_amdgcn_mfma_f32_16x16x32_bf16(
                    *(const bf16x8*)Ap, *(const bf16x8*)Bp, g, 0, 0, 0);
            g = __builtin_amdgcn_mfma_f32_16x16x32_bf16(
                    *(const bf16x8*)(Ap + 32), *(const bf16x8*)(Bp + 32), g, 0, 0, 0);
            g = __builtin_amdgcn_mfma_f32_16x16x32_bf16(
                    *(const bf16x8*)(Ap + 64), *(const bf16x8*)(Bp + 64), g, 0, 0, 0);
            g = __builtin_amdgcn_mfma_f32_16x16x32_bf16(
                    *(const bf16x8*)(Ap + 96), *(const bf16x8*)(Bp + 96), g, 0, 0, 0);
            const int vp = ntl * 16 + ln;
            if (vp < V1) {
                float* Mb = Mpart + (((size_t)tc * 256 + b) * 6 + (s * 2 + np)) * 625;
                #pragma unroll
                for (int r = 0; r < 4; ++r) {
                    const int v = mt * 16 + lq * 4 + r;
                    if (v < V1) Mb[v * V1 + vp] = g[r];
                }
            }
        }
    }
}

// ---------------------------------------------------------------------------
// reduce_softmax: grid (b, snp=s*2+np), 128 threads. Sum 5 chunk-partials,
// column softmax over v (axis=-2), + PA, write Sbf (bf16 S^T, zero-padded
// to [b][g][s][32][32] -- exactly applyKV's SlT layout). Blocks with b==0
// additionally emit Wdf: Wd pre-converted bf16 in MFMA fragment order
// [g][s][w][lane][16] so applyKV reads A-frags straight from L2.
// ---------------------------------------------------------------------------
__global__ __launch_bounds__(128) void reduce_softmax(
    const float* __restrict__ Mpart,
    const float* __restrict__ PA0, const float* __restrict__ PA1,
    const float* __restrict__ WdK, const float* __restrict__ WdV,
    ushort* __restrict__ Sbf, ushort* __restrict__ Wdf) {
    __shared__ float Ms[625];
    const int tid = threadIdx.x, b = blockIdx.x, snp = blockIdx.y;
    const int s = snp >> 1, np = snp & 1;

    // Wdf prep (6 blocks only): fragment (w,lane) = rows w*16+ln, cols lq*8(+32)
    if (b == 0) {
        for (int e = tid; e < 256; e += 128) {
            const int wv = e >> 6, l = e & 63;
            const int lnn = l & 15, lqq = l >> 4;
            const float* Wp = (np ? WdV : WdK) + s * 4096 + (wv * 16 + lnn) * 64 + lqq * 8;
            ushort* dst = Wdf + (((np * 3 + s) * 4 + wv) * 64 + l) * 16;
            #pragma unroll
            for (int j = 0; j < 8; ++j) {
                dst[j] = f2bb(Wp[j]);
                dst[8 + j] = f2bb(Wp[32 + j]);
            }
        }
    }

    for (int e = tid; e < 625; e += 128) {
        float sum = 0.f;
        #pragma unroll
        for (int tcc = 0; tcc < 5; ++tcc)
            sum += Mpart[(((size_t)tcc * 256 + b) * 6 + snp) * 625 + e];
        Ms[e] = sum;
    }
    __syncthreads();
    if (tid < 32) {
        ushort* SbfRow = Sbf + ((((size_t)b * 2 + np) * 3 + s) << 10) + tid * 32;
        if (tid < V1) {
            const int vp = tid;
            const float invIT = 1.0f / 640.0f;
            float mx = -1e30f;
            for (int v = 0; v < V1; ++v) mx = fmaxf(mx, Ms[v * V1 + vp]);
            float sum = 0.f;
            for (int v = 0; v < V1; ++v) sum += expf((Ms[v * V1 + vp] - mx) * invIT);
            const float rs = 1.f / sum;
            const float* PAn = np ? PA1 : PA0;
            for (int v = 0; v < V1; ++v) {
                const float e_ = expf((Ms[v * V1 + vp] - mx) * invIT);
                SbfRow[v] = f2bb(e_ * rs + PAn[(s * V1 + v) * V1 + vp]);
            }
            for (int v = V1; v < 32; ++v) SbfRow[v] = 0;
        } else {
            for (int v = 0; v < 32; ++v) SbfRow[v] = 0;
        }
    }
}

// ---------------------------------------------------------------------------
// gcn_S2 (VALU version, kept for the small V=10 fco case).
// ---------------------------------------------------------------------------
template<int V, int NP>
__global__ __launch_bounds__(256) void gcn_S2(
    const float* __restrict__ X,
    const float* __restrict__ Wa0, const float* __restrict__ ba0,
    const float* __restrict__ Wb0, const float* __restrict__ bb0,
    const float* __restrict__ PA0, float* __restrict__ Sout0,
    const float* __restrict__ Wa1, const float* __restrict__ ba1,
    const float* __restrict__ Wb1, const float* __restrict__ bb1,
    const float* __restrict__ PA1, float* __restrict__ Sout1) {
    constexpr int TC = 8;
    constexpr int NCH = TT / TC;
    constexpr int P = V * TC;
    constexpr int ROWS = NP * 32;
    constexpr int NRQ = ROWS / 4;
    constexpr int NC8 = P / 8;
    constexpr int NTILE = NRQ * NC8;
    constexpr int NM = NP * V * V;
    constexpr int NMI = (NM + 255) / 256;

    __shared__ ushort xs[64][P];
    __shared__ ushort ab[ROWS][P];
    __shared__ ushort wT[64][ROWS];
    __shared__ float biasL[ROWS];
    __shared__ float M[NM];

    const int tid = threadIdx.x, b = blockIdx.x, s = blockIdx.y;

    for (int e = tid; e < 16 * 64; e += 256) {
        int c = e & 63;
        int j = e >> 6;
        wT[c][j]      = f2bb(Wa0[s * 1024 + e]);
        wT[c][16 + j] = f2bb(Wb0[s * 1024 + e]);
        if constexpr (NP == 2) {
            wT[c][32 + j] = f2bb(Wa1[s * 1024 + e]);
            wT[c][48 + j] = f2bb(Wb1[s * 1024 + e]);
        }
    }
    if (tid < 16) {
        biasL[tid]      = ba0[s * 16 + tid];
        biasL[16 + tid] = bb0[s * 16 + tid];
        if constexpr (NP == 2) {
            biasL[32 + tid] = ba1[s * 16 + tid];
            biasL[48 + tid] = bb1[s * 16 + tid];
        }
    }

    float macc[NMI];
    #pragma unroll
    for (int k = 0; k < NMI; ++k) macc[k] = 0.f;

    const float* Xb = X + (size_t)b * V * DD;
    for (int tc = 0; tc < NCH; ++tc) {
        const int t0 = tc * TC;
        for (int e = tid; e < V * 64; e += 256) {
            const int v = e >> 6, c = e & 63;
            const float* src = Xb + (size_t)v * DD + c * TT + t0;
            const float4 f0 = *(const float4*)src;
            const float4 f1 = *(const float4*)(src + 4);
            const float tmp[8] = {f0.x, f0.y, f0.z, f0.w, f1.x, f1.y, f1.z, f1.w};
            *(uint4*)&xs[c][v * 8] = pack8(tmp);
        }
        __syncthreads();
        for (int tau = tid; tau < NTILE; tau += 256) {
            const int rq = tau % NRQ, co = tau / NRQ;
            float acc[4][8];
            #pragma unroll
            for (int r = 0; r < 4; ++r) {
                const float bv = biasL[4 * rq + r];
                #pragma unroll
                for (int cc = 0; cc < 8; ++cc) acc[r][cc] = bv;
            }
            for (int c = 0; c < 64; ++c) {
                const uint2 wv = *(const uint2*)&wT[c][4 * rq];
                const uint4 xv = *(const uint4*)&xs[c][8 * co];
                const float w0 = blo(wv.x), w1 = bhi(wv.x);
                const float w2 = blo(wv.y), w3 = bhi(wv.y);
                const float x0 = blo(xv.x), x1 = bhi(xv.x);
                const float x2 = blo(xv.y), x3 = bhi(xv.y);
                const float x4 = blo(xv.z), x5 = bhi(xv.z);
                const float x6 = blo(xv.w), x7 = bhi(xv.w);
                acc[0][0] += w0 * x0; acc[0][1] += w0 * x1;
                acc[0][2] += w0 * x2; acc[0][3] += w0 * x3;
                acc[0][4] += w0 * x4; acc[0][5] += w0 * x5;
                acc[0][6] += w0 * x6; acc[0][7] += w0 * x7;
                acc[1][0] += w1 * x0; acc[1][1] += w1 * x1;
                acc[1][2] += w1 * x2; acc[1][3] += w1 * x3;
                acc[1][4] += w1 * x4; acc[1][5] += w1 * x5;
                acc[1][6] += w1 * x6; acc[1][7] += w1 * x7;
                acc[2][0] += w2 * x0; acc[2][1] += w2 * x1;
                acc[2][2] += w2 * x2; acc[2][3] += w2 * x3;
                acc[2][4] += w2 * x4; acc[2][5] += w2 * x5;
                acc[2][6] += w2 * x6; acc[2][7] += w2 * x7;
                acc[3][0] += w3 * x0; acc[3][1] += w3 * x1;
                acc[3][2] += w3 * x2; acc[3][3] += w3 * x3;
                acc[3][4] += w3 * x4; acc[3][5] += w3 * x5;
                acc[3][6] += w3 * x6; acc[3][7] += w3 * x7;
            }
            #pragma unroll
            for (int r = 0; r < 4; ++r)
                *(uint4*)&ab[4 * rq + r][8 * co] = pack8(acc[r]);
        }
        __syncthreads();
        #pragma unroll
        for (int k = 0; k < NMI; ++k) {
            const int idx = tid + k * 256;
            if (idx < NM) {
                const int np = idx / (V * V), r = idx % (V * V);
                const int v = r / V, vp = r % V;
                const int ra = np * 32, rb = np * 32 + 16;
                float mm = 0.f;
                #pragma unroll
                for (int j = 0; j < 16; ++j) {
                    const uint4 av = *(const uint4*)&ab[ra + j][v * 8];
                    const uint4 bv = *(const uint4*)&ab[rb + j][vp * 8];
                    mm += blo(av.x) * blo(bv.x) + bhi(av.x) * bhi(bv.x)
                        + blo(av.y) * blo(bv.y) + bhi(av.y) * bhi(bv.y)
                        + blo(av.z) * blo(bv.z) + bhi(av.z) * bhi(bv.z)
                        + blo(av.w) * blo(bv.w) + bhi(av.w) * bhi(bv.w);
                }
                macc[k] += mm;
            }
        }
    }

    #pragma unroll
    for (int k = 0; k < NMI; ++k) {
        const int idx = tid + k * 256;
        if (idx < NM) M[idx] = macc[k];
    }
    __syncthreads();

    const float invIT = 1.0f / 640.0f;
    if (tid < NP * V) {
        const int np = tid / V, vp = tid % V;
        const float* Mn = &M[np * V * V];
        float mx = -1e30f;
        for (int v = 0; v < V; ++v) mx = fmaxf(mx, Mn[v * V + vp]);
        float sum = 0.f;
        for (int v = 0; v < V; ++v) sum += expf((Mn[v * V + vp] - mx) * invIT);
        const float rs = 1.f / sum;
        const float* PAn = (np == 0) ? PA0 : PA1;
        float* Sn = (np == 0) ? Sout0 : Sout1;
        for (int v = 0; v < V; ++v) {
            const float e_ = expf((Mn[v * V + vp] - mx) * invIT);
            Sn[((size_t)(b * 3 + s) * V + v) * V + vp] =
                e_ * rs + PAn[(s * V + v) * V + vp];
        }
    }
}

// ---------------------------------------------------------------------------
// gcn_applyKV: fused fck+fcv apply for V=25, all-MFMA, minimal staging.
// Xbf/Kg/Vg all HEAD-MAJOR [(b*8+h)][v][t][8cl]. Vg overwrites Xbf in place:
// with identical layouts, block (b,chunk) writes exactly the addresses it
// staged (t-slice chunk*64B+tl*16B per (h,v)) -> chunk-disjoint, race-free.
// ---------------------------------------------------------------------------
__global__ __launch_bounds__(256) void gcn_applyKV(
    const bf16* __restrict__ Xbf,
    const ushort* __restrict__ Sbf, const ushort* __restrict__ Wdf,
    const float* __restrict__ bdK, const float* __restrict__ gK, const float* __restrict__ beK,
    const float* __restrict__ bdV, const float* __restrict__ gV, const float* __restrict__ beV,
    bf16* __restrict__ Kg, bf16* __restrict__ Vg) {

    __shared__ ushort xsT[100 * 64];   // [p=v*4+tl][c], swz64 (persist)
    __shared__ ushort SlTs[6144];      // [(g*3+s)*1024 + vp*32 + v0] (persist)
    __shared__ ushort uC[8192];        // xsC [c][tl*32+v0] swzC, then zsT [p][c] swz64
    __shared__ float bias6[6 * 64];    // bdsK,bdsV, sclK,sclV, betK,betV

    const int tid = threadIdx.x, b = blockIdx.x, chunk = blockIdx.y;
    const int lane = tid & 63, w = tid >> 6;
    const int ln = lane & 15, lq = lane >> 4;
    const int t0 = chunk * 4;

    if (tid < 64) {
        bias6[tid]       = bdK[tid] + bdK[64 + tid] + bdK[128 + tid];
        bias6[64 + tid]  = bdV[tid] + bdV[64 + tid] + bdV[128 + tid];
        bias6[128 + tid] = gK[tid] * rsqrtf(1.f + 1e-5f);
        bias6[192 + tid] = gV[tid] * rsqrtf(1.f + 1e-5f);
        bias6[256 + tid] = beK[tid];
        bias6[320 + tid] = beV[tid];
    }
    // stage xsT from head-major Xbf: e = h*128 + v*4 + tl, e < 1024 (BUGFIX:
    // full h=0..7 range), skip v>=25. Lanes 0..3 cover one 64B t-slice run.
    const bf16* Xb = Xbf + (size_t)b * NH * HSLAB;
    for (int e = tid; e < 1024; e += 256) {
        const int h = e >> 7, v = (e >> 2) & 31, tl = e & 3;
        if (v < V1)
            *(uint4*)&xsT[swz64(v * 4 + tl, h * 8)] =
                *(const uint4*)(Xb + (size_t)h * HSLAB + v * 320 + (t0 + tl) * 8);
    }
    // stage SlTs: straight uint4 copy of precomputed bf16 S^T
    {
        const ushort* Sb = Sbf + (size_t)b * 6144;
        for (int e = tid; e < 768; e += 256)
            ((uint4*)SlTs)[e] = ((const uint4*)Sb)[e];
    }
    __syncthreads();   // xsT + SlTs staged

    // LDS transpose xsT -> xsC[c][tl*32+v0] (zero-pad v0>=25)
    {
        const int c = lane, q = w;   // 64 lanes = one row each, conflict-free
        #pragma unroll
        for (int j = 0; j < 4; ++j) {
            ushort vals[8];
            #pragma unroll
            for (int i = 0; i < 8; ++i) {
                const int v0 = q * 8 + i;
                vals[i] = (v0 < V1) ? xsT[swz64(v0 * 4 + j, c)] : (ushort)0;
            }
            uint4 pk;
            pk.x = (uint)vals[0] | ((uint)vals[1] << 16);
            pk.y = (uint)vals[2] | ((uint)vals[3] << 16);
            pk.z = (uint)vals[4] | ((uint)vals[5] << 16);
            pk.w = (uint)vals[6] | ((uint)vals[7] << 16);
            *(uint4*)&uC[swzC(c, j * 32 + q * 8)] = pk;
        }
    }
    __syncthreads();   // xsC ready

    // A-frags for GEMM-1 (held in regs all kernel): wave w = c-tile
    bf16x8 aF[4];
    #pragma unroll
    for (int tl = 0; tl < 4; ++tl)
        aF[tl] = *(const bf16x8*)&uC[swzC(w * 16 + ln, tl * 32 + lq * 8)];
    __syncthreads();   // aF reads done -> uC becomes zsT

    for (int g = 0; g < 2; ++g) {
        f32x4 acc[7];
        #pragma unroll
        for (int tn = 0; tn < 7; ++tn) acc[tn] = (f32x4){0.f, 0.f, 0.f, 0.f};

        for (int s = 0; s < 3; ++s) {
            // prefetch Wd A-frags (L2-hit; latency hides under GEMM-1)
            const ushort* wp = Wdf + ((((g * 3 + s) * 4 + w) * 64 + lane) << 4);
            union { uint4 u; bf16x8 v; } ua, ub;
            ua.u = *(const uint4*)wp;
            ub.u = *(const uint4*)(wp + 8);

            if (g | s) __syncthreads();   // prior GEMM-2 / out-copy done with zsT

            // ---- GEMM-1 (MFMA): D[c][v] = sum_v0 X^T[c][v0] * S[v0][v] ----
            #pragma unroll
            for (int nt = 0; nt < 2; ++nt) {
                const bf16x8 bF =
                    *(const bf16x8*)&SlTs[((g * 3 + s) << 10) + (nt * 16 + ln) * 32 + lq * 8];
                const int v = nt * 16 + ln;
                #pragma unroll
                for (int tl = 0; tl < 4; ++tl) {
                    f32x4 d = (f32x4){0.f, 0.f, 0.f, 0.f};
                    d = __builtin_amdgcn_mfma_f32_16x16x32_bf16(aF[tl], bF, d, 0, 0, 0);
                    if (v < V1) {
                        uint2 pk;
                        pk.x = (uint)f2bb(d[0]) | ((uint)f2bb(d[1]) << 16);
                        pk.y = (uint)f2bb(d[2]) | ((uint)f2bb(d[3]) << 16);
                        *(uint2*)&uC[swz64(v * 4 + tl, w * 16 + lq * 4)] = pk;
                    }
                }
            }
            __syncthreads();   // zsT ready

            // ---- GEMM-2 (MFMA): acc[o][p] += Wd[o][c] * z[p][c] ----
            #pragma unroll
            for (int tn = 0; tn < 7; ++tn) {
                const bf16x8 b0 = *(const bf16x8*)&uC[swz64(tn * 16 + ln, lq * 8)];
                const bf16x8 b1 = *(const bf16x8*)&uC[swz64(tn * 16 + ln, lq * 8 + 32)];
                acc[tn] = __builtin_amdgcn_mfma_f32_16x16x32_bf16(ua.v, b0, acc[tn], 0, 0, 0);
                acc[tn] = __builtin_amdgcn_mfma_f32_16x16x32_bf16(ub.v, b1, acc[tn], 0, 0, 0);
            }
        }
        __syncthreads();   // GEMM-2 done reading zsT

        // ---- epilogue: BN + residual + relu -> zsT (bf16) ----
        {
            const int c0 = w * 16 + lq * 4;
            float bb[4], ss[4], be[4];
            #pragma unroll
            for (int r = 0; r < 4; ++r) {
                bb[r] = bias6[g * 64 + c0 + r];
                ss[r] = bias6[128 + g * 64 + c0 + r];
                be[r] = bias6[256 + g * 64 + c0 + r];
            }
            #pragma unroll
            for (int tn = 0; tn < 7; ++tn) {
                const int p = tn * 16 + ln;
                if (p < 100) {
                    const uint2 u = *(const uint2*)&xsT[swz64(p, c0)];
                    const float rs[4] = {blo(u.x), bhi(u.x), blo(u.y), bhi(u.y)};
                    float y[4];
                    #pragma unroll
                    for (int r = 0; r < 4; ++r)
                        y[r] = fmaxf((acc[tn][r] + bb[r]) * ss[r] + be[r] + rs[r], 0.f);
                    uint2 pk;
                    pk.x = (uint)f2bb(y[0]) | ((uint)f2bb(y[1]) << 16);
                    pk.y = (uint)f2bb(y[2]) | ((uint)f2bb(y[3]) << 16);
                    *(uint2*)&uC[swz64(p, c0)] = pk;
                }
            }
        }
        __syncthreads();

        // ---- head-major bf16 output: same addressing as staging (BUGFIX:
        // e < 1024 to cover all 8 heads) ----
        bf16* outp = (g ? Vg : Kg) + (size_t)b * NH * HSLAB;
        for (int e = tid; e < 1024; e += 256) {
            const int h = e >> 7, v = (e >> 2) & 31, tl = e & 3;
            if (v < V1)
                *(uint4*)(outp + (size_t)h * HSLAB + v * 320 + (t0 + tl) * 8) =
                    *(const uint4*)&uC[swz64(v * 4 + tl, h * 8)];
        }
    }
}

// ---------------------------------------------------------------------------
// gcn_apply3 (old template, kept ONLY for the V=10 fco case, MODE 1).
// ---------------------------------------------------------------------------
template<int V, int TC, int MODE>
__global__ __launch_bounds__(256) void gcn_apply3(const float* __restrict__ X,
                                                  const float* __restrict__ Sbuf,
                                                  const float* __restrict__ Wd,
                                                  const float* __restrict__ bd,
                                                  const float* __restrict__ gamma,
                                                  const float* __restrict__ beta,
                                                  float* __restrict__ out_f,
                                                  const float* __restrict__ Obuf) {
    constexpr int VSLOT = 128 / TC;
    constexpr int ROWS = V * TC;
    constexpr int NT = (V == 25) ? 7 : 5;

    __shared__ ushort xsT[ROWS][72];
    __shared__ ushort zsT[128][72];
    __shared__ ushort wdT[64][72];
    __shared__ ushort Sl[3][VSLOT][34];
    __shared__ float bds[64], scl[64], bet[64];

    const int tid = threadIdx.x, b = blockIdx.x, chunk = blockIdx.y;
    const int ci = tid >> 4, pj = tid & 15;
    const int lane = tid & 63, w = tid >> 6;
    const int ln = lane & 15, lq = lane >> 4;
    const int t0 = chunk * TC;

    for (int e = tid; e < 3 * VSLOT * 17; e += 256) ((uint*)Sl)[e] = 0u;
    if (tid < 64) {
        bds[tid] = bd[tid] + bd[64 + tid] + bd[128 + tid];
        scl[tid] = gamma[tid] * rsqrtf(1.f + 1e-5f);
        bet[tid] = beta[tid];
    }
    __syncthreads();
    for (int e = tid; e < 3 * V * V; e += 256) {
        int s = e / (V * V), r = e % (V * V);
        Sl[s][r / V][r % V] = f2bb(Sbuf[(size_t)b * 3 * V * V + e]);
    }
    {
        const float* Xb = X + (size_t)b * V * DD;
        for (int e = tid; e < V * 64 * TC; e += 256) {
            int v = e / (64 * TC), inner = e % (64 * TC);
            int c = inner / TC, tl = inner % TC;
            xsT[v * TC + tl][c] = f2bb(Xb[(size_t)v * DD + c * TT + t0 + tl]);
        }
    }
    __syncthreads();

    f32x4 acc[NT];
    #pragma unroll
    for (int tn = 0; tn < NT; ++tn) acc[tn] = (f32x4){0.f, 0.f, 0.f, 0.f};

    for (int s = 0; s < 3; ++s) {
        if (s) __syncthreads();
        for (int e = tid; e < 4096; e += 256)
            wdT[e >> 6][e & 63] = f2bb(Wd[s * 4096 + e]);

        float za[4][8];
        #pragma unroll
        for (int r = 0; r < 4; ++r)
            #pragma unroll
            for (int cc = 0; cc < 8; ++cc) za[r][cc] = 0.f;

        for (int v0 = 0; v0 < 10; ++v0) {
            const float sv = b2f_us(Sl[s][v0][pj]);
            #pragma unroll
            for (int tl = 0; tl < 8; ++tl) {
                const uint2 u = *(const uint2*)&xsT[v0 * 8 + tl][ci * 4];
                za[0][tl] += blo(u.x) * sv;
                za[1][tl] += bhi(u.x) * sv;
                za[2][tl] += blo(u.y) * sv;
                za[3][tl] += bhi(u.y) * sv;
            }
        }
        #pragma unroll
        for (int cc = 0; cc < 8; ++cc) {
            uint2 pk;
            pk.x = (uint)f2bb(za[0][cc]) | ((uint)f2bb(za[1][cc]) << 16);
            pk.y = (uint)f2bb(za[2][cc]) | ((uint)f2bb(za[3][cc]) << 16);
            *(uint2*)&zsT[pj * 8 + cc][ci * 4] = pk;
        }
        __syncthreads();

        const bf16x8 a0 = *(const bf16x8*)&wdT[w * 16 + ln][lq * 8];
        const bf16x8 a1 = *(const bf16x8*)&wdT[w * 16 + ln][lq * 8 + 32];
        #pragma unroll
        for (int tn = 0; tn < NT; ++tn) {
            const bf16x8 b0 = ldfrag8(&zsT[tn * 16 + ln][lq * 8]);
            const bf16x8 b1 = ldfrag8(&zsT[tn * 16 + ln][lq * 8 + 32]);
            acc[tn] = __builtin_amdgcn_mfma_f32_16x16x32_bf16(a0, b0, acc[tn], 0, 0, 0);
            acc[tn] = __builtin_amdgcn_mfma_f32_16x16x32_bf16(a1, b1, acc[tn], 0, 0, 0);
        }
    }

    __syncthreads();
    {
        const int c0 = w * 16 + lq * 4;
        float bb[4], ss[4], be[4];
        #pragma unroll
        for (int r = 0; r < 4; ++r) {
            bb[r] = bds[c0 + r]; ss[r] = scl[c0 + r]; be[r] = bet[c0 + r];
        }
        #pragma unroll
        for (int tn = 0; tn < NT; ++tn) {
            const int p = tn * 16 + ln;
            if (p < ROWS) {
                const uint2 u = *(const uint2*)&xsT[p][c0];
                const float rs[4] = {blo(u.x), bhi(u.x), blo(u.y), bhi(u.y)};
                float y[4];
                #pragma unroll
                for (int r = 0; r < 4; ++r)
                    y[r] = fmaxf((acc[tn][r] + bb[r]) * ss[r] + be[r] + rs[r], 0.f);
                uint2 pk;
                pk.x = (uint)f2bb(y[0]) | ((uint)f2bb(y[1]) << 16);
                pk.y = (uint)f2bb(y[2]) | ((uint)f2bb(y[3]) << 16);
                *(uint2*)&zsT[p][c0] = pk;
            }
        }
    }
    __syncthreads();

    {
        const int v = pj;
        if (v < V) {
            #pragma unroll
            for (int r = 0; r < 4; ++r) {
                const int c = ci * 4 + r;
                const size_t base = (size_t)b * V * DD + (size_t)v * DD + c * TT + t0;
                const float4 o0 = *(const float4*)&Obuf[base];
                const float4 o1 = *(const float4*)&Obuf[base + 4];
                float4 y0, y1;
                y0.x = o0.x + b2f_us(zsT[v * 8 + 0][c]);
                y0.y = o0.y + b2f_us(zsT[v * 8 + 1][c]);
                y0.z = o0.z + b2f_us(zsT[v * 8 + 2][c]);
                y0.w = o0.w + b2f_us(zsT[v * 8 + 3][c]);
                y1.x = o1.x + b2f_us(zsT[v * 8 + 4][c]);
                y1.y = o1.y + b2f_us(zsT[v * 8 + 5][c]);
                y1.z = o1.z + b2f_us(zsT[v * 8 + 6][c]);
                y1.w = o1.w + b2f_us(zsT[v * 8 + 7][c]);
                *(float4*)&out_f[base] = y0;
                *(float4*)&out_f[base + 4] = y1;
            }
        }
    }
}

// ---------------------------------------------------------------------------
// attention: Kg/Vg head-major -> each (b,h) block reads one contiguous 16KB
// slab for K and one for V (uint4-coalesced, zero fetch amplification).
// Single-pass V staging (ks buffer holds the full 320-d slice).
// ---------------------------------------------------------------------------
__global__ __launch_bounds__(256) void attn_kernel(const float* __restrict__ Q,
                                                   const bf16* __restrict__ Kg,
                                                   const bf16* __restrict__ Vg,
                                                   float* __restrict__ O) {
    int b = blockIdx.x, h = blockIdx.y, tid = threadIdx.x;
    __shared__ float qs[10 * DSH];
    __shared__ float ks[V1 * 321];
    __shared__ float att[10 * V1];
    const float* Qb = Q + (size_t)b * 10 * DD + h * DSH;
    for (int e = tid; e < 10 * DSH; e += 256) {
        int q = e / DSH, d = e % DSH;
        qs[e] = Qb[(size_t)q * DD + d];
    }
    // stage K slab (contiguous 16KB): ks[kk*321 + cl*40 + t]
    const bf16* Kb = Kg + (size_t)(b * NH + h) * HSLAB;
    for (int e = tid; e < V1 * TT; e += 256) {
        const int kk = e / TT, t = e % TT;
        const uint4 u = *(const uint4*)(Kb + (size_t)e * 8);
        const ushort* us = (const ushort*)&u;
        float* dst = &ks[kk * 321 + t];
        #pragma unroll
        for (int cl = 0; cl < 8; ++cl) dst[cl * 40] = b2f_us(us[cl]);
    }
    __syncthreads();
    const float scale = 0.019764235376052370f;  // 1/sqrt(2560)
    for (int e = tid; e < 10 * V1; e += 256) {
        int q = e / V1, kk = e % V1;
        float acc = 0.f;
        #pragma unroll 8
        for (int d = 0; d < DSH; ++d) acc += qs[q * DSH + d] * ks[kk * 321 + d];
        att[e] = acc * scale;
    }
    __syncthreads();   // QK done reading ks; att raw scores complete
    if (tid < 10) {
        float mx = -1e30f;
        for (int k = 0; k < V1; ++k) mx = fmaxf(mx, att[tid * V1 + k]);
        float sum = 0.f;
        for (int k = 0; k < V1; ++k) {
            float e_ = expf(att[tid * V1 + k] - mx);
            att[tid * V1 + k] = e_;
            sum += e_;
        }
        float r = 1.0f / sum;
        for (int k = 0; k < V1; ++k) att[tid * V1 + k] *= r;
    }
    // stage V slab (contiguous 16KB), overwriting ks; runs alongside softmax
    const bf16* Vb = Vg + (size_t)(b * NH + h) * HSLAB;
    for (int e = tid; e < V1 * TT; e += 256) {
        const int kk = e / TT, t = e % TT;
        const uint4 u = *(const uint4*)(Vb + (size_t)e * 8);
        const ushort* us = (const ushort*)&u;
        float* dst = &ks[kk * 321 + t];
        #pragma unroll
        for (int cl = 0; cl < 8; ++cl) dst[cl * 40] = b2f_us(us[cl]);
    }
    __syncthreads();   // att normalized + V staged
    float* Ob = O + (size_t)b * 10 * DD + h * DSH;
    for (int e = tid; e < 10 * DSH; e += 256) {
        int q = e / DSH, dl = e % DSH;
        float acc = 0.f;
        #pragma unroll
        for (int k = 0; k < V1; ++k) acc += att[q * V1 + k] * ks[k * 321 + dl];
        Ob[(size_t)q * DD + dl] = qs[e] + acc;
    }
}

// ---------------------------------------------------------------------------
extern "C" void kernel_launch(void* const* d_in, const int* in_sizes, int n_in,
                              void* d_out, int out_size, void* d_ws, size_t ws_size,
                              hipStream_t stream) {
    const float* Q = (const float*)d_in[0];
    const float* K = (const float*)d_in[1];
    const float* fck_PA = (const float*)d_in[2];
    const float* fck_Wa = (const float*)d_in[3];
    const float* fck_ba = (const float*)d_in[4];
    const float* fck_Wb = (const float*)d_in[5];
    const float* fck_bb = (const float*)d_in[6];
    const float* fck_Wd = (const float*)d_in[7];
    const float* fck_bd = (const float*)d_in[8];
    const float* fck_gamma = (const float*)d_in[9];
    const float* fck_beta = (const float*)d_in[10];
    const float* fcv_PA = (const float*)d_in[11];
    const float* fcv_Wa = (const float*)d_in[12];
    const float* fcv_ba = (const float*)d_in[13];
    const float* fcv_Wb = (const float*)d_in[14];
    const float* fcv_bb = (const float*)d_in[15];
    const float* fcv_Wd = (const float*)d_in[16];
    const float* fcv_bd = (const float*)d_in[17];
    const float* fcv_gamma = (const float*)d_in[18];
    const float* fcv_beta = (const float*)d_in[19];
    const float* fco_PA = (const float*)d_in[20];
    const float* fco_Wa = (const float*)d_in[21];
    const float* fco_ba = (const float*)d_in[22];
    const float* fco_Wb = (const float*)d_in[23];
    const float* fco_bb = (const float*)d_in[24];
    const float* fco_Wd = (const float*)d_in[25];
    const float* fco_bd = (const float*)d_in[26];
    const float* fco_gamma = (const float*)d_in[27];
    const float* fco_beta = (const float*)d_in[28];

    // Workspace map (unchanged):
    //   [0, 32.768 MB)        Xbf (head-major bf16 K, by gcn_S3) — overwritten
    //                         IN PLACE by gcn_applyKV as Vg (same addressing).
    //   [32.768, 65.536)      Kg (head-major)
    //   [65.536, 84.736)      Mpart (S3->reduce);  then O (attn->...)
    //   [65.536, 91.750)        O spans this region (disjoint lifetimes)
    //   [84.736, 87.882)      Sbf  (reduce->applyKV, dead before attn)
    //   [88.000, 88.197)      Wdf  (reduce->applyKV, dead before attn)
    //   [95.590 ..]           S3 (fco adjacency, fp32)
    char* wsb = (char*)d_ws;
    bf16* Xbf = (bf16*)(wsb);
    bf16* Vg = (bf16*)(wsb);                     // in-place over Xbf
    bf16* Kg = (bf16*)(wsb + 32768000);
    float* Mpart = (float*)(wsb + 65536000);     // [5][256][6][625] fp32 = 19.2 MB
    float* O = (float*)(wsb + 65536000);         // 26.2 MB, live after applyKV
    ushort* Sbf = (ushort*)(wsb + 84736000);     // [256][2][3][32][32] bf16 = 3.1 MB
    ushort* Wdf = (ushort*)(wsb + 88000000);     // [2][3][4][64][16] bf16 = 192 KB
    float* S3 = (float*)(wsb + 95590400);

    gcn_S3<<<dim3(BB * 5), dim3(256), 0, stream>>>(
        K, fck_Wa, fck_ba, fck_Wb, fck_bb,
        fcv_Wa, fcv_ba, fcv_Wb, fcv_bb, Xbf, Mpart);

    reduce_softmax<<<dim3(BB, 6), dim3(128), 0, stream>>>(
        Mpart, fck_PA, fcv_PA, fck_Wd, fcv_Wd, Sbf, Wdf);

    gcn_applyKV<<<dim3(BB, 10), dim3(256), 0, stream>>>(
        Xbf, Sbf, Wdf,
        fck_bd, fck_gamma, fck_beta,
        fcv_bd, fcv_gamma, fcv_beta, Kg, Vg);

    attn_kernel<<<dim3(BB, NH), dim3(256), 0, stream>>>(Q, Kg, Vg, O);

    gcn_S2<V2, 1><<<dim3(BB, 3), dim3(256), 0, stream>>>(
        O, fco_Wa, fco_ba, fco_Wb, fco_bb, fco_PA, S3,
        nullptr, nullptr, nullptr, nullptr, nullptr, nullptr);

    gcn_apply3<V2, 8, 1><<<dim3(BB, 5), dim3(256), 0, stream>>>(
        O, S3, fco_Wd, fco_bd, fco_gamma, fco_beta, (float*)d_out, O);
}

// Round 6
// 466.291 us; speedup vs baseline: 1.5574x; 1.0544x over previous
//
#include <hip/hip_runtime.h>
#include <hip/hip_bf16.h>

#define BB 256
#define CC 64
#define TT 40
#define DD 2560   // CC*TT
#define V1 25
#define V2 10
#define INTER 16
#define NH 8
#define DSH 320   // DD/NH
#define HSLAB 8000  // V1*TT*8 elems per (b,h) slab in head-major layout

typedef __hip_bfloat16 bf16;
typedef unsigned int uint;
typedef unsigned short ushort;
typedef __attribute__((ext_vector_type(8))) short bf16x8;
typedef __attribute__((ext_vector_type(4))) float f32x4;

__device__ __forceinline__ float b2f(bf16 x) { return __bfloat162float(x); }

__device__ __forceinline__ ushort f2bb(float f) {
    uint x = __float_as_uint(f);
    uint r = x + 0x7fffu + ((x >> 16) & 1u);
    return (ushort)(r >> 16);
}
__device__ __forceinline__ float blo(uint u) { return __uint_as_float(u << 16); }
__device__ __forceinline__ float bhi(uint u) { return __uint_as_float(u & 0xffff0000u); }
__device__ __forceinline__ float b2f_us(ushort h) { return __uint_as_float(((uint)h) << 16); }
__device__ __forceinline__ uint4 pack8(const float* a) {
    uint4 pk;
    pk.x = (uint)f2bb(a[0]) | ((uint)f2bb(a[1]) << 16);
    pk.y = (uint)f2bb(a[2]) | ((uint)f2bb(a[3]) << 16);
    pk.z = (uint)f2bb(a[4]) | ((uint)f2bb(a[5]) << 16);
    pk.w = (uint)f2bb(a[6]) | ((uint)f2bb(a[7]) << 16);
    return pk;
}

// LDS swizzle helpers (ushort index). 64-ushort (128B) rows, 16B-granule XOR
// by low row bits -> every vectorized access pattern hits its bank floor.
__device__ __forceinline__ int swz64(int row, int col) {
    return row * 64 + ((((col >> 3) ^ row) & 7) << 3) + (col & 7);
}
// 128-ushort (256B) rows, granule XOR by (c&15)
__device__ __forceinline__ int swzC(int c, int col) {
    return c * 128 + ((((col >> 3) ^ c) & 15) << 3) + (col & 7);
}

// ---------------------------------------------------------------------------
// gcn_S3 (V=25, fck+fcv fused): grid = (tc*256 + b), 1280 blocks.
// Per block: stage x chunk once; EXPORT head-major bf16 Xbf; then per subset:
// proj MFMA + Gram MFMA -> Mpart.
// ---------------------------------------------------------------------------
__global__ __launch_bounds__(256) void gcn_S3(
    const float* __restrict__ X,
    const float* __restrict__ Wa0, const float* __restrict__ ba0,
    const float* __restrict__ Wb0, const float* __restrict__ bb0,
    const float* __restrict__ Wa1, const float* __restrict__ ba1,
    const float* __restrict__ Wb1, const float* __restrict__ bb1,
    bf16* __restrict__ Xw, float* __restrict__ Mpart) {
    __shared__ ushort xsT[208][72];    // [p=v*8+tl][c]; rows 200..207 garbage
    __shared__ ushort wT[64][72];      // [mat*16+j][c] for current s
    __shared__ ushort abT[4][32][136]; // [mat][v][j*8+tl]
    __shared__ float biasS[64];

    const int tid = threadIdx.x;
    const int b = blockIdx.x & 255, tc = blockIdx.x >> 8;
    const int t0 = tc * 8;
    const int lane = tid & 63, w = tid >> 6;
    const int ln = lane & 15, lq = lane >> 4;

    // stage x chunk: (v,c) -> 8 t's, bf16 into transposed rows p=v*8+tl
    const float* Xb = X + (size_t)b * V1 * DD;
    for (int e = tid; e < V1 * 64; e += 256) {
        const int v = e >> 6, c = e & 63;
        const float* src = Xb + (size_t)v * DD + c * TT + t0;
        const float4 f0 = *(const float4*)src;
        const float4 f1 = *(const float4*)(src + 4);
        const float tmp[8] = {f0.x, f0.y, f0.z, f0.w, f1.x, f1.y, f1.z, f1.w};
        #pragma unroll
        for (int tl = 0; tl < 8; ++tl) xsT[v * 8 + tl][c] = f2bb(tmp[tl]);
    }
    __syncthreads();                   // xsT complete

    // export head-major bf16 X: e -> (v, h, tl)
    for (int e = tid; e < 1600; e += 256) {
        const int v = e >> 6, h = (e >> 3) & 7, tl = e & 7;
        *(uint4*)(Xw + (size_t)(b * NH + h) * HSLAB + v * 320 + (t0 + tl) * 8) =
            *(const uint4*)&xsT[v * 8 + tl][h * 8];
    }

    for (int s = 0; s < 3; ++s) {
        if (s) __syncthreads();        // prev Gram done with abT, proj done with wT
        for (int e = tid; e < 4096; e += 256) {
            const int mat = e >> 10, r = e & 1023;
            const float* Wp = (mat == 0) ? Wa0 : (mat == 1) ? Wb0 : (mat == 2) ? Wa1 : Wb1;
            wT[(mat << 4) + (r >> 6)][r & 63] = f2bb(Wp[s * 1024 + r]);
        }
        if (tid < 64) {
            const int mat = tid >> 4, j = tid & 15;
            const float* bp = (mat == 0) ? ba0 : (mat == 1) ? bb0 : (mat == 2) ? ba1 : bb1;
            biasS[tid] = bp[s * 16 + j];
        }
        __syncthreads();               // wT/xsT ready

        // ---- projection: wave w computes mat w over 13 n-tiles ----
        const bf16x8 a0 = *(const bf16x8*)&wT[w * 16 + ln][lq * 8];
        const bf16x8 a1 = *(const bf16x8*)&wT[w * 16 + ln][lq * 8 + 32];
        float br[4];
        #pragma unroll
        for (int r = 0; r < 4; ++r) br[r] = biasS[w * 16 + lq * 4 + r];
        for (int nt = 0; nt < 13; ++nt) {
            const bf16x8 b0 = *(const bf16x8*)&xsT[nt * 16 + ln][lq * 8];
            const bf16x8 b1 = *(const bf16x8*)&xsT[nt * 16 + ln][lq * 8 + 32];
            f32x4 acc = (f32x4){0.f, 0.f, 0.f, 0.f};
            acc = __builtin_amdgcn_mfma_f32_16x16x32_bf16(a0, b0, acc, 0, 0, 0);
            acc = __builtin_amdgcn_mfma_f32_16x16x32_bf16(a1, b1, acc, 0, 0, 0);
            const int p = nt * 16 + ln;
            if (p < 200) {
                const int v = p >> 3, tl = p & 7;
                #pragma unroll
                for (int r = 0; r < 4; ++r)
                    abT[w][v][(lq * 4 + r) * 8 + tl] = f2bb(acc[r] + br[r]);
            }
        }
        __syncthreads();               // abT ready

        // ---- Gram: 8 tile-units (np,mt,nt), wave w does units w and w+4 ----
        #pragma unroll
        for (int uu = 0; uu < 2; ++uu) {
            const int u = w + uu * 4;
            const int np = u >> 2, mt = (u >> 1) & 1, ntl = u & 1;
            const ushort* Ap = &abT[np * 2 + 0][mt * 16 + ln][lq * 8];
            const ushort* Bp = &abT[np * 2 + 1][ntl * 16 + ln][lq * 8];
            f32x4 g = (f32x4){0.f, 0.f, 0.f, 0.f};
            g = __builtin_amdgcn_mfma_f32_16x16x32_bf16(
                    *(const bf16x8*)Ap, *(const bf16x8*)Bp, g, 0, 0, 0);
            g = __builtin_amdgcn_mfma_f32_16x16x32_bf16(
                    *(const bf16x8*)(Ap + 32), *(const bf16x8*)(Bp + 32), g, 0, 0, 0);
            g = __builtin_amdgcn_mfma_f32_16x16x32_bf16(
                    *(const bf16x8*)(Ap + 64), *(const bf16x8*)(Bp + 64), g, 0, 0, 0);
            g = __builtin_amdgcn_mfma_f32_16x16x32_bf16(
                    *(const bf16x8*)(Ap + 96), *(const bf16x8*)(Bp + 96), g, 0, 0, 0);
            const int vp = ntl * 16 + ln;
            if (vp < V1) {
                float* Mb = Mpart + (((size_t)tc * 256 + b) * 6 + (s * 2 + np)) * 625;
                #pragma unroll
                for (int r = 0; r < 4; ++r) {
                    const int v = mt * 16 + lq * 4 + r;
                    if (v < V1) Mb[v * V1 + vp] = g[r];
                }
            }
        }
    }
}

// ---------------------------------------------------------------------------
// reduce_softmax: sum 5 chunk-partials, column softmax, + PA, write Sbf
// (bf16 S^T zero-padded [b][g][s][32][32]). b==0 blocks emit Wdf (fck/fcv Wd
// pre-converted bf16 in MFMA fragment order [g][s][w][lane][16]).
// ---------------------------------------------------------------------------
__global__ __launch_bounds__(128) void reduce_softmax(
    const float* __restrict__ Mpart,
    const float* __restrict__ PA0, const float* __restrict__ PA1,
    const float* __restrict__ WdK, const float* __restrict__ WdV,
    ushort* __restrict__ Sbf, ushort* __restrict__ Wdf) {
    __shared__ float Ms[625];
    const int tid = threadIdx.x, b = blockIdx.x, snp = blockIdx.y;
    const int s = snp >> 1, np = snp & 1;

    if (b == 0) {
        for (int e = tid; e < 256; e += 128) {
            const int wv = e >> 6, l = e & 63;
            const int lnn = l & 15, lqq = l >> 4;
            const float* Wp = (np ? WdV : WdK) + s * 4096 + (wv * 16 + lnn) * 64 + lqq * 8;
            ushort* dst = Wdf + (((np * 3 + s) * 4 + wv) * 64 + l) * 16;
            #pragma unroll
            for (int j = 0; j < 8; ++j) {
                dst[j] = f2bb(Wp[j]);
                dst[8 + j] = f2bb(Wp[32 + j]);
            }
        }
    }

    for (int e = tid; e < 625; e += 128) {
        float sum = 0.f;
        #pragma unroll
        for (int tcc = 0; tcc < 5; ++tcc)
            sum += Mpart[(((size_t)tcc * 256 + b) * 6 + snp) * 625 + e];
        Ms[e] = sum;
    }
    __syncthreads();
    if (tid < 32) {
        ushort* SbfRow = Sbf + ((((size_t)b * 2 + np) * 3 + s) << 10) + tid * 32;
        if (tid < V1) {
            const int vp = tid;
            const float invIT = 1.0f / 640.0f;
            float mx = -1e30f;
            for (int v = 0; v < V1; ++v) mx = fmaxf(mx, Ms[v * V1 + vp]);
            float sum = 0.f;
            for (int v = 0; v < V1; ++v) sum += expf((Ms[v * V1 + vp] - mx) * invIT);
            const float rs = 1.f / sum;
            const float* PAn = np ? PA1 : PA0;
            for (int v = 0; v < V1; ++v) {
                const float e_ = expf((Ms[v * V1 + vp] - mx) * invIT);
                SbfRow[v] = f2bb(e_ * rs + PAn[(s * V1 + v) * V1 + vp]);
            }
            for (int v = V1; v < 32; ++v) SbfRow[v] = 0;
        } else {
            for (int v = 0; v < 32; ++v) SbfRow[v] = 0;
        }
    }
}

// ---------------------------------------------------------------------------
// gcn_S2O (V=10 fco): VALU Gram as before; softmax tail writes SbfO (bf16
// S^T zero-padded [b][3][16][16]); b==0 blocks emit Wdf3 (fco_Wd bf16 in
// MFMA fragment order [s][w][lane][16]).
// ---------------------------------------------------------------------------
__global__ __launch_bounds__(256) void gcn_S2O(
    const float* __restrict__ X,
    const float* __restrict__ Wa0, const float* __restrict__ ba0,
    const float* __restrict__ Wb0, const float* __restrict__ bb0,
    const float* __restrict__ PA0, const float* __restrict__ WdO,
    ushort* __restrict__ SbfO, ushort* __restrict__ Wdf3) {
    constexpr int V = V2;      // 10
    constexpr int P = 80;      // V*8
    __shared__ ushort xs[64][P];
    __shared__ ushort ab[32][P];
    __shared__ ushort wT[64][32];
    __shared__ float biasL[32];
    __shared__ float M[100];

    const int tid = threadIdx.x, b = blockIdx.x, s = blockIdx.y;

    if (b == 0) {   // Wdf3 prep (3 blocks, one per s)
        const int e = tid;
        if (e < 256) {
            const int wv = e >> 6, l = e & 63;
            const int lnn = l & 15, lqq = l >> 4;
            const float* Wp = WdO + s * 4096 + (wv * 16 + lnn) * 64 + lqq * 8;
            ushort* dst = Wdf3 + (((s * 4 + wv) * 64 + l) << 4);
            #pragma unroll
            for (int j = 0; j < 8; ++j) {
                dst[j] = f2bb(Wp[j]);
                dst[8 + j] = f2bb(Wp[32 + j]);
            }
        }
    }

    for (int e = tid; e < 16 * 64; e += 256) {
        int c = e & 63, j = e >> 6;
        wT[c][j]      = f2bb(Wa0[s * 1024 + e]);
        wT[c][16 + j] = f2bb(Wb0[s * 1024 + e]);
    }
    if (tid < 16) {
        biasL[tid]      = ba0[s * 16 + tid];
        biasL[16 + tid] = bb0[s * 16 + tid];
    }

    float macc = 0.f;

    const float* Xb = X + (size_t)b * V * DD;
    for (int tc = 0; tc < 5; ++tc) {
        const int t0 = tc * 8;
        for (int e = tid; e < V * 64; e += 256) {
            const int v = e >> 6, c = e & 63;
            const float* src = Xb + (size_t)v * DD + c * TT + t0;
            const float4 f0 = *(const float4*)src;
            const float4 f1 = *(const float4*)(src + 4);
            const float tmp[8] = {f0.x, f0.y, f0.z, f0.w, f1.x, f1.y, f1.z, f1.w};
            *(uint4*)&xs[c][v * 8] = pack8(tmp);
        }
        __syncthreads();
        for (int tau = tid; tau < 80; tau += 256) {
            const int rq = tau % 8, co = tau / 8;
            float acc[4][8];
            #pragma unroll
            for (int r = 0; r < 4; ++r) {
                const float bv = biasL[4 * rq + r];
                #pragma unroll
                for (int cc = 0; cc < 8; ++cc) acc[r][cc] = bv;
            }
            for (int c = 0; c < 64; ++c) {
                const uint2 wv = *(const uint2*)&wT[c][4 * rq];
                const uint4 xv = *(const uint4*)&xs[c][8 * co];
                const float w0 = blo(wv.x), w1 = bhi(wv.x);
                const float w2 = blo(wv.y), w3 = bhi(wv.y);
                const float x0 = blo(xv.x), x1 = bhi(xv.x);
                const float x2 = blo(xv.y), x3 = bhi(xv.y);
                const float x4 = blo(xv.z), x5 = bhi(xv.z);
                const float x6 = blo(xv.w), x7 = bhi(xv.w);
                acc[0][0] += w0 * x0; acc[0][1] += w0 * x1;
                acc[0][2] += w0 * x2; acc[0][3] += w0 * x3;
                acc[0][4] += w0 * x4; acc[0][5] += w0 * x5;
                acc[0][6] += w0 * x6; acc[0][7] += w0 * x7;
                acc[1][0] += w1 * x0; acc[1][1] += w1 * x1;
                acc[1][2] += w1 * x2; acc[1][3] += w1 * x3;
                acc[1][4] += w1 * x4; acc[1][5] += w1 * x5;
                acc[1][6] += w1 * x6; acc[1][7] += w1 * x7;
                acc[2][0] += w2 * x0; acc[2][1] += w2 * x1;
                acc[2][2] += w2 * x2; acc[2][3] += w2 * x3;
                acc[2][4] += w2 * x4; acc[2][5] += w2 * x5;
                acc[2][6] += w2 * x6; acc[2][7] += w2 * x7;
                acc[3][0] += w3 * x0; acc[3][1] += w3 * x1;
                acc[3][2] += w3 * x2; acc[3][3] += w3 * x3;
                acc[3][4] += w3 * x4; acc[3][5] += w3 * x5;
                acc[3][6] += w3 * x6; acc[3][7] += w3 * x7;
            }
            #pragma unroll
            for (int r = 0; r < 4; ++r)
                *(uint4*)&ab[4 * rq + r][8 * co] = pack8(acc[r]);
        }
        __syncthreads();
        if (tid < 100) {
            const int v = tid / V, vp = tid % V;
            float mm = 0.f;
            #pragma unroll
            for (int j = 0; j < 16; ++j) {
                const uint4 av = *(const uint4*)&ab[j][v * 8];
                const uint4 bv = *(const uint4*)&ab[16 + j][vp * 8];
                mm += blo(av.x) * blo(bv.x) + bhi(av.x) * bhi(bv.x)
                    + blo(av.y) * blo(bv.y) + bhi(av.y) * bhi(bv.y)
                    + blo(av.z) * blo(bv.z) + bhi(av.z) * bhi(bv.z)
                    + blo(av.w) * blo(bv.w) + bhi(av.w) * bhi(bv.w);
            }
            macc += mm;
        }
    }

    if (tid < 100) M[tid] = macc;
    __syncthreads();

    const float invIT = 1.0f / 640.0f;
    if (tid < 16) {
        ushort* So = SbfO + ((size_t)b * 3 + s) * 256 + tid * 16;
        if (tid < V) {
            const int vp = tid;
            float mx = -1e30f;
            for (int v = 0; v < V; ++v) mx = fmaxf(mx, M[v * V + vp]);
            float sum = 0.f;
            for (int v = 0; v < V; ++v) sum += expf((M[v * V + vp] - mx) * invIT);
            const float rs = 1.f / sum;
            for (int v = 0; v < V; ++v) {
                const float e_ = expf((M[v * V + vp] - mx) * invIT);
                So[v] = f2bb(e_ * rs + PA0[(s * V + v) * V + vp]);
            }
            for (int v = V; v < 16; ++v) So[v] = 0;
        } else {
            for (int v = 0; v < 16; ++v) So[v] = 0;
        }
    }
}

// ---------------------------------------------------------------------------
// gcn_applyKV: fused fck+fcv apply for V=25, all-MFMA (unchanged, verified).
// ---------------------------------------------------------------------------
__global__ __launch_bounds__(256) void gcn_applyKV(
    const bf16* __restrict__ Xbf,
    const ushort* __restrict__ Sbf, const ushort* __restrict__ Wdf,
    const float* __restrict__ bdK, const float* __restrict__ gK, const float* __restrict__ beK,
    const float* __restrict__ bdV, const float* __restrict__ gV, const float* __restrict__ beV,
    bf16* __restrict__ Kg, bf16* __restrict__ Vg) {

    __shared__ ushort xsT[100 * 64];   // [p=v*4+tl][c], swz64 (persist)
    __shared__ ushort SlTs[6144];      // [(g*3+s)*1024 + vp*32 + v0] (persist)
    __shared__ ushort uC[8192];        // xsC [c][tl*32+v0] swzC, then zsT [p][c] swz64
    __shared__ float bias6[6 * 64];

    const int tid = threadIdx.x, b = blockIdx.x, chunk = blockIdx.y;
    const int lane = tid & 63, w = tid >> 6;
    const int ln = lane & 15, lq = lane >> 4;
    const int t0 = chunk * 4;

    if (tid < 64) {
        bias6[tid]       = bdK[tid] + bdK[64 + tid] + bdK[128 + tid];
        bias6[64 + tid]  = bdV[tid] + bdV[64 + tid] + bdV[128 + tid];
        bias6[128 + tid] = gK[tid] * rsqrtf(1.f + 1e-5f);
        bias6[192 + tid] = gV[tid] * rsqrtf(1.f + 1e-5f);
        bias6[256 + tid] = beK[tid];
        bias6[320 + tid] = beV[tid];
    }
    const bf16* Xb = Xbf + (size_t)b * NH * HSLAB;
    for (int e = tid; e < 1024; e += 256) {
        const int h = e >> 7, v = (e >> 2) & 31, tl = e & 3;
        if (v < V1)
            *(uint4*)&xsT[swz64(v * 4 + tl, h * 8)] =
                *(const uint4*)(Xb + (size_t)h * HSLAB + v * 320 + (t0 + tl) * 8);
    }
    {
        const ushort* Sb = Sbf + (size_t)b * 6144;
        for (int e = tid; e < 768; e += 256)
            ((uint4*)SlTs)[e] = ((const uint4*)Sb)[e];
    }
    __syncthreads();   // xsT + SlTs staged

    {
        const int c = lane, q = w;
        #pragma unroll
        for (int j = 0; j < 4; ++j) {
            ushort vals[8];
            #pragma unroll
            for (int i = 0; i < 8; ++i) {
                const int v0 = q * 8 + i;
                vals[i] = (v0 < V1) ? xsT[swz64(v0 * 4 + j, c)] : (ushort)0;
            }
            uint4 pk;
            pk.x = (uint)vals[0] | ((uint)vals[1] << 16);
            pk.y = (uint)vals[2] | ((uint)vals[3] << 16);
            pk.z = (uint)vals[4] | ((uint)vals[5] << 16);
            pk.w = (uint)vals[6] | ((uint)vals[7] << 16);
            *(uint4*)&uC[swzC(c, j * 32 + q * 8)] = pk;
        }
    }
    __syncthreads();   // xsC ready

    bf16x8 aF[4];
    #pragma unroll
    for (int tl = 0; tl < 4; ++tl)
        aF[tl] = *(const bf16x8*)&uC[swzC(w * 16 + ln, tl * 32 + lq * 8)];
    __syncthreads();   // aF reads done -> uC becomes zsT

    for (int g = 0; g < 2; ++g) {
        f32x4 acc[7];
        #pragma unroll
        for (int tn = 0; tn < 7; ++tn) acc[tn] = (f32x4){0.f, 0.f, 0.f, 0.f};

        for (int s = 0; s < 3; ++s) {
            const ushort* wp = Wdf + ((((g * 3 + s) * 4 + w) * 64 + lane) << 4);
            union { uint4 u; bf16x8 v; } ua, ub;
            ua.u = *(const uint4*)wp;
            ub.u = *(const uint4*)(wp + 8);

            if (g | s) __syncthreads();

            #pragma unroll
            for (int nt = 0; nt < 2; ++nt) {
                const bf16x8 bF =
                    *(const bf16x8*)&SlTs[((g * 3 + s) << 10) + (nt * 16 + ln) * 32 + lq * 8];
                const int v = nt * 16 + ln;
                #pragma unroll
                for (int tl = 0; tl < 4; ++tl) {
                    f32x4 d = (f32x4){0.f, 0.f, 0.f, 0.f};
                    d = __builtin_amdgcn_mfma_f32_16x16x32_bf16(aF[tl], bF, d, 0, 0, 0);
                    if (v < V1) {
                        uint2 pk;
                        pk.x = (uint)f2bb(d[0]) | ((uint)f2bb(d[1]) << 16);
                        pk.y = (uint)f2bb(d[2]) | ((uint)f2bb(d[3]) << 16);
                        *(uint2*)&uC[swz64(v * 4 + tl, w * 16 + lq * 4)] = pk;
                    }
                }
            }
            __syncthreads();   // zsT ready

            #pragma unroll
            for (int tn = 0; tn < 7; ++tn) {
                const bf16x8 b0 = *(const bf16x8*)&uC[swz64(tn * 16 + ln, lq * 8)];
                const bf16x8 b1 = *(const bf16x8*)&uC[swz64(tn * 16 + ln, lq * 8 + 32)];
                acc[tn] = __builtin_amdgcn_mfma_f32_16x16x32_bf16(ua.v, b0, acc[tn], 0, 0, 0);
                acc[tn] = __builtin_amdgcn_mfma_f32_16x16x32_bf16(ub.v, b1, acc[tn], 0, 0, 0);
            }
        }
        __syncthreads();   // GEMM-2 done reading zsT

        {
            const int c0 = w * 16 + lq * 4;
            float bb[4], ss[4], be[4];
            #pragma unroll
            for (int r = 0; r < 4; ++r) {
                bb[r] = bias6[g * 64 + c0 + r];
                ss[r] = bias6[128 + g * 64 + c0 + r];
                be[r] = bias6[256 + g * 64 + c0 + r];
            }
            #pragma unroll
            for (int tn = 0; tn < 7; ++tn) {
                const int p = tn * 16 + ln;
                if (p < 100) {
                    const uint2 u = *(const uint2*)&xsT[swz64(p, c0)];
                    const float rs[4] = {blo(u.x), bhi(u.x), blo(u.y), bhi(u.y)};
                    float y[4];
                    #pragma unroll
                    for (int r = 0; r < 4; ++r)
                        y[r] = fmaxf((acc[tn][r] + bb[r]) * ss[r] + be[r] + rs[r], 0.f);
                    uint2 pk;
                    pk.x = (uint)f2bb(y[0]) | ((uint)f2bb(y[1]) << 16);
                    pk.y = (uint)f2bb(y[2]) | ((uint)f2bb(y[3]) << 16);
                    *(uint2*)&uC[swz64(p, c0)] = pk;
                }
            }
        }
        __syncthreads();

        bf16* outp = (g ? Vg : Kg) + (size_t)b * NH * HSLAB;
        for (int e = tid; e < 1024; e += 256) {
            const int h = e >> 7, v = (e >> 2) & 31, tl = e & 3;
            if (v < V1)
                *(uint4*)(outp + (size_t)h * HSLAB + v * 320 + (t0 + tl) * 8) =
                    *(const uint4*)&uC[swz64(v * 4 + tl, h * 8)];
        }
    }
}

// ---------------------------------------------------------------------------
// gcn_applyO: fco apply (V=10), all-MFMA, applyKV-style. grid (256 b, 5 tc).
// GEMM-1: K = v0 padded 10->32; k>=16 operand halves are register zeros
// (lq<2 select), so xsC16/SlTs16 only pad to 16. GEMM-2: Wdf3 A-frags from
// L2. Epilogue: BN + bf16 residual + relu; final out = Obuf fp32 + result.
// ---------------------------------------------------------------------------
__global__ __launch_bounds__(256) void gcn_applyO(
    const float* __restrict__ X,            // O fp32 (b, v=10, c, t)
    const ushort* __restrict__ SbfO, const ushort* __restrict__ Wdf3,
    const float* __restrict__ bdO, const float* __restrict__ gO, const float* __restrict__ beO,
    float* __restrict__ out_f, const float* __restrict__ Obuf) {

    __shared__ ushort xsT[80 * 64];    // [p=v*8+tl][c], swz64 (persist: residual)
    __shared__ ushort uC[8192];        // xsC16 [c][tl*16+v0] swzC, then zsT [p][c] swz64
    __shared__ ushort SlTs16[832];     // [s][v][v0] 3*16*16 (+spec-pad)
    __shared__ float bias3[3 * 64];

    const int tid = threadIdx.x, b = blockIdx.x, chunk = blockIdx.y;
    const int lane = tid & 63, w = tid >> 6;
    const int ln = lane & 15, lq = lane >> 4;
    const int t0 = chunk * 8;

    if (tid < 64) {
        bias3[tid]       = bdO[tid] + bdO[64 + tid] + bdO[128 + tid];
        bias3[64 + tid]  = gO[tid] * rsqrtf(1.f + 1e-5f);
        bias3[128 + tid] = beO[tid];
    }
    // stage xsT from fp32 O: (v,c) -> 8 t's (two float4 loads)
    const float* Xb = X + (size_t)b * V2 * DD;
    for (int e = tid; e < 640; e += 256) {
        const int v = e >> 6, c = e & 63;
        const float* src = Xb + (size_t)v * DD + c * TT + t0;
        const float4 f0 = *(const float4*)src;
        const float4 f1 = *(const float4*)(src + 4);
        const float tmp[8] = {f0.x, f0.y, f0.z, f0.w, f1.x, f1.y, f1.z, f1.w};
        #pragma unroll
        for (int tl = 0; tl < 8; ++tl) xsT[swz64(v * 8 + tl, c)] = f2bb(tmp[tl]);
    }
    // stage SlTs16 (768 ushorts)
    {
        const uint4* Sb = (const uint4*)(SbfO + (size_t)b * 768);
        for (int e = tid; e < 96; e += 256) ((uint4*)SlTs16)[e] = Sb[e];
    }
    __syncthreads();   // xsT + SlTs16 staged

    // transpose xsT -> xsC16[c][tl*16+v0] (zero-pad v0 >= 10)
    {
        const int c = lane;
        #pragma unroll
        for (int jj = 0; jj < 4; ++jj) {
            const int u_ = w * 4 + jj;            // 16 combos: tl(8) x q(2)
            const int tl = u_ >> 1, q = u_ & 1;
            ushort vals[8];
            #pragma unroll
            for (int i = 0; i < 8; ++i) {
                const int v0 = q * 8 + i;
                vals[i] = (v0 < V2) ? xsT[swz64(v0 * 8 + tl, c)] : (ushort)0;
            }
            uint4 pk;
            pk.x = (uint)vals[0] | ((uint)vals[1] << 16);
            pk.y = (uint)vals[2] | ((uint)vals[3] << 16);
            pk.z = (uint)vals[4] | ((uint)vals[5] << 16);
            pk.w = (uint)vals[6] | ((uint)vals[7] << 16);
            *(uint4*)&uC[swzC(c, tl * 16 + q * 8)] = pk;
        }
    }
    __syncthreads();   // xsC16 ready

    // A-frags: aF[tl], k-halves >= 16 are zero
    union { uint4 u; bf16x8 v; } z8; z8.u = (uint4){0u, 0u, 0u, 0u};
    bf16x8 aF[8];
    #pragma unroll
    for (int tl = 0; tl < 8; ++tl)
        aF[tl] = (lq < 2) ? *(const bf16x8*)&uC[swzC(w * 16 + ln, tl * 16 + lq * 8)]
                          : z8.v;
    __syncthreads();   // aF reads done -> uC becomes zsT

    f32x4 acc[5];
    #pragma unroll
    for (int tn = 0; tn < 5; ++tn) acc[tn] = (f32x4){0.f, 0.f, 0.f, 0.f};

    for (int s = 0; s < 3; ++s) {
        // prefetch Wdf3 A-frags (L2-hit)
        const ushort* wp = Wdf3 + (((s * 4 + w) * 64 + lane) << 4);
        union { uint4 u; bf16x8 v; } ua, ub;
        ua.u = *(const uint4*)wp;
        ub.u = *(const uint4*)(wp + 8);

        if (s) __syncthreads();   // prior GEMM-2 done with zsT

        // ---- GEMM-1 (MFMA): z[c][v] = sum_v0 X^T[c][v0] * S[v0][v] ----
        const bf16x8 bF = (lq < 2)
            ? *(const bf16x8*)&SlTs16[s * 256 + ln * 16 + lq * 8] : z8.v;
        #pragma unroll
        for (int tl = 0; tl < 8; ++tl) {
            f32x4 d = (f32x4){0.f, 0.f, 0.f, 0.f};
            d = __builtin_amdgcn_mfma_f32_16x16x32_bf16(aF[tl], bF, d, 0, 0, 0);
            if (ln < V2) {    // col = ln -> v
                uint2 pk;
                pk.x = (uint)f2bb(d[0]) | ((uint)f2bb(d[1]) << 16);
                pk.y = (uint)f2bb(d[2]) | ((uint)f2bb(d[3]) << 16);
                *(uint2*)&uC[swz64(ln * 8 + tl, w * 16 + lq * 4)] = pk;
            }
        }
        __syncthreads();   // zsT ready

        // ---- GEMM-2 (MFMA): acc[o][p] += Wd[o][c] * z[p][c] ----
        #pragma unroll
        for (int tn = 0; tn < 5; ++tn) {
            const bf16x8 b0 = *(const bf16x8*)&uC[swz64(tn * 16 + ln, lq * 8)];
            const bf16x8 b1 = *(const bf16x8*)&uC[swz64(tn * 16 + ln, lq * 8 + 32)];
            acc[tn] = __builtin_amdgcn_mfma_f32_16x16x32_bf16(ua.v, b0, acc[tn], 0, 0, 0);
            acc[tn] = __builtin_amdgcn_mfma_f32_16x16x32_bf16(ub.v, b1, acc[tn], 0, 0, 0);
        }
    }
    __syncthreads();   // GEMM-2 done reading zsT

    // ---- epilogue: BN + bf16 residual + relu -> zsT ----
    {
        const int c0 = w * 16 + lq * 4;
        float bb[4], ss[4], be[4];
        #pragma unroll
        for (int r = 0; r < 4; ++r) {
            bb[r] = bias3[c0 + r];
            ss[r] = bias3[64 + c0 + r];
            be[r] = bias3[128 + c0 + r];
        }
        #pragma unroll
        for (int tn = 0; tn < 5; ++tn) {
            const int p = tn * 16 + ln;   // < 80
            const uint2 u = *(const uint2*)&xsT[swz64(p, c0)];
            const float rs[4] = {blo(u.x), bhi(u.x), blo(u.y), bhi(u.y)};
            float y[4];
            #pragma unroll
            for (int r = 0; r < 4; ++r)
                y[r] = fmaxf((acc[tn][r] + bb[r]) * ss[r] + be[r] + rs[r], 0.f);
            uint2 pk;
            pk.x = (uint)f2bb(y[0]) | ((uint)f2bb(y[1]) << 16);
            pk.y = (uint)f2bb(y[2]) | ((uint)f2bb(y[3]) << 16);
            *(uint2*)&uC[swz64(p, c0)] = pk;
        }
    }
    __syncthreads();

    // ---- final: out = Obuf (fp32) + relu-result; float4 writes ----
    {
        const int v = tid & 15, ci = tid >> 4;
        if (v < V2) {
            #pragma unroll
            for (int r = 0; r < 4; ++r) {
                const int c = ci * 4 + r;
                const size_t base = (size_t)b * V2 * DD + (size_t)v * DD + c * TT + t0;
                const float4 o0 = *(const float4*)&Obuf[base];
                const float4 o1 = *(const float4*)&Obuf[base + 4];
                float4 y0, y1;
                y0.x = o0.x + b2f_us(uC[swz64(v * 8 + 0, c)]);
                y0.y = o0.y + b2f_us(uC[swz64(v * 8 + 1, c)]);
                y0.z = o0.z + b2f_us(uC[swz64(v * 8 + 2, c)]);
                y0.w = o0.w + b2f_us(uC[swz64(v * 8 + 3, c)]);
                y1.x = o1.x + b2f_us(uC[swz64(v * 8 + 4, c)]);
                y1.y = o1.y + b2f_us(uC[swz64(v * 8 + 5, c)]);
                y1.z = o1.z + b2f_us(uC[swz64(v * 8 + 6, c)]);
                y1.w = o1.w + b2f_us(uC[swz64(v * 8 + 7, c)]);
                *(float4*)&out_f[base] = y0;
                *(float4*)&out_f[base + 4] = y1;
            }
        }
    }
}

// ---------------------------------------------------------------------------
// attention: Kg/Vg head-major; contiguous 16KB slabs per (b,h). Unchanged.
// ---------------------------------------------------------------------------
__global__ __launch_bounds__(256) void attn_kernel(const float* __restrict__ Q,
                                                   const bf16* __restrict__ Kg,
                                                   const bf16* __restrict__ Vg,
                                                   float* __restrict__ O) {
    int b = blockIdx.x, h = blockIdx.y, tid = threadIdx.x;
    __shared__ float qs[10 * DSH];
    __shared__ float ks[V1 * 321];
    __shared__ float att[10 * V1];
    const float* Qb = Q + (size_t)b * 10 * DD + h * DSH;
    for (int e = tid; e < 10 * DSH; e += 256) {
        int q = e / DSH, d = e % DSH;
        qs[e] = Qb[(size_t)q * DD + d];
    }
    const bf16* Kb = Kg + (size_t)(b * NH + h) * HSLAB;
    for (int e = tid; e < V1 * TT; e += 256) {
        const int kk = e / TT, t = e % TT;
        const uint4 u = *(const uint4*)(Kb + (size_t)e * 8);
        const ushort* us = (const ushort*)&u;
        float* dst = &ks[kk * 321 + t];
        #pragma unroll
        for (int cl = 0; cl < 8; ++cl) dst[cl * 40] = b2f_us(us[cl]);
    }
    __syncthreads();
    const float scale = 0.019764235376052370f;  // 1/sqrt(2560)
    for (int e = tid; e < 10 * V1; e += 256) {
        int q = e / V1, kk = e % V1;
        float acc = 0.f;
        #pragma unroll 8
        for (int d = 0; d < DSH; ++d) acc += qs[q * DSH + d] * ks[kk * 321 + d];
        att[e] = acc * scale;
    }
    __syncthreads();
    if (tid < 10) {
        float mx = -1e30f;
        for (int k = 0; k < V1; ++k) mx = fmaxf(mx, att[tid * V1 + k]);
        float sum = 0.f;
        for (int k = 0; k < V1; ++k) {
            float e_ = expf(att[tid * V1 + k] - mx);
            att[tid * V1 + k] = e_;
            sum += e_;
        }
        float r = 1.0f / sum;
        for (int k = 0; k < V1; ++k) att[tid * V1 + k] *= r;
    }
    const bf16* Vb = Vg + (size_t)(b * NH + h) * HSLAB;
    for (int e = tid; e < V1 * TT; e += 256) {
        const int kk = e / TT, t = e % TT;
        const uint4 u = *(const uint4*)(Vb + (size_t)e * 8);
        const ushort* us = (const ushort*)&u;
        float* dst = &ks[kk * 321 + t];
        #pragma unroll
        for (int cl = 0; cl < 8; ++cl) dst[cl * 40] = b2f_us(us[cl]);
    }
    __syncthreads();
    float* Ob = O + (size_t)b * 10 * DD + h * DSH;
    for (int e = tid; e < 10 * DSH; e += 256) {
        int q = e / DSH, dl = e % DSH;
        float acc = 0.f;
        #pragma unroll
        for (int k = 0; k < V1; ++k) acc += att[q * V1 + k] * ks[k * 321 + dl];
        Ob[(size_t)q * DD + dl] = qs[e] + acc;
    }
}

// ---------------------------------------------------------------------------
extern "C" void kernel_launch(void* const* d_in, const int* in_sizes, int n_in,
                              void* d_out, int out_size, void* d_ws, size_t ws_size,
                              hipStream_t stream) {
    const float* Q = (const float*)d_in[0];
    const float* K = (const float*)d_in[1];
    const float* fck_PA = (const float*)d_in[2];
    const float* fck_Wa = (const float*)d_in[3];
    const float* fck_ba = (const float*)d_in[4];
    const float* fck_Wb = (const float*)d_in[5];
    const float* fck_bb = (const float*)d_in[6];
    const float* fck_Wd = (const float*)d_in[7];
    const float* fck_bd = (const float*)d_in[8];
    const float* fck_gamma = (const float*)d_in[9];
    const float* fck_beta = (const float*)d_in[10];
    const float* fcv_PA = (const float*)d_in[11];
    const float* fcv_Wa = (const float*)d_in[12];
    const float* fcv_ba = (const float*)d_in[13];
    const float* fcv_Wb = (const float*)d_in[14];
    const float* fcv_bb = (const float*)d_in[15];
    const float* fcv_Wd = (const float*)d_in[16];
    const float* fcv_bd = (const float*)d_in[17];
    const float* fcv_gamma = (const float*)d_in[18];
    const float* fcv_beta = (const float*)d_in[19];
    const float* fco_PA = (const float*)d_in[20];
    const float* fco_Wa = (const float*)d_in[21];
    const float* fco_ba = (const float*)d_in[22];
    const float* fco_Wb = (const float*)d_in[23];
    const float* fco_bb = (const float*)d_in[24];
    const float* fco_Wd = (const float*)d_in[25];
    const float* fco_bd = (const float*)d_in[26];
    const float* fco_gamma = (const float*)d_in[27];
    const float* fco_beta = (const float*)d_in[28];

    // Workspace map:
    //   [0, 32.768 MB)        Xbf (head-major bf16 K) — overwritten in place
    //                         by gcn_applyKV as Vg (same addressing).
    //   [32.768, 65.536)      Kg (head-major; dead after attn) — then SbfO
    //                         (393 KB) + Wdf3 (24.6 KB) for the fco tail.
    //   [65.536, 84.736)      Mpart (S3->reduce);  then O (attn->applyO)
    //   [65.536, 91.750)        O spans this region (disjoint lifetimes)
    //   [84.736, 87.882)      Sbf  (reduce->applyKV, dead before attn)
    //   [88.000, 88.197)      Wdf  (reduce->applyKV, dead before attn)
    char* wsb = (char*)d_ws;
    bf16* Xbf = (bf16*)(wsb);
    bf16* Vg = (bf16*)(wsb);                     // in-place over Xbf
    bf16* Kg = (bf16*)(wsb + 32768000);
    float* Mpart = (float*)(wsb + 65536000);     // [5][256][6][625] fp32 = 19.2 MB
    float* O = (float*)(wsb + 65536000);         // 26.2 MB, live after applyKV
    ushort* Sbf = (ushort*)(wsb + 84736000);     // [256][2][3][32][32] bf16 = 3.1 MB
    ushort* Wdf = (ushort*)(wsb + 88000000);     // [2][3][4][64][16] bf16 = 192 KB
    ushort* SbfO = (ushort*)(wsb + 32768000);    // [256][3][16][16] bf16 = 393 KB (over dead Kg)
    ushort* Wdf3 = (ushort*)(wsb + 33300000);    // [3][4][64][16] bf16 = 24.6 KB

    gcn_S3<<<dim3(BB * 5), dim3(256), 0, stream>>>(
        K, fck_Wa, fck_ba, fck_Wb, fck_bb,
        fcv_Wa, fcv_ba, fcv_Wb, fcv_bb, Xbf, Mpart);

    reduce_softmax<<<dim3(BB, 6), dim3(128), 0, stream>>>(
        Mpart, fck_PA, fcv_PA, fck_Wd, fcv_Wd, Sbf, Wdf);

    gcn_applyKV<<<dim3(BB, 10), dim3(256), 0, stream>>>(
        Xbf, Sbf, Wdf,
        fck_bd, fck_gamma, fck_beta,
        fcv_bd, fcv_gamma, fcv_beta, Kg, Vg);

    attn_kernel<<<dim3(BB, NH), dim3(256), 0, stream>>>(Q, Kg, Vg, O);

    gcn_S2O<<<dim3(BB, 3), dim3(256), 0, stream>>>(
        O, fco_Wa, fco_ba, fco_Wb, fco_bb, fco_PA, fco_Wd, SbfO, Wdf3);

    gcn_applyO<<<dim3(BB, 5), dim3(256), 0, stream>>>(
        O, SbfO, Wdf3, fco_bd, fco_gamma, fco_beta, (float*)d_out, O);
}

// Round 7
// 446.414 us; speedup vs baseline: 1.6267x; 1.0445x over previous
//
#include <hip/hip_runtime.h>
#include <hip/hip_bf16.h>

#define BB 256
#define CC 64
#define TT 40
#define DD 2560   // CC*TT
#define V1 25
#define V2 10
#define INTER 16
#define NH 8
#define DSH 320   // DD/NH
#define HSLAB 8000  // V1*TT*8 elems per (b,h) slab in head-major layout

typedef __hip_bfloat16 bf16;
typedef unsigned int uint;
typedef unsigned short ushort;
typedef __attribute__((ext_vector_type(8))) short bf16x8;
typedef __attribute__((ext_vector_type(4))) float f32x4;

__device__ __forceinline__ float b2f(bf16 x) { return __bfloat162float(x); }

__device__ __forceinline__ ushort f2bb(float f) {
    uint x = __float_as_uint(f);
    uint r = x + 0x7fffu + ((x >> 16) & 1u);
    return (ushort)(r >> 16);
}
__device__ __forceinline__ float blo(uint u) { return __uint_as_float(u << 16); }
__device__ __forceinline__ float bhi(uint u) { return __uint_as_float(u & 0xffff0000u); }
__device__ __forceinline__ float b2f_us(ushort h) { return __uint_as_float(((uint)h) << 16); }
__device__ __forceinline__ uint4 pack8(const float* a) {
    uint4 pk;
    pk.x = (uint)f2bb(a[0]) | ((uint)f2bb(a[1]) << 16);
    pk.y = (uint)f2bb(a[2]) | ((uint)f2bb(a[3]) << 16);
    pk.z = (uint)f2bb(a[4]) | ((uint)f2bb(a[5]) << 16);
    pk.w = (uint)f2bb(a[6]) | ((uint)f2bb(a[7]) << 16);
    return pk;
}

// LDS swizzle helpers (ushort index). 64-ushort (128B) rows, 16B-granule XOR
// by low row bits -> every vectorized access pattern hits its bank floor.
__device__ __forceinline__ int swz64(int row, int col) {
    return row * 64 + ((((col >> 3) ^ row) & 7) << 3) + (col & 7);
}
// 128-ushort (256B) rows, granule XOR by (c&15)
__device__ __forceinline__ int swzC(int c, int col) {
    return c * 128 + ((((col >> 3) ^ c) & 15) << 3) + (col & 7);
}

// ---------------------------------------------------------------------------
// prep_wabf: 1 block. Pre-convert Wa/Wb (fck+fcv) into MFMA fragment order
// Wabf[s][mat][lane][16] so gcn_S3 reads proj A-frags straight from L2.
// Wabf[((s*4+mat)*64+lane)*16 + i]      = W_mat[s*1024 + ln*64 + lq*8 + i]
// Wabf[((s*4+mat)*64+lane)*16 + 8 + i]  = W_mat[s*1024 + ln*64 + lq*8 + 32 + i]
// (identical per-lane contents to the old wT staging; verified mapping.)
// ---------------------------------------------------------------------------
__global__ __launch_bounds__(256) void prep_wabf(
    const float* __restrict__ Wa0, const float* __restrict__ Wb0,
    const float* __restrict__ Wa1, const float* __restrict__ Wb1,
    ushort* __restrict__ Wabf) {
    const int tid = threadIdx.x;
    for (int e = tid; e < 768; e += 256) {
        const int lane = e & 63, mat = (e >> 6) & 3, s = e >> 8;
        const int ln = lane & 15, lq = lane >> 4;
        const float* Wp = (mat == 0) ? Wa0 : (mat == 1) ? Wb0 : (mat == 2) ? Wa1 : Wb1;
        const float* src = Wp + s * 1024 + ln * 64 + lq * 8;
        ushort* dst = Wabf + e * 16;
        #pragma unroll
        for (int i = 0; i < 8; ++i) {
            dst[i] = f2bb(src[i]);
            dst[8 + i] = f2bb(src[32 + i]);
        }
    }
}

// ---------------------------------------------------------------------------
// gcn_S3 (V=25, fck+fcv fused): grid = (tc*256 + b), 1280 blocks x 512 thr.
// Waves 0-7: proj mat = w&3 (nt range split by w>>2); Gram unit = w.
// Per block: stage x chunk once; EXPORT head-major bf16 Xbf; then per subset:
// proj MFMA (A-frags prefetched from Wabf/L2) + Gram MFMA -> Mpart.
// LDS 64.0 KB -> 2 blocks/CU x 8 waves = 16 waves/CU.
// ---------------------------------------------------------------------------
__global__ __launch_bounds__(512) void gcn_S3(
    const float* __restrict__ X,
    const ushort* __restrict__ Wabf,
    const float* __restrict__ ba0, const float* __restrict__ bb0,
    const float* __restrict__ ba1, const float* __restrict__ bb1,
    bf16* __restrict__ Xw, float* __restrict__ Mpart) {
    __shared__ ushort xsT[208][72];    // [p=v*8+tl][c]; rows 200..207 garbage
    __shared__ ushort abT[4][32][136]; // [mat][v][j*8+tl]
    __shared__ float biasS3[192];      // [s][mat*16+j]

    const int tid = threadIdx.x;
    const int b = blockIdx.x & 255, tc = blockIdx.x >> 8;
    const int t0 = tc * 8;
    const int lane = tid & 63, w = tid >> 6;       // w 0..7
    const int ln = lane & 15, lq = lane >> 4;
    const int mat = w & 3, half = w >> 2;

    // stage x chunk: (v,c) -> 8 t's, bf16 into transposed rows p=v*8+tl
    const float* Xb = X + (size_t)b * V1 * DD;
    for (int e = tid; e < V1 * 64; e += 512) {
        const int v = e >> 6, c = e & 63;
        const float* src = Xb + (size_t)v * DD + c * TT + t0;
        const float4 f0 = *(const float4*)src;
        const float4 f1 = *(const float4*)(src + 4);
        const float tmp[8] = {f0.x, f0.y, f0.z, f0.w, f1.x, f1.y, f1.z, f1.w};
        #pragma unroll
        for (int tl = 0; tl < 8; ++tl) xsT[v * 8 + tl][c] = f2bb(tmp[tl]);
    }
    if (tid < 192) {
        const int s = tid >> 6, m2 = (tid >> 4) & 3, j = tid & 15;
        const float* bp = (m2 == 0) ? ba0 : (m2 == 1) ? bb0 : (m2 == 2) ? ba1 : bb1;
        biasS3[tid] = bp[s * 16 + j];
    }
    __syncthreads();                   // xsT + biasS3 complete

    // export head-major bf16 X: e -> (v, h, tl)
    for (int e = tid; e < 1600; e += 512) {
        const int v = e >> 6, h = (e >> 3) & 7, tl = e & 7;
        *(uint4*)(Xw + (size_t)(b * NH + h) * HSLAB + v * 320 + (t0 + tl) * 8) =
            *(const uint4*)&xsT[v * 8 + tl][h * 8];
    }

    for (int s = 0; s < 3; ++s) {
        // prefetch proj A-frags for (s, mat) from L2 (no LDS dependence)
        const ushort* wp = Wabf + (((s * 4 + mat) * 64 + lane) << 4);
        union { uint4 u; bf16x8 v; } ua, ub;
        ua.u = *(const uint4*)wp;
        ub.u = *(const uint4*)(wp + 8);
        float br[4];
        #pragma unroll
        for (int r = 0; r < 4; ++r) br[r] = biasS3[s * 64 + mat * 16 + lq * 4 + r];

        if (s) __syncthreads();        // Gram[s-1] done reading abT

        // ---- projection: wave pair (mat, half) covers 13 n-tiles ----
        const int ntEnd = half ? 13 : 7;
        for (int nt = half ? 7 : 0; nt < ntEnd; ++nt) {
            const bf16x8 b0 = *(const bf16x8*)&xsT[nt * 16 + ln][lq * 8];
            const bf16x8 b1 = *(const bf16x8*)&xsT[nt * 16 + ln][lq * 8 + 32];
            f32x4 acc = (f32x4){0.f, 0.f, 0.f, 0.f};
            acc = __builtin_amdgcn_mfma_f32_16x16x32_bf16(ua.v, b0, acc, 0, 0, 0);
            acc = __builtin_amdgcn_mfma_f32_16x16x32_bf16(ub.v, b1, acc, 0, 0, 0);
            const int p = nt * 16 + ln;
            if (p < 200) {
                const int v = p >> 3, tl = p & 7;
                #pragma unroll
                for (int r = 0; r < 4; ++r)
                    abT[mat][v][(lq * 4 + r) * 8 + tl] = f2bb(acc[r] + br[r]);
            }
        }
        __syncthreads();               // abT ready

        // ---- Gram: 8 tile-units (np,mt,nt), wave w does unit w ----
        {
            const int np = w >> 2, mt = (w >> 1) & 1, ntl = w & 1;
            const ushort* Ap = &abT[np * 2 + 0][mt * 16 + ln][lq * 8];
            const ushort* Bp = &abT[np * 2 + 1][ntl * 16 + ln][lq * 8];
            f32x4 g = (f32x4){0.f, 0.f, 0.f, 0.f};
            g = __builtin_amdgcn_mfma_f32_16x16x32_bf16(
                    *(const bf16x8*)Ap, *(const bf16x8*)Bp, g, 0, 0, 0);
            g = __builtin_amdgcn_mfma_f32_16x16x32_bf16(
                    *(const bf16x8*)(Ap + 32), *(const bf16x8*)(Bp + 32), g, 0, 0, 0);
            g = __builtin_amdgcn_mfma_f32_16x16x32_bf16(
                    *(const bf16x8*)(Ap + 64), *(const bf16x8*)(Bp + 64), g, 0, 0, 0);
            g = __builtin_amdgcn_mfma_f32_16x16x32_bf16(
                    *(const bf16x8*)(Ap + 96), *(const bf16x8*)(Bp + 96), g, 0, 0, 0);
            const int vp = ntl * 16 + ln;
            if (vp < V1) {
                float* Mb = Mpart + (((size_t)tc * 256 + b) * 6 + (s * 2 + np)) * 625;
                #pragma unroll
                for (int r = 0; r < 4; ++r) {
                    const int v = mt * 16 + lq * 4 + r;
                    if (v < V1) Mb[v * V1 + vp] = g[r];
                }
            }
        }
    }
}

// ---------------------------------------------------------------------------
// reduce_softmax: sum 5 chunk-partials, column softmax, + PA, write Sbf
// (bf16 S^T zero-padded [b][g][s][32][32]). b==0 blocks emit Wdf (fck/fcv Wd
// pre-converted bf16 in MFMA fragment order [g][s][w][lane][16]).
// ---------------------------------------------------------------------------
__global__ __launch_bounds__(128) void reduce_softmax(
    const float* __restrict__ Mpart,
    const float* __restrict__ PA0, const float* __restrict__ PA1,
    const float* __restrict__ WdK, const float* __restrict__ WdV,
    ushort* __restrict__ Sbf, ushort* __restrict__ Wdf) {
    __shared__ float Ms[625];
    const int tid = threadIdx.x, b = blockIdx.x, snp = blockIdx.y;
    const int s = snp >> 1, np = snp & 1;

    if (b == 0) {
        for (int e = tid; e < 256; e += 128) {
            const int wv = e >> 6, l = e & 63;
            const int lnn = l & 15, lqq = l >> 4;
            const float* Wp = (np ? WdV : WdK) + s * 4096 + (wv * 16 + lnn) * 64 + lqq * 8;
            ushort* dst = Wdf + (((np * 3 + s) * 4 + wv) * 64 + l) * 16;
            #pragma unroll
            for (int j = 0; j < 8; ++j) {
                dst[j] = f2bb(Wp[j]);
                dst[8 + j] = f2bb(Wp[32 + j]);
            }
        }
    }

    for (int e = tid; e < 625; e += 128) {
        float sum = 0.f;
        #pragma unroll
        for (int tcc = 0; tcc < 5; ++tcc)
            sum += Mpart[(((size_t)tcc * 256 + b) * 6 + snp) * 625 + e];
        Ms[e] = sum;
    }
    __syncthreads();
    if (tid < 32) {
        ushort* SbfRow = Sbf + ((((size_t)b * 2 + np) * 3 + s) << 10) + tid * 32;
        if (tid < V1) {
            const int vp = tid;
            const float invIT = 1.0f / 640.0f;
            float mx = -1e30f;
            for (int v = 0; v < V1; ++v) mx = fmaxf(mx, Ms[v * V1 + vp]);
            float sum = 0.f;
            for (int v = 0; v < V1; ++v) sum += expf((Ms[v * V1 + vp] - mx) * invIT);
            const float rs = 1.f / sum;
            const float* PAn = np ? PA1 : PA0;
            for (int v = 0; v < V1; ++v) {
                const float e_ = expf((Ms[v * V1 + vp] - mx) * invIT);
                SbfRow[v] = f2bb(e_ * rs + PAn[(s * V1 + v) * V1 + vp]);
            }
            for (int v = V1; v < 32; ++v) SbfRow[v] = 0;
        } else {
            for (int v = 0; v < 32; ++v) SbfRow[v] = 0;
        }
    }
}

// ---------------------------------------------------------------------------
// gcn_S2O (V=10 fco): VALU Gram as before; softmax tail writes SbfO (bf16
// S^T zero-padded [b][3][16][16]); b==0 blocks emit Wdf3 (fco_Wd bf16 in
// MFMA fragment order [s][w][lane][16]).
// ---------------------------------------------------------------------------
__global__ __launch_bounds__(256) void gcn_S2O(
    const float* __restrict__ X,
    const float* __restrict__ Wa0, const float* __restrict__ ba0,
    const float* __restrict__ Wb0, const float* __restrict__ bb0,
    const float* __restrict__ PA0, const float* __restrict__ WdO,
    ushort* __restrict__ SbfO, ushort* __restrict__ Wdf3) {
    constexpr int V = V2;      // 10
    constexpr int P = 80;      // V*8
    __shared__ ushort xs[64][P];
    __shared__ ushort ab[32][P];
    __shared__ ushort wT[64][32];
    __shared__ float biasL[32];
    __shared__ float M[100];

    const int tid = threadIdx.x, b = blockIdx.x, s = blockIdx.y;

    if (b == 0) {   // Wdf3 prep (3 blocks, one per s)
        const int e = tid;
        if (e < 256) {
            const int wv = e >> 6, l = e & 63;
            const int lnn = l & 15, lqq = l >> 4;
            const float* Wp = WdO + s * 4096 + (wv * 16 + lnn) * 64 + lqq * 8;
            ushort* dst = Wdf3 + (((s * 4 + wv) * 64 + l) << 4);
            #pragma unroll
            for (int j = 0; j < 8; ++j) {
                dst[j] = f2bb(Wp[j]);
                dst[8 + j] = f2bb(Wp[32 + j]);
            }
        }
    }

    for (int e = tid; e < 16 * 64; e += 256) {
        int c = e & 63, j = e >> 6;
        wT[c][j]      = f2bb(Wa0[s * 1024 + e]);
        wT[c][16 + j] = f2bb(Wb0[s * 1024 + e]);
    }
    if (tid < 16) {
        biasL[tid]      = ba0[s * 16 + tid];
        biasL[16 + tid] = bb0[s * 16 + tid];
    }

    float macc = 0.f;

    const float* Xb = X + (size_t)b * V * DD;
    for (int tc = 0; tc < 5; ++tc) {
        const int t0 = tc * 8;
        for (int e = tid; e < V * 64; e += 256) {
            const int v = e >> 6, c = e & 63;
            const float* src = Xb + (size_t)v * DD + c * TT + t0;
            const float4 f0 = *(const float4*)src;
            const float4 f1 = *(const float4*)(src + 4);
            const float tmp[8] = {f0.x, f0.y, f0.z, f0.w, f1.x, f1.y, f1.z, f1.w};
            *(uint4*)&xs[c][v * 8] = pack8(tmp);
        }
        __syncthreads();
        for (int tau = tid; tau < 80; tau += 256) {
            const int rq = tau % 8, co = tau / 8;
            float acc[4][8];
            #pragma unroll
            for (int r = 0; r < 4; ++r) {
                const float bv = biasL[4 * rq + r];
                #pragma unroll
                for (int cc = 0; cc < 8; ++cc) acc[r][cc] = bv;
            }
            for (int c = 0; c < 64; ++c) {
                const uint2 wv = *(const uint2*)&wT[c][4 * rq];
                const uint4 xv = *(const uint4*)&xs[c][8 * co];
                const float w0 = blo(wv.x), w1 = bhi(wv.x);
                const float w2 = blo(wv.y), w3 = bhi(wv.y);
                const float x0 = blo(xv.x), x1 = bhi(xv.x);
                const float x2 = blo(xv.y), x3 = bhi(xv.y);
                const float x4 = blo(xv.z), x5 = bhi(xv.z);
                const float x6 = blo(xv.w), x7 = bhi(xv.w);
                acc[0][0] += w0 * x0; acc[0][1] += w0 * x1;
                acc[0][2] += w0 * x2; acc[0][3] += w0 * x3;
                acc[0][4] += w0 * x4; acc[0][5] += w0 * x5;
                acc[0][6] += w0 * x6; acc[0][7] += w0 * x7;
                acc[1][0] += w1 * x0; acc[1][1] += w1 * x1;
                acc[1][2] += w1 * x2; acc[1][3] += w1 * x3;
                acc[1][4] += w1 * x4; acc[1][5] += w1 * x5;
                acc[1][6] += w1 * x6; acc[1][7] += w1 * x7;
                acc[2][0] += w2 * x0; acc[2][1] += w2 * x1;
                acc[2][2] += w2 * x2; acc[2][3] += w2 * x3;
                acc[2][4] += w2 * x4; acc[2][5] += w2 * x5;
                acc[2][6] += w2 * x6; acc[2][7] += w2 * x7;
                acc[3][0] += w3 * x0; acc[3][1] += w3 * x1;
                acc[3][2] += w3 * x2; acc[3][3] += w3 * x3;
                acc[3][4] += w3 * x4; acc[3][5] += w3 * x5;
                acc[3][6] += w3 * x6; acc[3][7] += w3 * x7;
            }
            #pragma unroll
            for (int r = 0; r < 4; ++r)
                *(uint4*)&ab[4 * rq + r][8 * co] = pack8(acc[r]);
        }
        __syncthreads();
        if (tid < 100) {
            const int v = tid / V, vp = tid % V;
            float mm = 0.f;
            #pragma unroll
            for (int j = 0; j < 16; ++j) {
                const uint4 av = *(const uint4*)&ab[j][v * 8];
                const uint4 bv = *(const uint4*)&ab[16 + j][vp * 8];
                mm += blo(av.x) * blo(bv.x) + bhi(av.x) * bhi(bv.x)
                    + blo(av.y) * blo(bv.y) + bhi(av.y) * bhi(bv.y)
                    + blo(av.z) * blo(bv.z) + bhi(av.z) * bhi(bv.z)
                    + blo(av.w) * blo(bv.w) + bhi(av.w) * bhi(bv.w);
            }
            macc += mm;
        }
    }

    if (tid < 100) M[tid] = macc;
    __syncthreads();

    const float invIT = 1.0f / 640.0f;
    if (tid < 16) {
        ushort* So = SbfO + ((size_t)b * 3 + s) * 256 + tid * 16;
        if (tid < V) {
            const int vp = tid;
            float mx = -1e30f;
            for (int v = 0; v < V; ++v) mx = fmaxf(mx, M[v * V + vp]);
            float sum = 0.f;
            for (int v = 0; v < V; ++v) sum += expf((M[v * V + vp] - mx) * invIT);
            const float rs = 1.f / sum;
            for (int v = 0; v < V; ++v) {
                const float e_ = expf((M[v * V + vp] - mx) * invIT);
                So[v] = f2bb(e_ * rs + PA0[(s * V + v) * V + vp]);
            }
            for (int v = V; v < 16; ++v) So[v] = 0;
        } else {
            for (int v = 0; v < 16; ++v) So[v] = 0;
        }
    }
}

// ---------------------------------------------------------------------------
// gcn_applyKV: fused fck+fcv apply for V=25, all-MFMA (unchanged, verified).
// ---------------------------------------------------------------------------
__global__ __launch_bounds__(256) void gcn_applyKV(
    const bf16* __restrict__ Xbf,
    const ushort* __restrict__ Sbf, const ushort* __restrict__ Wdf,
    const float* __restrict__ bdK, const float* __restrict__ gK, const float* __restrict__ beK,
    const float* __restrict__ bdV, const float* __restrict__ gV, const float* __restrict__ beV,
    bf16* __restrict__ Kg, bf16* __restrict__ Vg) {

    __shared__ ushort xsT[100 * 64];   // [p=v*4+tl][c], swz64 (persist)
    __shared__ ushort SlTs[6144];      // [(g*3+s)*1024 + vp*32 + v0] (persist)
    __shared__ ushort uC[8192];        // xsC [c][tl*32+v0] swzC, then zsT [p][c] swz64
    __shared__ float bias6[6 * 64];

    const int tid = threadIdx.x, b = blockIdx.x, chunk = blockIdx.y;
    const int lane = tid & 63, w = tid >> 6;
    const int ln = lane & 15, lq = lane >> 4;
    const int t0 = chunk * 4;

    if (tid < 64) {
        bias6[tid]       = bdK[tid] + bdK[64 + tid] + bdK[128 + tid];
        bias6[64 + tid]  = bdV[tid] + bdV[64 + tid] + bdV[128 + tid];
        bias6[128 + tid] = gK[tid] * rsqrtf(1.f + 1e-5f);
        bias6[192 + tid] = gV[tid] * rsqrtf(1.f + 1e-5f);
        bias6[256 + tid] = beK[tid];
        bias6[320 + tid] = beV[tid];
    }
    const bf16* Xb = Xbf + (size_t)b * NH * HSLAB;
    for (int e = tid; e < 1024; e += 256) {
        const int h = e >> 7, v = (e >> 2) & 31, tl = e & 3;
        if (v < V1)
            *(uint4*)&xsT[swz64(v * 4 + tl, h * 8)] =
                *(const uint4*)(Xb + (size_t)h * HSLAB + v * 320 + (t0 + tl) * 8);
    }
    {
        const ushort* Sb = Sbf + (size_t)b * 6144;
        for (int e = tid; e < 768; e += 256)
            ((uint4*)SlTs)[e] = ((const uint4*)Sb)[e];
    }
    __syncthreads();   // xsT + SlTs staged

    {
        const int c = lane, q = w;
        #pragma unroll
        for (int j = 0; j < 4; ++j) {
            ushort vals[8];
            #pragma unroll
            for (int i = 0; i < 8; ++i) {
                const int v0 = q * 8 + i;
                vals[i] = (v0 < V1) ? xsT[swz64(v0 * 4 + j, c)] : (ushort)0;
            }
            uint4 pk;
            pk.x = (uint)vals[0] | ((uint)vals[1] << 16);
            pk.y = (uint)vals[2] | ((uint)vals[3] << 16);
            pk.z = (uint)vals[4] | ((uint)vals[5] << 16);
            pk.w = (uint)vals[6] | ((uint)vals[7] << 16);
            *(uint4*)&uC[swzC(c, j * 32 + q * 8)] = pk;
        }
    }
    __syncthreads();   // xsC ready

    bf16x8 aF[4];
    #pragma unroll
    for (int tl = 0; tl < 4; ++tl)
        aF[tl] = *(const bf16x8*)&uC[swzC(w * 16 + ln, tl * 32 + lq * 8)];
    __syncthreads();   // aF reads done -> uC becomes zsT

    for (int g = 0; g < 2; ++g) {
        f32x4 acc[7];
        #pragma unroll
        for (int tn = 0; tn < 7; ++tn) acc[tn] = (f32x4){0.f, 0.f, 0.f, 0.f};

        for (int s = 0; s < 3; ++s) {
            const ushort* wp = Wdf + ((((g * 3 + s) * 4 + w) * 64 + lane) << 4);
            union { uint4 u; bf16x8 v; } ua, ub;
            ua.u = *(const uint4*)wp;
            ub.u = *(const uint4*)(wp + 8);

            if (g | s) __syncthreads();

            #pragma unroll
            for (int nt = 0; nt < 2; ++nt) {
                const bf16x8 bF =
                    *(const bf16x8*)&SlTs[((g * 3 + s) << 10) + (nt * 16 + ln) * 32 + lq * 8];
                const int v = nt * 16 + ln;
                #pragma unroll
                for (int tl = 0; tl < 4; ++tl) {
                    f32x4 d = (f32x4){0.f, 0.f, 0.f, 0.f};
                    d = __builtin_amdgcn_mfma_f32_16x16x32_bf16(aF[tl], bF, d, 0, 0, 0);
                    if (v < V1) {
                        uint2 pk;
                        pk.x = (uint)f2bb(d[0]) | ((uint)f2bb(d[1]) << 16);
                        pk.y = (uint)f2bb(d[2]) | ((uint)f2bb(d[3]) << 16);
                        *(uint2*)&uC[swz64(v * 4 + tl, w * 16 + lq * 4)] = pk;
                    }
                }
            }
            __syncthreads();   // zsT ready

            #pragma unroll
            for (int tn = 0; tn < 7; ++tn) {
                const bf16x8 b0 = *(const bf16x8*)&uC[swz64(tn * 16 + ln, lq * 8)];
                const bf16x8 b1 = *(const bf16x8*)&uC[swz64(tn * 16 + ln, lq * 8 + 32)];
                acc[tn] = __builtin_amdgcn_mfma_f32_16x16x32_bf16(ua.v, b0, acc[tn], 0, 0, 0);
                acc[tn] = __builtin_amdgcn_mfma_f32_16x16x32_bf16(ub.v, b1, acc[tn], 0, 0, 0);
            }
        }
        __syncthreads();   // GEMM-2 done reading zsT

        {
            const int c0 = w * 16 + lq * 4;
            float bb[4], ss[4], be[4];
            #pragma unroll
            for (int r = 0; r < 4; ++r) {
                bb[r] = bias6[g * 64 + c0 + r];
                ss[r] = bias6[128 + g * 64 + c0 + r];
                be[r] = bias6[256 + g * 64 + c0 + r];
            }
            #pragma unroll
            for (int tn = 0; tn < 7; ++tn) {
                const int p = tn * 16 + ln;
                if (p < 100) {
                    const uint2 u = *(const uint2*)&xsT[swz64(p, c0)];
                    const float rs[4] = {blo(u.x), bhi(u.x), blo(u.y), bhi(u.y)};
                    float y[4];
                    #pragma unroll
                    for (int r = 0; r < 4; ++r)
                        y[r] = fmaxf((acc[tn][r] + bb[r]) * ss[r] + be[r] + rs[r], 0.f);
                    uint2 pk;
                    pk.x = (uint)f2bb(y[0]) | ((uint)f2bb(y[1]) << 16);
                    pk.y = (uint)f2bb(y[2]) | ((uint)f2bb(y[3]) << 16);
                    *(uint2*)&uC[swz64(p, c0)] = pk;
                }
            }
        }
        __syncthreads();

        bf16* outp = (g ? Vg : Kg) + (size_t)b * NH * HSLAB;
        for (int e = tid; e < 1024; e += 256) {
            const int h = e >> 7, v = (e >> 2) & 31, tl = e & 3;
            if (v < V1)
                *(uint4*)(outp + (size_t)h * HSLAB + v * 320 + (t0 + tl) * 8) =
                    *(const uint4*)&uC[swz64(v * 4 + tl, h * 8)];
        }
    }
}

// ---------------------------------------------------------------------------
// gcn_applyO: fco apply (V=10), all-MFMA, applyKV-style (unchanged).
// ---------------------------------------------------------------------------
__global__ __launch_bounds__(256) void gcn_applyO(
    const float* __restrict__ X,            // O fp32 (b, v=10, c, t)
    const ushort* __restrict__ SbfO, const ushort* __restrict__ Wdf3,
    const float* __restrict__ bdO, const float* __restrict__ gO, const float* __restrict__ beO,
    float* __restrict__ out_f, const float* __restrict__ Obuf) {

    __shared__ ushort xsT[80 * 64];    // [p=v*8+tl][c], swz64 (persist: residual)
    __shared__ ushort uC[8192];        // xsC16 [c][tl*16+v0] swzC, then zsT [p][c] swz64
    __shared__ ushort SlTs16[832];     // [s][v][v0] 3*16*16 (+spec-pad)
    __shared__ float bias3[3 * 64];

    const int tid = threadIdx.x, b = blockIdx.x, chunk = blockIdx.y;
    const int lane = tid & 63, w = tid >> 6;
    const int ln = lane & 15, lq = lane >> 4;
    const int t0 = chunk * 8;

    if (tid < 64) {
        bias3[tid]       = bdO[tid] + bdO[64 + tid] + bdO[128 + tid];
        bias3[64 + tid]  = gO[tid] * rsqrtf(1.f + 1e-5f);
        bias3[128 + tid] = beO[tid];
    }
    const float* Xb = X + (size_t)b * V2 * DD;
    for (int e = tid; e < 640; e += 256) {
        const int v = e >> 6, c = e & 63;
        const float* src = Xb + (size_t)v * DD + c * TT + t0;
        const float4 f0 = *(const float4*)src;
        const float4 f1 = *(const float4*)(src + 4);
        const float tmp[8] = {f0.x, f0.y, f0.z, f0.w, f1.x, f1.y, f1.z, f1.w};
        #pragma unroll
        for (int tl = 0; tl < 8; ++tl) xsT[swz64(v * 8 + tl, c)] = f2bb(tmp[tl]);
    }
    {
        const uint4* Sb = (const uint4*)(SbfO + (size_t)b * 768);
        for (int e = tid; e < 96; e += 256) ((uint4*)SlTs16)[e] = Sb[e];
    }
    __syncthreads();   // xsT + SlTs16 staged

    {
        const int c = lane;
        #pragma unroll
        for (int jj = 0; jj < 4; ++jj) {
            const int u_ = w * 4 + jj;            // 16 combos: tl(8) x q(2)
            const int tl = u_ >> 1, q = u_ & 1;
            ushort vals[8];
            #pragma unroll
            for (int i = 0; i < 8; ++i) {
                const int v0 = q * 8 + i;
                vals[i] = (v0 < V2) ? xsT[swz64(v0 * 8 + tl, c)] : (ushort)0;
            }
            uint4 pk;
            pk.x = (uint)vals[0] | ((uint)vals[1] << 16);
            pk.y = (uint)vals[2] | ((uint)vals[3] << 16);
            pk.z = (uint)vals[4] | ((uint)vals[5] << 16);
            pk.w = (uint)vals[6] | ((uint)vals[7] << 16);
            *(uint4*)&uC[swzC(c, tl * 16 + q * 8)] = pk;
        }
    }
    __syncthreads();   // xsC16 ready

    union { uint4 u; bf16x8 v; } z8; z8.u = (uint4){0u, 0u, 0u, 0u};
    bf16x8 aF[8];
    #pragma unroll
    for (int tl = 0; tl < 8; ++tl)
        aF[tl] = (lq < 2) ? *(const bf16x8*)&uC[swzC(w * 16 + ln, tl * 16 + lq * 8)]
                          : z8.v;
    __syncthreads();   // aF reads done -> uC becomes zsT

    f32x4 acc[5];
    #pragma unroll
    for (int tn = 0; tn < 5; ++tn) acc[tn] = (f32x4){0.f, 0.f, 0.f, 0.f};

    for (int s = 0; s < 3; ++s) {
        const ushort* wp = Wdf3 + (((s * 4 + w) * 64 + lane) << 4);
        union { uint4 u; bf16x8 v; } ua, ub;
        ua.u = *(const uint4*)wp;
        ub.u = *(const uint4*)(wp + 8);

        if (s) __syncthreads();   // prior GEMM-2 done with zsT

        const bf16x8 bF = (lq < 2)
            ? *(const bf16x8*)&SlTs16[s * 256 + ln * 16 + lq * 8] : z8.v;
        #pragma unroll
        for (int tl = 0; tl < 8; ++tl) {
            f32x4 d = (f32x4){0.f, 0.f, 0.f, 0.f};
            d = __builtin_amdgcn_mfma_f32_16x16x32_bf16(aF[tl], bF, d, 0, 0, 0);
            if (ln < V2) {    // col = ln -> v
                uint2 pk;
                pk.x = (uint)f2bb(d[0]) | ((uint)f2bb(d[1]) << 16);
                pk.y = (uint)f2bb(d[2]) | ((uint)f2bb(d[3]) << 16);
                *(uint2*)&uC[swz64(ln * 8 + tl, w * 16 + lq * 4)] = pk;
            }
        }
        __syncthreads();   // zsT ready

        #pragma unroll
        for (int tn = 0; tn < 5; ++tn) {
            const bf16x8 b0 = *(const bf16x8*)&uC[swz64(tn * 16 + ln, lq * 8)];
            const bf16x8 b1 = *(const bf16x8*)&uC[swz64(tn * 16 + ln, lq * 8 + 32)];
            acc[tn] = __builtin_amdgcn_mfma_f32_16x16x32_bf16(ua.v, b0, acc[tn], 0, 0, 0);
            acc[tn] = __builtin_amdgcn_mfma_f32_16x16x32_bf16(ub.v, b1, acc[tn], 0, 0, 0);
        }
    }
    __syncthreads();   // GEMM-2 done reading zsT

    {
        const int c0 = w * 16 + lq * 4;
        float bb[4], ss[4], be[4];
        #pragma unroll
        for (int r = 0; r < 4; ++r) {
            bb[r] = bias3[c0 + r];
            ss[r] = bias3[64 + c0 + r];
            be[r] = bias3[128 + c0 + r];
        }
        #pragma unroll
        for (int tn = 0; tn < 5; ++tn) {
            const int p = tn * 16 + ln;   // < 80
            const uint2 u = *(const uint2*)&xsT[swz64(p, c0)];
            const float rs[4] = {blo(u.x), bhi(u.x), blo(u.y), bhi(u.y)};
            float y[4];
            #pragma unroll
            for (int r = 0; r < 4; ++r)
                y[r] = fmaxf((acc[tn][r] + bb[r]) * ss[r] + be[r] + rs[r], 0.f);
            uint2 pk;
            pk.x = (uint)f2bb(y[0]) | ((uint)f2bb(y[1]) << 16);
            pk.y = (uint)f2bb(y[2]) | ((uint)f2bb(y[3]) << 16);
            *(uint2*)&uC[swz64(p, c0)] = pk;
        }
    }
    __syncthreads();

    {
        const int v = tid & 15, ci = tid >> 4;
        if (v < V2) {
            #pragma unroll
            for (int r = 0; r < 4; ++r) {
                const int c = ci * 4 + r;
                const size_t base = (size_t)b * V2 * DD + (size_t)v * DD + c * TT + t0;
                const float4 o0 = *(const float4*)&Obuf[base];
                const float4 o1 = *(const float4*)&Obuf[base + 4];
                float4 y0, y1;
                y0.x = o0.x + b2f_us(uC[swz64(v * 8 + 0, c)]);
                y0.y = o0.y + b2f_us(uC[swz64(v * 8 + 1, c)]);
                y0.z = o0.z + b2f_us(uC[swz64(v * 8 + 2, c)]);
                y0.w = o0.w + b2f_us(uC[swz64(v * 8 + 3, c)]);
                y1.x = o1.x + b2f_us(uC[swz64(v * 8 + 4, c)]);
                y1.y = o1.y + b2f_us(uC[swz64(v * 8 + 5, c)]);
                y1.z = o1.z + b2f_us(uC[swz64(v * 8 + 6, c)]);
                y1.w = o1.w + b2f_us(uC[swz64(v * 8 + 7, c)]);
                *(float4*)&out_f[base] = y0;
                *(float4*)&out_f[base + 4] = y1;
            }
        }
    }
}

// ---------------------------------------------------------------------------
// attention: Kg/Vg head-major; contiguous 16KB slabs per (b,h). Unchanged.
// ---------------------------------------------------------------------------
__global__ __launch_bounds__(256) void attn_kernel(const float* __restrict__ Q,
                                                   const bf16* __restrict__ Kg,
                                                   const bf16* __restrict__ Vg,
                                                   float* __restrict__ O) {
    int b = blockIdx.x, h = blockIdx.y, tid = threadIdx.x;
    __shared__ float qs[10 * DSH];
    __shared__ float ks[V1 * 321];
    __shared__ float att[10 * V1];
    const float* Qb = Q + (size_t)b * 10 * DD + h * DSH;
    for (int e = tid; e < 10 * DSH; e += 256) {
        int q = e / DSH, d = e % DSH;
        qs[e] = Qb[(size_t)q * DD + d];
    }
    const bf16* Kb = Kg + (size_t)(b * NH + h) * HSLAB;
    for (int e = tid; e < V1 * TT; e += 256) {
        const int kk = e / TT, t = e % TT;
        const uint4 u = *(const uint4*)(Kb + (size_t)e * 8);
        const ushort* us = (const ushort*)&u;
        float* dst = &ks[kk * 321 + t];
        #pragma unroll
        for (int cl = 0; cl < 8; ++cl) dst[cl * 40] = b2f_us(us[cl]);
    }
    __syncthreads();
    const float scale = 0.019764235376052370f;  // 1/sqrt(2560)
    for (int e = tid; e < 10 * V1; e += 256) {
        int q = e / V1, kk = e % V1;
        float acc = 0.f;
        #pragma unroll 8
        for (int d = 0; d < DSH; ++d) acc += qs[q * DSH + d] * ks[kk * 321 + d];
        att[e] = acc * scale;
    }
    __syncthreads();
    if (tid < 10) {
        float mx = -1e30f;
        for (int k = 0; k < V1; ++k) mx = fmaxf(mx, att[tid * V1 + k]);
        float sum = 0.f;
        for (int k = 0; k < V1; ++k) {
            float e_ = expf(att[tid * V1 + k] - mx);
            att[tid * V1 + k] = e_;
            sum += e_;
        }
        float r = 1.0f / sum;
        for (int k = 0; k < V1; ++k) att[tid * V1 + k] *= r;
    }
    const bf16* Vb = Vg + (size_t)(b * NH + h) * HSLAB;
    for (int e = tid; e < V1 * TT; e += 256) {
        const int kk = e / TT, t = e % TT;
        const uint4 u = *(const uint4*)(Vb + (size_t)e * 8);
        const ushort* us = (const ushort*)&u;
        float* dst = &ks[kk * 321 + t];
        #pragma unroll
        for (int cl = 0; cl < 8; ++cl) dst[cl * 40] = b2f_us(us[cl]);
    }
    __syncthreads();
    float* Ob = O + (size_t)b * 10 * DD + h * DSH;
    for (int e = tid; e < 10 * DSH; e += 256) {
        int q = e / DSH, dl = e % DSH;
        float acc = 0.f;
        #pragma unroll
        for (int k = 0; k < V1; ++k) acc += att[q * V1 + k] * ks[k * 321 + dl];
        Ob[(size_t)q * DD + dl] = qs[e] + acc;
    }
}

// ---------------------------------------------------------------------------
extern "C" void kernel_launch(void* const* d_in, const int* in_sizes, int n_in,
                              void* d_out, int out_size, void* d_ws, size_t ws_size,
                              hipStream_t stream) {
    const float* Q = (const float*)d_in[0];
    const float* K = (const float*)d_in[1];
    const float* fck_PA = (const float*)d_in[2];
    const float* fck_Wa = (const float*)d_in[3];
    const float* fck_ba = (const float*)d_in[4];
    const float* fck_Wb = (const float*)d_in[5];
    const float* fck_bb = (const float*)d_in[6];
    const float* fck_Wd = (const float*)d_in[7];
    const float* fck_bd = (const float*)d_in[8];
    const float* fck_gamma = (const float*)d_in[9];
    const float* fck_beta = (const float*)d_in[10];
    const float* fcv_PA = (const float*)d_in[11];
    const float* fcv_Wa = (const float*)d_in[12];
    const float* fcv_ba = (const float*)d_in[13];
    const float* fcv_Wb = (const float*)d_in[14];
    const float* fcv_bb = (const float*)d_in[15];
    const float* fcv_Wd = (const float*)d_in[16];
    const float* fcv_bd = (const float*)d_in[17];
    const float* fcv_gamma = (const float*)d_in[18];
    const float* fcv_beta = (const float*)d_in[19];
    const float* fco_PA = (const float*)d_in[20];
    const float* fco_Wa = (const float*)d_in[21];
    const float* fco_ba = (const float*)d_in[22];
    const float* fco_Wb = (const float*)d_in[23];
    const float* fco_bb = (const float*)d_in[24];
    const float* fco_Wd = (const float*)d_in[25];
    const float* fco_bd = (const float*)d_in[26];
    const float* fco_gamma = (const float*)d_in[27];
    const float* fco_beta = (const float*)d_in[28];

    // Workspace map:
    //   [0, 32.768 MB)        Xbf (head-major bf16 K) — overwritten in place
    //                         by gcn_applyKV as Vg (same addressing).
    //   [32.768, 65.536)      Kg (head-major; dead after attn) — then SbfO
    //                         (393 KB) + Wdf3 (24.6 KB) for the fco tail.
    //   [65.536, 84.736)      Mpart (S3->reduce);  then O (attn->applyO)
    //   [65.536, 91.750)        O spans this region (disjoint lifetimes)
    //   [84.736, 87.882)      Sbf  (reduce->applyKV, dead before attn)
    //   [88.000, 88.197)      Wdf  (reduce->applyKV, dead before attn)
    //   [95.590, 95.615)      Wabf (prep->gcn_S3, fragment-ordered Wa/Wb)
    char* wsb = (char*)d_ws;
    bf16* Xbf = (bf16*)(wsb);
    bf16* Vg = (bf16*)(wsb);                     // in-place over Xbf
    bf16* Kg = (bf16*)(wsb + 32768000);
    float* Mpart = (float*)(wsb + 65536000);     // [5][256][6][625] fp32 = 19.2 MB
    float* O = (float*)(wsb + 65536000);         // 26.2 MB, live after applyKV
    ushort* Sbf = (ushort*)(wsb + 84736000);     // [256][2][3][32][32] bf16 = 3.1 MB
    ushort* Wdf = (ushort*)(wsb + 88000000);     // [2][3][4][64][16] bf16 = 192 KB
    ushort* SbfO = (ushort*)(wsb + 32768000);    // [256][3][16][16] bf16 = 393 KB (over dead Kg)
    ushort* Wdf3 = (ushort*)(wsb + 33300000);    // [3][4][64][16] bf16 = 24.6 KB
    ushort* Wabf = (ushort*)(wsb + 95590400);    // [3][4][64][16] bf16 = 24.6 KB

    prep_wabf<<<dim3(1), dim3(256), 0, stream>>>(
        fck_Wa, fck_Wb, fcv_Wa, fcv_Wb, Wabf);

    gcn_S3<<<dim3(BB * 5), dim3(512), 0, stream>>>(
        K, Wabf, fck_ba, fck_bb, fcv_ba, fcv_bb, Xbf, Mpart);

    reduce_softmax<<<dim3(BB, 6), dim3(128), 0, stream>>>(
        Mpart, fck_PA, fcv_PA, fck_Wd, fcv_Wd, Sbf, Wdf);

    gcn_applyKV<<<dim3(BB, 10), dim3(256), 0, stream>>>(
        Xbf, Sbf, Wdf,
        fck_bd, fck_gamma, fck_beta,
        fcv_bd, fcv_gamma, fcv_beta, Kg, Vg);

    attn_kernel<<<dim3(BB, NH), dim3(256), 0, stream>>>(Q, Kg, Vg, O);

    gcn_S2O<<<dim3(BB, 3), dim3(256), 0, stream>>>(
        O, fco_Wa, fco_ba, fco_Wb, fco_bb, fco_PA, fco_Wd, SbfO, Wdf3);

    gcn_applyO<<<dim3(BB, 5), dim3(256), 0, stream>>>(
        O, SbfO, Wdf3, fco_bd, fco_gamma, fco_beta, (float*)d_out, O);
}

// Round 8
// 422.950 us; speedup vs baseline: 1.7170x; 1.0555x over previous
//
#include <hip/hip_runtime.h>
#include <hip/hip_bf16.h>

#define BB 256
#define CC 64
#define TT 40
#define DD 2560   // CC*TT
#define V1 25
#define V2 10
#define INTER 16
#define NH 8
#define DSH 320   // DD/NH
#define HSLAB 8000  // V1*TT*8 elems per (b,h) slab in head-major layout

typedef __hip_bfloat16 bf16;
typedef unsigned int uint;
typedef unsigned short ushort;
typedef __attribute__((ext_vector_type(8))) short bf16x8;
typedef __attribute__((ext_vector_type(4))) float f32x4;

__device__ __forceinline__ float b2f(bf16 x) { return __bfloat162float(x); }

__device__ __forceinline__ ushort f2bb(float f) {
    uint x = __float_as_uint(f);
    uint r = x + 0x7fffu + ((x >> 16) & 1u);
    return (ushort)(r >> 16);
}
__device__ __forceinline__ float blo(uint u) { return __uint_as_float(u << 16); }
__device__ __forceinline__ float bhi(uint u) { return __uint_as_float(u & 0xffff0000u); }
__device__ __forceinline__ float b2f_us(ushort h) { return __uint_as_float(((uint)h) << 16); }
__device__ __forceinline__ uint4 pack8(const float* a) {
    uint4 pk;
    pk.x = (uint)f2bb(a[0]) | ((uint)f2bb(a[1]) << 16);
    pk.y = (uint)f2bb(a[2]) | ((uint)f2bb(a[3]) << 16);
    pk.z = (uint)f2bb(a[4]) | ((uint)f2bb(a[5]) << 16);
    pk.w = (uint)f2bb(a[6]) | ((uint)f2bb(a[7]) << 16);
    return pk;
}

// LDS swizzle helpers (ushort index). 64-ushort (128B) rows, 16B-granule XOR
// by low row bits -> every vectorized access pattern hits its bank floor.
__device__ __forceinline__ int swz64(int row, int col) {
    return row * 64 + ((((col >> 3) ^ row) & 7) << 3) + (col & 7);
}
// 128-ushort (256B) rows, granule XOR by (c&15)
__device__ __forceinline__ int swzC(int c, int col) {
    return c * 128 + ((((col >> 3) ^ c) & 15) << 3) + (col & 7);
}
// 320-ushort rows (attn): granule-XOR by row&7 (bijective within 8-granule grp)
__device__ __forceinline__ int swz320(int row, int k) {
    const int g = k >> 3;
    return row * 320 + (((g & ~7) | ((g ^ row) & 7)) << 3) + (k & 7);
}

// ---------------------------------------------------------------------------
// prep_wabf: 1 block. Pre-convert Wa/Wb (fck+fcv) into MFMA fragment order
// Wabf[s][mat][lane][16] so gcn_S3 reads proj A-frags straight from L2.
// ---------------------------------------------------------------------------
__global__ __launch_bounds__(256) void prep_wabf(
    const float* __restrict__ Wa0, const float* __restrict__ Wb0,
    const float* __restrict__ Wa1, const float* __restrict__ Wb1,
    ushort* __restrict__ Wabf) {
    const int tid = threadIdx.x;
    for (int e = tid; e < 768; e += 256) {
        const int lane = e & 63, mat = (e >> 6) & 3, s = e >> 8;
        const int ln = lane & 15, lq = lane >> 4;
        const float* Wp = (mat == 0) ? Wa0 : (mat == 1) ? Wb0 : (mat == 2) ? Wa1 : Wb1;
        const float* src = Wp + s * 1024 + ln * 64 + lq * 8;
        ushort* dst = Wabf + e * 16;
        #pragma unroll
        for (int i = 0; i < 8; ++i) {
            dst[i] = f2bb(src[i]);
            dst[8 + i] = f2bb(src[32 + i]);
        }
    }
}

// ---------------------------------------------------------------------------
// gcn_S3 (V=25, fck+fcv fused): grid = (tc*256 + b), 1280 blocks x 512 thr.
// ---------------------------------------------------------------------------
__global__ __launch_bounds__(512) void gcn_S3(
    const float* __restrict__ X,
    const ushort* __restrict__ Wabf,
    const float* __restrict__ ba0, const float* __restrict__ bb0,
    const float* __restrict__ ba1, const float* __restrict__ bb1,
    bf16* __restrict__ Xw, float* __restrict__ Mpart) {
    __shared__ ushort xsT[208][72];    // [p=v*8+tl][c]; rows 200..207 garbage
    __shared__ ushort abT[4][32][136]; // [mat][v][j*8+tl]
    __shared__ float biasS3[192];      // [s][mat*16+j]

    const int tid = threadIdx.x;
    const int b = blockIdx.x & 255, tc = blockIdx.x >> 8;
    const int t0 = tc * 8;
    const int lane = tid & 63, w = tid >> 6;       // w 0..7
    const int ln = lane & 15, lq = lane >> 4;
    const int mat = w & 3, half = w >> 2;

    const float* Xb = X + (size_t)b * V1 * DD;
    for (int e = tid; e < V1 * 64; e += 512) {
        const int v = e >> 6, c = e & 63;
        const float* src = Xb + (size_t)v * DD + c * TT + t0;
        const float4 f0 = *(const float4*)src;
        const float4 f1 = *(const float4*)(src + 4);
        const float tmp[8] = {f0.x, f0.y, f0.z, f0.w, f1.x, f1.y, f1.z, f1.w};
        #pragma unroll
        for (int tl = 0; tl < 8; ++tl) xsT[v * 8 + tl][c] = f2bb(tmp[tl]);
    }
    if (tid < 192) {
        const int s = tid >> 6, m2 = (tid >> 4) & 3, j = tid & 15;
        const float* bp = (m2 == 0) ? ba0 : (m2 == 1) ? bb0 : (m2 == 2) ? ba1 : bb1;
        biasS3[tid] = bp[s * 16 + j];
    }
    __syncthreads();                   // xsT + biasS3 complete

    for (int e = tid; e < 1600; e += 512) {
        const int v = e >> 6, h = (e >> 3) & 7, tl = e & 7;
        *(uint4*)(Xw + (size_t)(b * NH + h) * HSLAB + v * 320 + (t0 + tl) * 8) =
            *(const uint4*)&xsT[v * 8 + tl][h * 8];
    }

    for (int s = 0; s < 3; ++s) {
        const ushort* wp = Wabf + (((s * 4 + mat) * 64 + lane) << 4);
        union { uint4 u; bf16x8 v; } ua, ub;
        ua.u = *(const uint4*)wp;
        ub.u = *(const uint4*)(wp + 8);
        float br[4];
        #pragma unroll
        for (int r = 0; r < 4; ++r) br[r] = biasS3[s * 64 + mat * 16 + lq * 4 + r];

        if (s) __syncthreads();        // Gram[s-1] done reading abT

        const int ntEnd = half ? 13 : 7;
        for (int nt = half ? 7 : 0; nt < ntEnd; ++nt) {
            const bf16x8 b0 = *(const bf16x8*)&xsT[nt * 16 + ln][lq * 8];
            const bf16x8 b1 = *(const bf16x8*)&xsT[nt * 16 + ln][lq * 8 + 32];
            f32x4 acc = (f32x4){0.f, 0.f, 0.f, 0.f};
            acc = __builtin_amdgcn_mfma_f32_16x16x32_bf16(ua.v, b0, acc, 0, 0, 0);
            acc = __builtin_amdgcn_mfma_f32_16x16x32_bf16(ub.v, b1, acc, 0, 0, 0);
            const int p = nt * 16 + ln;
            if (p < 200) {
                const int v = p >> 3, tl = p & 7;
                #pragma unroll
                for (int r = 0; r < 4; ++r)
                    abT[mat][v][(lq * 4 + r) * 8 + tl] = f2bb(acc[r] + br[r]);
            }
        }
        __syncthreads();               // abT ready

        {
            const int np = w >> 2, mt = (w >> 1) & 1, ntl = w & 1;
            const ushort* Ap = &abT[np * 2 + 0][mt * 16 + ln][lq * 8];
            const ushort* Bp = &abT[np * 2 + 1][ntl * 16 + ln][lq * 8];
            f32x4 g = (f32x4){0.f, 0.f, 0.f, 0.f};
            g = __builtin_amdgcn_mfma_f32_16x16x32_bf16(
                    *(const bf16x8*)Ap, *(const bf16x8*)Bp, g, 0, 0, 0);
            g = __builtin_amdgcn_mfma_f32_16x16x32_bf16(
                    *(const bf16x8*)(Ap + 32), *(const bf16x8*)(Bp + 32), g, 0, 0, 0);
            g = __builtin_amdgcn_mfma_f32_16x16x32_bf16(
                    *(const bf16x8*)(Ap + 64), *(const bf16x8*)(Bp + 64), g, 0, 0, 0);
            g = __builtin_amdgcn_mfma_f32_16x16x32_bf16(
                    *(const bf16x8*)(Ap + 96), *(const bf16x8*)(Bp + 96), g, 0, 0, 0);
            const int vp = ntl * 16 + ln;
            if (vp < V1) {
                float* Mb = Mpart + (((size_t)tc * 256 + b) * 6 + (s * 2 + np)) * 625;
                #pragma unroll
                for (int r = 0; r < 4; ++r) {
                    const int v = mt * 16 + lq * 4 + r;
                    if (v < V1) Mb[v * V1 + vp] = g[r];
                }
            }
        }
    }
}

// ---------------------------------------------------------------------------
// reduce_softmax (unchanged).
// ---------------------------------------------------------------------------
__global__ __launch_bounds__(128) void reduce_softmax(
    const float* __restrict__ Mpart,
    const float* __restrict__ PA0, const float* __restrict__ PA1,
    const float* __restrict__ WdK, const float* __restrict__ WdV,
    ushort* __restrict__ Sbf, ushort* __restrict__ Wdf) {
    __shared__ float Ms[625];
    const int tid = threadIdx.x, b = blockIdx.x, snp = blockIdx.y;
    const int s = snp >> 1, np = snp & 1;

    if (b == 0) {
        for (int e = tid; e < 256; e += 128) {
            const int wv = e >> 6, l = e & 63;
            const int lnn = l & 15, lqq = l >> 4;
            const float* Wp = (np ? WdV : WdK) + s * 4096 + (wv * 16 + lnn) * 64 + lqq * 8;
            ushort* dst = Wdf + (((np * 3 + s) * 4 + wv) * 64 + l) * 16;
            #pragma unroll
            for (int j = 0; j < 8; ++j) {
                dst[j] = f2bb(Wp[j]);
                dst[8 + j] = f2bb(Wp[32 + j]);
            }
        }
    }

    for (int e = tid; e < 625; e += 128) {
        float sum = 0.f;
        #pragma unroll
        for (int tcc = 0; tcc < 5; ++tcc)
            sum += Mpart[(((size_t)tcc * 256 + b) * 6 + snp) * 625 + e];
        Ms[e] = sum;
    }
    __syncthreads();
    if (tid < 32) {
        ushort* SbfRow = Sbf + ((((size_t)b * 2 + np) * 3 + s) << 10) + tid * 32;
        if (tid < V1) {
            const int vp = tid;
            const float invIT = 1.0f / 640.0f;
            float mx = -1e30f;
            for (int v = 0; v < V1; ++v) mx = fmaxf(mx, Ms[v * V1 + vp]);
            float sum = 0.f;
            for (int v = 0; v < V1; ++v) sum += expf((Ms[v * V1 + vp] - mx) * invIT);
            const float rs = 1.f / sum;
            const float* PAn = np ? PA1 : PA0;
            for (int v = 0; v < V1; ++v) {
                const float e_ = expf((Ms[v * V1 + vp] - mx) * invIT);
                SbfRow[v] = f2bb(e_ * rs + PAn[(s * V1 + v) * V1 + vp]);
            }
            for (int v = V1; v < 32; ++v) SbfRow[v] = 0;
        } else {
            for (int v = 0; v < 32; ++v) SbfRow[v] = 0;
        }
    }
}

// ---------------------------------------------------------------------------
// gcn_S2O (V=10 fco, unchanged).
// ---------------------------------------------------------------------------
__global__ __launch_bounds__(256) void gcn_S2O(
    const float* __restrict__ X,
    const float* __restrict__ Wa0, const float* __restrict__ ba0,
    const float* __restrict__ Wb0, const float* __restrict__ bb0,
    const float* __restrict__ PA0, const float* __restrict__ WdO,
    ushort* __restrict__ SbfO, ushort* __restrict__ Wdf3) {
    constexpr int V = V2;      // 10
    constexpr int P = 80;      // V*8
    __shared__ ushort xs[64][P];
    __shared__ ushort ab[32][P];
    __shared__ ushort wT[64][32];
    __shared__ float biasL[32];
    __shared__ float M[100];

    const int tid = threadIdx.x, b = blockIdx.x, s = blockIdx.y;

    if (b == 0) {
        const int e = tid;
        if (e < 256) {
            const int wv = e >> 6, l = e & 63;
            const int lnn = l & 15, lqq = l >> 4;
            const float* Wp = WdO + s * 4096 + (wv * 16 + lnn) * 64 + lqq * 8;
            ushort* dst = Wdf3 + (((s * 4 + wv) * 64 + l) << 4);
            #pragma unroll
            for (int j = 0; j < 8; ++j) {
                dst[j] = f2bb(Wp[j]);
                dst[8 + j] = f2bb(Wp[32 + j]);
            }
        }
    }

    for (int e = tid; e < 16 * 64; e += 256) {
        int c = e & 63, j = e >> 6;
        wT[c][j]      = f2bb(Wa0[s * 1024 + e]);
        wT[c][16 + j] = f2bb(Wb0[s * 1024 + e]);
    }
    if (tid < 16) {
        biasL[tid]      = ba0[s * 16 + tid];
        biasL[16 + tid] = bb0[s * 16 + tid];
    }

    float macc = 0.f;

    const float* Xb = X + (size_t)b * V * DD;
    for (int tc = 0; tc < 5; ++tc) {
        const int t0 = tc * 8;
        for (int e = tid; e < V * 64; e += 256) {
            const int v = e >> 6, c = e & 63;
            const float* src = Xb + (size_t)v * DD + c * TT + t0;
            const float4 f0 = *(const float4*)src;
            const float4 f1 = *(const float4*)(src + 4);
            const float tmp[8] = {f0.x, f0.y, f0.z, f0.w, f1.x, f1.y, f1.z, f1.w};
            *(uint4*)&xs[c][v * 8] = pack8(tmp);
        }
        __syncthreads();
        for (int tau = tid; tau < 80; tau += 256) {
            const int rq = tau % 8, co = tau / 8;
            float acc[4][8];
            #pragma unroll
            for (int r = 0; r < 4; ++r) {
                const float bv = biasL[4 * rq + r];
                #pragma unroll
                for (int cc = 0; cc < 8; ++cc) acc[r][cc] = bv;
            }
            for (int c = 0; c < 64; ++c) {
                const uint2 wv = *(const uint2*)&wT[c][4 * rq];
                const uint4 xv = *(const uint4*)&xs[c][8 * co];
                const float w0 = blo(wv.x), w1 = bhi(wv.x);
                const float w2 = blo(wv.y), w3 = bhi(wv.y);
                const float x0 = blo(xv.x), x1 = bhi(xv.x);
                const float x2 = blo(xv.y), x3 = bhi(xv.y);
                const float x4 = blo(xv.z), x5 = bhi(xv.z);
                const float x6 = blo(xv.w), x7 = bhi(xv.w);
                acc[0][0] += w0 * x0; acc[0][1] += w0 * x1;
                acc[0][2] += w0 * x2; acc[0][3] += w0 * x3;
                acc[0][4] += w0 * x4; acc[0][5] += w0 * x5;
                acc[0][6] += w0 * x6; acc[0][7] += w0 * x7;
                acc[1][0] += w1 * x0; acc[1][1] += w1 * x1;
                acc[1][2] += w1 * x2; acc[1][3] += w1 * x3;
                acc[1][4] += w1 * x4; acc[1][5] += w1 * x5;
                acc[1][6] += w1 * x6; acc[1][7] += w1 * x7;
                acc[2][0] += w2 * x0; acc[2][1] += w2 * x1;
                acc[2][2] += w2 * x2; acc[2][3] += w2 * x3;
                acc[2][4] += w2 * x4; acc[2][5] += w2 * x5;
                acc[2][6] += w2 * x6; acc[2][7] += w2 * x7;
                acc[3][0] += w3 * x0; acc[3][1] += w3 * x1;
                acc[3][2] += w3 * x2; acc[3][3] += w3 * x3;
                acc[3][4] += w3 * x4; acc[3][5] += w3 * x5;
                acc[3][6] += w3 * x6; acc[3][7] += w3 * x7;
            }
            #pragma unroll
            for (int r = 0; r < 4; ++r)
                *(uint4*)&ab[4 * rq + r][8 * co] = pack8(acc[r]);
        }
        __syncthreads();
        if (tid < 100) {
            const int v = tid / V, vp = tid % V;
            float mm = 0.f;
            #pragma unroll
            for (int j = 0; j < 16; ++j) {
                const uint4 av = *(const uint4*)&ab[j][v * 8];
                const uint4 bv = *(const uint4*)&ab[16 + j][vp * 8];
                mm += blo(av.x) * blo(bv.x) + bhi(av.x) * bhi(bv.x)
                    + blo(av.y) * blo(bv.y) + bhi(av.y) * bhi(bv.y)
                    + blo(av.z) * blo(bv.z) + bhi(av.z) * bhi(bv.z)
                    + blo(av.w) * blo(bv.w) + bhi(av.w) * bhi(bv.w);
            }
            macc += mm;
        }
    }

    if (tid < 100) M[tid] = macc;
    __syncthreads();

    const float invIT = 1.0f / 640.0f;
    if (tid < 16) {
        ushort* So = SbfO + ((size_t)b * 3 + s) * 256 + tid * 16;
        if (tid < V) {
            const int vp = tid;
            float mx = -1e30f;
            for (int v = 0; v < V; ++v) mx = fmaxf(mx, M[v * V + vp]);
            float sum = 0.f;
            for (int v = 0; v < V; ++v) sum += expf((M[v * V + vp] - mx) * invIT);
            const float rs = 1.f / sum;
            for (int v = 0; v < V; ++v) {
                const float e_ = expf((M[v * V + vp] - mx) * invIT);
                So[v] = f2bb(e_ * rs + PA0[(s * V + v) * V + vp]);
            }
            for (int v = V; v < 16; ++v) So[v] = 0;
        } else {
            for (int v = 0; v < 16; ++v) So[v] = 0;
        }
    }
}

// ---------------------------------------------------------------------------
// gcn_applyKV (unchanged, verified).
// ---------------------------------------------------------------------------
__global__ __launch_bounds__(256) void gcn_applyKV(
    const bf16* __restrict__ Xbf,
    const ushort* __restrict__ Sbf, const ushort* __restrict__ Wdf,
    const float* __restrict__ bdK, const float* __restrict__ gK, const float* __restrict__ beK,
    const float* __restrict__ bdV, const float* __restrict__ gV, const float* __restrict__ beV,
    bf16* __restrict__ Kg, bf16* __restrict__ Vg) {

    __shared__ ushort xsT[100 * 64];   // [p=v*4+tl][c], swz64 (persist)
    __shared__ ushort SlTs[6144];      // [(g*3+s)*1024 + vp*32 + v0] (persist)
    __shared__ ushort uC[8192];        // xsC [c][tl*32+v0] swzC, then zsT [p][c] swz64
    __shared__ float bias6[6 * 64];

    const int tid = threadIdx.x, b = blockIdx.x, chunk = blockIdx.y;
    const int lane = tid & 63, w = tid >> 6;
    const int ln = lane & 15, lq = lane >> 4;
    const int t0 = chunk * 4;

    if (tid < 64) {
        bias6[tid]       = bdK[tid] + bdK[64 + tid] + bdK[128 + tid];
        bias6[64 + tid]  = bdV[tid] + bdV[64 + tid] + bdV[128 + tid];
        bias6[128 + tid] = gK[tid] * rsqrtf(1.f + 1e-5f);
        bias6[192 + tid] = gV[tid] * rsqrtf(1.f + 1e-5f);
        bias6[256 + tid] = beK[tid];
        bias6[320 + tid] = beV[tid];
    }
    const bf16* Xb = Xbf + (size_t)b * NH * HSLAB;
    for (int e = tid; e < 1024; e += 256) {
        const int h = e >> 7, v = (e >> 2) & 31, tl = e & 3;
        if (v < V1)
            *(uint4*)&xsT[swz64(v * 4 + tl, h * 8)] =
                *(const uint4*)(Xb + (size_t)h * HSLAB + v * 320 + (t0 + tl) * 8);
    }
    {
        const ushort* Sb = Sbf + (size_t)b * 6144;
        for (int e = tid; e < 768; e += 256)
            ((uint4*)SlTs)[e] = ((const uint4*)Sb)[e];
    }
    __syncthreads();   // xsT + SlTs staged

    {
        const int c = lane, q = w;
        #pragma unroll
        for (int j = 0; j < 4; ++j) {
            ushort vals[8];
            #pragma unroll
            for (int i = 0; i < 8; ++i) {
                const int v0 = q * 8 + i;
                vals[i] = (v0 < V1) ? xsT[swz64(v0 * 4 + j, c)] : (ushort)0;
            }
            uint4 pk;
            pk.x = (uint)vals[0] | ((uint)vals[1] << 16);
            pk.y = (uint)vals[2] | ((uint)vals[3] << 16);
            pk.z = (uint)vals[4] | ((uint)vals[5] << 16);
            pk.w = (uint)vals[6] | ((uint)vals[7] << 16);
            *(uint4*)&uC[swzC(c, j * 32 + q * 8)] = pk;
        }
    }
    __syncthreads();   // xsC ready

    bf16x8 aF[4];
    #pragma unroll
    for (int tl = 0; tl < 4; ++tl)
        aF[tl] = *(const bf16x8*)&uC[swzC(w * 16 + ln, tl * 32 + lq * 8)];
    __syncthreads();   // aF reads done -> uC becomes zsT

    for (int g = 0; g < 2; ++g) {
        f32x4 acc[7];
        #pragma unroll
        for (int tn = 0; tn < 7; ++tn) acc[tn] = (f32x4){0.f, 0.f, 0.f, 0.f};

        for (int s = 0; s < 3; ++s) {
            const ushort* wp = Wdf + ((((g * 3 + s) * 4 + w) * 64 + lane) << 4);
            union { uint4 u; bf16x8 v; } ua, ub;
            ua.u = *(const uint4*)wp;
            ub.u = *(const uint4*)(wp + 8);

            if (g | s) __syncthreads();

            #pragma unroll
            for (int nt = 0; nt < 2; ++nt) {
                const bf16x8 bF =
                    *(const bf16x8*)&SlTs[((g * 3 + s) << 10) + (nt * 16 + ln) * 32 + lq * 8];
                const int v = nt * 16 + ln;
                #pragma unroll
                for (int tl = 0; tl < 4; ++tl) {
                    f32x4 d = (f32x4){0.f, 0.f, 0.f, 0.f};
                    d = __builtin_amdgcn_mfma_f32_16x16x32_bf16(aF[tl], bF, d, 0, 0, 0);
                    if (v < V1) {
                        uint2 pk;
                        pk.x = (uint)f2bb(d[0]) | ((uint)f2bb(d[1]) << 16);
                        pk.y = (uint)f2bb(d[2]) | ((uint)f2bb(d[3]) << 16);
                        *(uint2*)&uC[swz64(v * 4 + tl, w * 16 + lq * 4)] = pk;
                    }
                }
            }
            __syncthreads();   // zsT ready

            #pragma unroll
            for (int tn = 0; tn < 7; ++tn) {
                const bf16x8 b0 = *(const bf16x8*)&uC[swz64(tn * 16 + ln, lq * 8)];
                const bf16x8 b1 = *(const bf16x8*)&uC[swz64(tn * 16 + ln, lq * 8 + 32)];
                acc[tn] = __builtin_amdgcn_mfma_f32_16x16x32_bf16(ua.v, b0, acc[tn], 0, 0, 0);
                acc[tn] = __builtin_amdgcn_mfma_f32_16x16x32_bf16(ub.v, b1, acc[tn], 0, 0, 0);
            }
        }
        __syncthreads();   // GEMM-2 done reading zsT

        {
            const int c0 = w * 16 + lq * 4;
            float bb[4], ss[4], be[4];
            #pragma unroll
            for (int r = 0; r < 4; ++r) {
                bb[r] = bias6[g * 64 + c0 + r];
                ss[r] = bias6[128 + g * 64 + c0 + r];
                be[r] = bias6[256 + g * 64 + c0 + r];
            }
            #pragma unroll
            for (int tn = 0; tn < 7; ++tn) {
                const int p = tn * 16 + ln;
                if (p < 100) {
                    const uint2 u = *(const uint2*)&xsT[swz64(p, c0)];
                    const float rs[4] = {blo(u.x), bhi(u.x), blo(u.y), bhi(u.y)};
                    float y[4];
                    #pragma unroll
                    for (int r = 0; r < 4; ++r)
                        y[r] = fmaxf((acc[tn][r] + bb[r]) * ss[r] + be[r] + rs[r], 0.f);
                    uint2 pk;
                    pk.x = (uint)f2bb(y[0]) | ((uint)f2bb(y[1]) << 16);
                    pk.y = (uint)f2bb(y[2]) | ((uint)f2bb(y[3]) << 16);
                    *(uint2*)&uC[swz64(p, c0)] = pk;
                }
            }
        }
        __syncthreads();

        bf16* outp = (g ? Vg : Kg) + (size_t)b * NH * HSLAB;
        for (int e = tid; e < 1024; e += 256) {
            const int h = e >> 7, v = (e >> 2) & 31, tl = e & 3;
            if (v < V1)
                *(uint4*)(outp + (size_t)h * HSLAB + v * 320 + (t0 + tl) * 8) =
                    *(const uint4*)&uC[swz64(v * 4 + tl, h * 8)];
        }
    }
}

// ---------------------------------------------------------------------------
// gcn_applyO (unchanged).
// ---------------------------------------------------------------------------
__global__ __launch_bounds__(256) void gcn_applyO(
    const float* __restrict__ X,            // O fp32 (b, v=10, c, t)
    const ushort* __restrict__ SbfO, const ushort* __restrict__ Wdf3,
    const float* __restrict__ bdO, const float* __restrict__ gO, const float* __restrict__ beO,
    float* __restrict__ out_f, const float* __restrict__ Obuf) {

    __shared__ ushort xsT[80 * 64];    // [p=v*8+tl][c], swz64 (persist: residual)
    __shared__ ushort uC[8192];        // xsC16 [c][tl*16+v0] swzC, then zsT [p][c] swz64
    __shared__ ushort SlTs16[832];     // [s][v][v0] 3*16*16 (+spec-pad)
    __shared__ float bias3[3 * 64];

    const int tid = threadIdx.x, b = blockIdx.x, chunk = blockIdx.y;
    const int lane = tid & 63, w = tid >> 6;
    const int ln = lane & 15, lq = lane >> 4;
    const int t0 = chunk * 8;

    if (tid < 64) {
        bias3[tid]       = bdO[tid] + bdO[64 + tid] + bdO[128 + tid];
        bias3[64 + tid]  = gO[tid] * rsqrtf(1.f + 1e-5f);
        bias3[128 + tid] = beO[tid];
    }
    const float* Xb = X + (size_t)b * V2 * DD;
    for (int e = tid; e < 640; e += 256) {
        const int v = e >> 6, c = e & 63;
        const float* src = Xb + (size_t)v * DD + c * TT + t0;
        const float4 f0 = *(const float4*)src;
        const float4 f1 = *(const float4*)(src + 4);
        const float tmp[8] = {f0.x, f0.y, f0.z, f0.w, f1.x, f1.y, f1.z, f1.w};
        #pragma unroll
        for (int tl = 0; tl < 8; ++tl) xsT[swz64(v * 8 + tl, c)] = f2bb(tmp[tl]);
    }
    {
        const uint4* Sb = (const uint4*)(SbfO + (size_t)b * 768);
        for (int e = tid; e < 96; e += 256) ((uint4*)SlTs16)[e] = Sb[e];
    }
    __syncthreads();   // xsT + SlTs16 staged

    {
        const int c = lane;
        #pragma unroll
        for (int jj = 0; jj < 4; ++jj) {
            const int u_ = w * 4 + jj;            // 16 combos: tl(8) x q(2)
            const int tl = u_ >> 1, q = u_ & 1;
            ushort vals[8];
            #pragma unroll
            for (int i = 0; i < 8; ++i) {
                const int v0 = q * 8 + i;
                vals[i] = (v0 < V2) ? xsT[swz64(v0 * 8 + tl, c)] : (ushort)0;
            }
            uint4 pk;
            pk.x = (uint)vals[0] | ((uint)vals[1] << 16);
            pk.y = (uint)vals[2] | ((uint)vals[3] << 16);
            pk.z = (uint)vals[4] | ((uint)vals[5] << 16);
            pk.w = (uint)vals[6] | ((uint)vals[7] << 16);
            *(uint4*)&uC[swzC(c, tl * 16 + q * 8)] = pk;
        }
    }
    __syncthreads();   // xsC16 ready

    union { uint4 u; bf16x8 v; } z8; z8.u = (uint4){0u, 0u, 0u, 0u};
    bf16x8 aF[8];
    #pragma unroll
    for (int tl = 0; tl < 8; ++tl)
        aF[tl] = (lq < 2) ? *(const bf16x8*)&uC[swzC(w * 16 + ln, tl * 16 + lq * 8)]
                          : z8.v;
    __syncthreads();   // aF reads done -> uC becomes zsT

    f32x4 acc[5];
    #pragma unroll
    for (int tn = 0; tn < 5; ++tn) acc[tn] = (f32x4){0.f, 0.f, 0.f, 0.f};

    for (int s = 0; s < 3; ++s) {
        const ushort* wp = Wdf3 + (((s * 4 + w) * 64 + lane) << 4);
        union { uint4 u; bf16x8 v; } ua, ub;
        ua.u = *(const uint4*)wp;
        ub.u = *(const uint4*)(wp + 8);

        if (s) __syncthreads();   // prior GEMM-2 done with zsT

        const bf16x8 bF = (lq < 2)
            ? *(const bf16x8*)&SlTs16[s * 256 + ln * 16 + lq * 8] : z8.v;
        #pragma unroll
        for (int tl = 0; tl < 8; ++tl) {
            f32x4 d = (f32x4){0.f, 0.f, 0.f, 0.f};
            d = __builtin_amdgcn_mfma_f32_16x16x32_bf16(aF[tl], bF, d, 0, 0, 0);
            if (ln < V2) {    // col = ln -> v
                uint2 pk;
                pk.x = (uint)f2bb(d[0]) | ((uint)f2bb(d[1]) << 16);
                pk.y = (uint)f2bb(d[2]) | ((uint)f2bb(d[3]) << 16);
                *(uint2*)&uC[swz64(ln * 8 + tl, w * 16 + lq * 4)] = pk;
            }
        }
        __syncthreads();   // zsT ready

        #pragma unroll
        for (int tn = 0; tn < 5; ++tn) {
            const bf16x8 b0 = *(const bf16x8*)&uC[swz64(tn * 16 + ln, lq * 8)];
            const bf16x8 b1 = *(const bf16x8*)&uC[swz64(tn * 16 + ln, lq * 8 + 32)];
            acc[tn] = __builtin_amdgcn_mfma_f32_16x16x32_bf16(ua.v, b0, acc[tn], 0, 0, 0);
            acc[tn] = __builtin_amdgcn_mfma_f32_16x16x32_bf16(ub.v, b1, acc[tn], 0, 0, 0);
        }
    }
    __syncthreads();   // GEMM-2 done reading zsT

    {
        const int c0 = w * 16 + lq * 4;
        float bb[4], ss[4], be[4];
        #pragma unroll
        for (int r = 0; r < 4; ++r) {
            bb[r] = bias3[c0 + r];
            ss[r] = bias3[64 + c0 + r];
            be[r] = bias3[128 + c0 + r];
        }
        #pragma unroll
        for (int tn = 0; tn < 5; ++tn) {
            const int p = tn * 16 + ln;   // < 80
            const uint2 u = *(const uint2*)&xsT[swz64(p, c0)];
            const float rs[4] = {blo(u.x), bhi(u.x), blo(u.y), bhi(u.y)};
            float y[4];
            #pragma unroll
            for (int r = 0; r < 4; ++r)
                y[r] = fmaxf((acc[tn][r] + bb[r]) * ss[r] + be[r] + rs[r], 0.f);
            uint2 pk;
            pk.x = (uint)f2bb(y[0]) | ((uint)f2bb(y[1]) << 16);
            pk.y = (uint)f2bb(y[2]) | ((uint)f2bb(y[3]) << 16);
            *(uint2*)&uC[swz64(p, c0)] = pk;
        }
    }
    __syncthreads();

    {
        const int v = tid & 15, ci = tid >> 4;
        if (v < V2) {
            #pragma unroll
            for (int r = 0; r < 4; ++r) {
                const int c = ci * 4 + r;
                const size_t base = (size_t)b * V2 * DD + (size_t)v * DD + c * TT + t0;
                const float4 o0 = *(const float4*)&Obuf[base];
                const float4 o1 = *(const float4*)&Obuf[base + 4];
                float4 y0, y1;
                y0.x = o0.x + b2f_us(uC[swz64(v * 8 + 0, c)]);
                y0.y = o0.y + b2f_us(uC[swz64(v * 8 + 1, c)]);
                y0.z = o0.z + b2f_us(uC[swz64(v * 8 + 2, c)]);
                y0.w = o0.w + b2f_us(uC[swz64(v * 8 + 3, c)]);
                y1.x = o1.x + b2f_us(uC[swz64(v * 8 + 4, c)]);
                y1.y = o1.y + b2f_us(uC[swz64(v * 8 + 5, c)]);
                y1.z = o1.z + b2f_us(uC[swz64(v * 8 + 6, c)]);
                y1.w = o1.w + b2f_us(uC[swz64(v * 8 + 7, c)]);
                *(float4*)&out_f[base] = y0;
                *(float4*)&out_f[base + 4] = y1;
            }
        }
    }
}

// ---------------------------------------------------------------------------
// attention (MFMA QK + float4 PV):
//   QK^T via mfma_16x16x32 with Q hi/lo bf16 split (error ~ fp32xbf16).
//   k-order = slab order (k = t*8+cl): K B-frags read straight from staged
//   slab; Q staged in k-order. A/B-frag recipe identical to applyKV (proven):
//   frag lane (ln,lq) reads rows[idx=ln][k@lq*8]; D[m=lq*4+r][n=ln].
//   4 waves: ntl = w&1 (kk tile), khalf = w>>1 (k-chunks 0-4 / 5-9);
//   partials summed in LDS. PV stays VALU but float4 (stride-324 V buffer,
//   odd granule count -> conflict-free b128). Residual re-reads Q from
//   global (L2-hot: same block staged it). Rows q>=10 / kk>=25 of the MFMA
//   tiles are garbage but land only in discarded D rows/cols.
// ---------------------------------------------------------------------------
__global__ __launch_bounds__(256) void attn_kernel(const float* __restrict__ Q,
                                                   const bf16* __restrict__ Kg,
                                                   const bf16* __restrict__ Vg,
                                                   float* __restrict__ O) {
    __shared__ float smA[10240];       // 40,960B: qs2h+qs2l+ksw (bf16) -> vbuf fp32
    __shared__ float attP[4][16][16];  // per-wave QK partials
    __shared__ float attF[16][32];     // combined scores -> probabilities
    ushort* qs2h = (ushort*)smA;               // [16][320] swz320 (rows>=10 garbage)
    ushort* qs2l = (ushort*)smA + 5120;        // [16][320] swz320
    ushort* ksw  = (ushort*)smA + 10240;       // [32][320] swz320 (rows>=25 garbage)
    float* vbuf = smA;                         // [25][324] fp32 (overlays after QK)

    const int b = blockIdx.x, h = blockIdx.y, tid = threadIdx.x;
    const int lane = tid & 63, w = tid >> 6;
    const int ln = lane & 15, lq = lane >> 4;

    // ---- stage Q (hi/lo bf16, k-order) + K (direct slab copy, swizzled) ----
    const float* Qb = Q + (size_t)b * 10 * DD + h * DSH;
    for (int e = tid; e < 800; e += 256) {
        const int q = e / 80, seg = e % 80;
        const int dd0 = seg * 4;
        const float4 f = *(const float4*)(Qb + (size_t)q * DD + dd0);
        const float ff[4] = {f.x, f.y, f.z, f.w};
        #pragma unroll
        for (int j = 0; j < 4; ++j) {
            const int dd = dd0 + j;
            const int k = (dd % 40) * 8 + dd / 40;   // slab k-order
            const int idx = swz320(q, k);
            const ushort hi = f2bb(ff[j]);
            qs2h[idx] = hi;
            qs2l[idx] = f2bb(ff[j] - b2f_us(hi));
        }
    }
    const bf16* Kb = Kg + (size_t)(b * NH + h) * HSLAB;
    for (int e = tid; e < 1000; e += 256) {
        const int kk = e / 40, g = e % 40;
        const int gp = (g & ~7) | ((g ^ kk) & 7);
        *(uint4*)&ksw[kk * 320 + gp * 8] = *(const uint4*)(Kb + (size_t)e * 8);
    }
    __syncthreads();

    // ---- QK^T MFMA: wave w -> (ntl = w&1, k-chunks (w>>1)*5 .. +4) ----
    {
        const int ntl = w & 1;
        const int ch0 = (w >> 1) * 5;
        f32x4 d = (f32x4){0.f, 0.f, 0.f, 0.f};
        #pragma unroll
        for (int c5 = 0; c5 < 5; ++c5) {
            const int k0 = (ch0 + c5) * 32 + lq * 8;
            const bf16x8 ah = *(const bf16x8*)&qs2h[swz320(ln, k0)];
            const bf16x8 al = *(const bf16x8*)&qs2l[swz320(ln, k0)];
            const bf16x8 bF = *(const bf16x8*)&ksw[swz320(ntl * 16 + ln, k0)];
            d = __builtin_amdgcn_mfma_f32_16x16x32_bf16(ah, bF, d, 0, 0, 0);
            d = __builtin_amdgcn_mfma_f32_16x16x32_bf16(al, bF, d, 0, 0, 0);
        }
        #pragma unroll
        for (int r = 0; r < 4; ++r) attP[w][lq * 4 + r][ln] = d[r];
    }
    __syncthreads();   // attP complete; qs2/ksw dead

    // ---- combine partials + scale; stage V fp32 (stride 324) over smA ----
    const float scale = 0.019764235376052370f;  // 1/sqrt(2560)
    for (int e = tid; e < 512; e += 256) {
        const int q = e >> 5, kk = e & 31;
        const int ntl = kk >> 4, kkl = kk & 15;
        attF[q][kk] = (attP[ntl][q][kkl] + attP[ntl + 2][q][kkl]) * scale;
    }
    const bf16* Vb = Vg + (size_t)(b * NH + h) * HSLAB;
    for (int e = tid; e < 1000; e += 256) {
        const int kk = e / TT, t = e % TT;
        const uint4 u = *(const uint4*)(Vb + (size_t)e * 8);
        const ushort* us = (const ushort*)&u;
        float* dst = &vbuf[kk * 324 + t];
        #pragma unroll
        for (int cl = 0; cl < 8; ++cl) dst[cl * 40] = b2f_us(us[cl]);
    }
    __syncthreads();   // attF raw scores + vbuf ready

    // ---- softmax over kk per q row ----
    if (tid < 10) {
        float mx = -1e30f;
        for (int k = 0; k < V1; ++k) mx = fmaxf(mx, attF[tid][k]);
        float sum = 0.f;
        for (int k = 0; k < V1; ++k) {
            float e_ = expf(attF[tid][k] - mx);
            attF[tid][k] = e_;
            sum += e_;
        }
        float r = 1.0f / sum;
        for (int k = 0; k < V1; ++k) attF[tid][k] *= r;
    }
    __syncthreads();

    // ---- PV (float4) + residual from global Q (L2-hot) ----
    float* Ob = O + (size_t)b * 10 * DD + h * DSH;
    for (int e = tid; e < 800; e += 256) {
        const int q = e / 80, seg = e % 80;
        const int dl0 = seg * 4;
        float ax = 0.f, ay = 0.f, az = 0.f, aw = 0.f;
        #pragma unroll
        for (int kk = 0; kk < V1; ++kk) {
            const float a = attF[q][kk];
            const float4 v = *(const float4*)&vbuf[kk * 324 + dl0];
            ax += a * v.x; ay += a * v.y; az += a * v.z; aw += a * v.w;
        }
        const float4 qv = *(const float4*)(Qb + (size_t)q * DD + dl0);
        float4 o;
        o.x = qv.x + ax; o.y = qv.y + ay; o.z = qv.z + az; o.w = qv.w + aw;
        *(float4*)(Ob + (size_t)q * DD + dl0) = o;
    }
}

// ---------------------------------------------------------------------------
extern "C" void kernel_launch(void* const* d_in, const int* in_sizes, int n_in,
                              void* d_out, int out_size, void* d_ws, size_t ws_size,
                              hipStream_t stream) {
    const float* Q = (const float*)d_in[0];
    const float* K = (const float*)d_in[1];
    const float* fck_PA = (const float*)d_in[2];
    const float* fck_Wa = (const float*)d_in[3];
    const float* fck_ba = (const float*)d_in[4];
    const float* fck_Wb = (const float*)d_in[5];
    const float* fck_bb = (const float*)d_in[6];
    const float* fck_Wd = (const float*)d_in[7];
    const float* fck_bd = (const float*)d_in[8];
    const float* fck_gamma = (const float*)d_in[9];
    const float* fck_beta = (const float*)d_in[10];
    const float* fcv_PA = (const float*)d_in[11];
    const float* fcv_Wa = (const float*)d_in[12];
    const float* fcv_ba = (const float*)d_in[13];
    const float* fcv_Wb = (const float*)d_in[14];
    const float* fcv_bb = (const float*)d_in[15];
    const float* fcv_Wd = (const float*)d_in[16];
    const float* fcv_bd = (const float*)d_in[17];
    const float* fcv_gamma = (const float*)d_in[18];
    const float* fcv_beta = (const float*)d_in[19];
    const float* fco_PA = (const float*)d_in[20];
    const float* fco_Wa = (const float*)d_in[21];
    const float* fco_ba = (const float*)d_in[22];
    const float* fco_Wb = (const float*)d_in[23];
    const float* fco_bb = (const float*)d_in[24];
    const float* fco_Wd = (const float*)d_in[25];
    const float* fco_bd = (const float*)d_in[26];
    const float* fco_gamma = (const float*)d_in[27];
    const float* fco_beta = (const float*)d_in[28];

    // Workspace map (unchanged from round 7).
    char* wsb = (char*)d_ws;
    bf16* Xbf = (bf16*)(wsb);
    bf16* Vg = (bf16*)(wsb);                     // in-place over Xbf
    bf16* Kg = (bf16*)(wsb + 32768000);
    float* Mpart = (float*)(wsb + 65536000);     // [5][256][6][625] fp32 = 19.2 MB
    float* O = (float*)(wsb + 65536000);         // 26.2 MB, live after applyKV
    ushort* Sbf = (ushort*)(wsb + 84736000);     // [256][2][3][32][32] bf16 = 3.1 MB
    ushort* Wdf = (ushort*)(wsb + 88000000);     // [2][3][4][64][16] bf16 = 192 KB
    ushort* SbfO = (ushort*)(wsb + 32768000);    // [256][3][16][16] bf16 (over dead Kg)
    ushort* Wdf3 = (ushort*)(wsb + 33300000);    // [3][4][64][16] bf16 = 24.6 KB
    ushort* Wabf = (ushort*)(wsb + 95590400);    // [3][4][64][16] bf16 = 24.6 KB

    prep_wabf<<<dim3(1), dim3(256), 0, stream>>>(
        fck_Wa, fck_Wb, fcv_Wa, fcv_Wb, Wabf);

    gcn_S3<<<dim3(BB * 5), dim3(512), 0, stream>>>(
        K, Wabf, fck_ba, fck_bb, fcv_ba, fcv_bb, Xbf, Mpart);

    reduce_softmax<<<dim3(BB, 6), dim3(128), 0, stream>>>(
        Mpart, fck_PA, fcv_PA, fck_Wd, fcv_Wd, Sbf, Wdf);

    gcn_applyKV<<<dim3(BB, 10), dim3(256), 0, stream>>>(
        Xbf, Sbf, Wdf,
        fck_bd, fck_gamma, fck_beta,
        fcv_bd, fcv_gamma, fcv_beta, Kg, Vg);

    attn_kernel<<<dim3(BB, NH), dim3(256), 0, stream>>>(Q, Kg, Vg, O);

    gcn_S2O<<<dim3(BB, 3), dim3(256), 0, stream>>>(
        O, fco_Wa, fco_ba, fco_Wb, fco_bb, fco_PA, fco_Wd, SbfO, Wdf3);

    gcn_applyO<<<dim3(BB, 5), dim3(256), 0, stream>>>(
        O, SbfO, Wdf3, fco_bd, fco_gamma, fco_beta, (float*)d_out, O);
}

// Round 9
// 384.188 us; speedup vs baseline: 1.8902x; 1.1009x over previous
//
#include <hip/hip_runtime.h>
#include <hip/hip_bf16.h>

#define BB 256
#define CC 64
#define TT 40
#define DD 2560   // CC*TT
#define V1 25
#define V2 10
#define INTER 16
#define NH 8
#define DSH 320   // DD/NH
#define HSLAB 8000  // V1*TT*8 elems per (b,h) slab in head-major layout

typedef __hip_bfloat16 bf16;
typedef unsigned int uint;
typedef unsigned short ushort;
typedef __attribute__((ext_vector_type(8))) short bf16x8;
typedef __attribute__((ext_vector_type(4))) float f32x4;

__device__ __forceinline__ float b2f(bf16 x) { return __bfloat162float(x); }

__device__ __forceinline__ ushort f2bb(float f) {
    uint x = __float_as_uint(f);
    uint r = x + 0x7fffu + ((x >> 16) & 1u);
    return (ushort)(r >> 16);
}
__device__ __forceinline__ float blo(uint u) { return __uint_as_float(u << 16); }
__device__ __forceinline__ float bhi(uint u) { return __uint_as_float(u & 0xffff0000u); }
__device__ __forceinline__ float b2f_us(ushort h) { return __uint_as_float(((uint)h) << 16); }
__device__ __forceinline__ uint4 pack8(const float* a) {
    uint4 pk;
    pk.x = (uint)f2bb(a[0]) | ((uint)f2bb(a[1]) << 16);
    pk.y = (uint)f2bb(a[2]) | ((uint)f2bb(a[3]) << 16);
    pk.z = (uint)f2bb(a[4]) | ((uint)f2bb(a[5]) << 16);
    pk.w = (uint)f2bb(a[6]) | ((uint)f2bb(a[7]) << 16);
    return pk;
}

// LDS swizzle helpers (ushort index). 64-ushort (128B) rows, 16B-granule XOR
// by low row bits -> every vectorized access pattern hits its bank floor.
__device__ __forceinline__ int swz64(int row, int col) {
    return row * 64 + ((((col >> 3) ^ row) & 7) << 3) + (col & 7);
}
// 128-ushort (256B) rows, granule XOR by (c&15)
__device__ __forceinline__ int swzC(int c, int col) {
    return c * 128 + ((((col >> 3) ^ c) & 15) << 3) + (col & 7);
}
// 320-ushort rows (attn): granule-XOR by row&7 (bijective within 8-granule grp)
__device__ __forceinline__ int swz320(int row, int k) {
    const int g = k >> 3;
    return row * 320 + (((g & ~7) | ((g ^ row) & 7)) << 3) + (k & 7);
}

// ---------------------------------------------------------------------------
// prep_wabf: 1 block. Pre-convert Wa/Wb into MFMA fragment order:
//   e < 768 : fck/fcv -> Wabf[s][mat4][lane][16]
//   e >= 768: fco     -> WabfO[s][mat2][lane][16]
// ---------------------------------------------------------------------------
__global__ __launch_bounds__(256) void prep_wabf(
    const float* __restrict__ Wa0, const float* __restrict__ Wb0,
    const float* __restrict__ Wa1, const float* __restrict__ Wb1,
    const float* __restrict__ WaO, const float* __restrict__ WbO,
    ushort* __restrict__ Wabf, ushort* __restrict__ WabfO) {
    const int tid = threadIdx.x;
    for (int e = tid; e < 1152; e += 256) {
        const float* Wp;
        ushort* dst;
        int s, lane;
        if (e < 768) {
            lane = e & 63;
            const int mat = (e >> 6) & 3;
            s = e >> 8;
            Wp = (mat == 0) ? Wa0 : (mat == 1) ? Wb0 : (mat == 2) ? Wa1 : Wb1;
            dst = Wabf + e * 16;
        } else {
            const int eo = e - 768;
            lane = eo & 63;
            const int mat = (eo >> 6) & 1;
            s = eo >> 7;
            Wp = mat ? WbO : WaO;
            dst = WabfO + eo * 16;
        }
        const int ln = lane & 15, lq = lane >> 4;
        const float* src = Wp + s * 1024 + ln * 64 + lq * 8;
        #pragma unroll
        for (int i = 0; i < 8; ++i) {
            dst[i] = f2bb(src[i]);
            dst[8 + i] = f2bb(src[32 + i]);
        }
    }
}

// ---------------------------------------------------------------------------
// gcn_S3 (V=25, fck+fcv fused): grid = (tc*256 + b), 1280 blocks x 512 thr.
// ---------------------------------------------------------------------------
__global__ __launch_bounds__(512) void gcn_S3(
    const float* __restrict__ X,
    const ushort* __restrict__ Wabf,
    const float* __restrict__ ba0, const float* __restrict__ bb0,
    const float* __restrict__ ba1, const float* __restrict__ bb1,
    bf16* __restrict__ Xw, float* __restrict__ Mpart) {
    __shared__ ushort xsT[208][72];    // [p=v*8+tl][c]; rows 200..207 garbage
    __shared__ ushort abT[4][32][136]; // [mat][v][j*8+tl]
    __shared__ float biasS3[192];      // [s][mat*16+j]

    const int tid = threadIdx.x;
    const int b = blockIdx.x & 255, tc = blockIdx.x >> 8;
    const int t0 = tc * 8;
    const int lane = tid & 63, w = tid >> 6;       // w 0..7
    const int ln = lane & 15, lq = lane >> 4;
    const int mat = w & 3, half = w >> 2;

    const float* Xb = X + (size_t)b * V1 * DD;
    for (int e = tid; e < V1 * 64; e += 512) {
        const int v = e >> 6, c = e & 63;
        const float* src = Xb + (size_t)v * DD + c * TT + t0;
        const float4 f0 = *(const float4*)src;
        const float4 f1 = *(const float4*)(src + 4);
        const float tmp[8] = {f0.x, f0.y, f0.z, f0.w, f1.x, f1.y, f1.z, f1.w};
        #pragma unroll
        for (int tl = 0; tl < 8; ++tl) xsT[v * 8 + tl][c] = f2bb(tmp[tl]);
    }
    if (tid < 192) {
        const int s = tid >> 6, m2 = (tid >> 4) & 3, j = tid & 15;
        const float* bp = (m2 == 0) ? ba0 : (m2 == 1) ? bb0 : (m2 == 2) ? ba1 : bb1;
        biasS3[tid] = bp[s * 16 + j];
    }
    __syncthreads();                   // xsT + biasS3 complete

    for (int e = tid; e < 1600; e += 512) {
        const int v = e >> 6, h = (e >> 3) & 7, tl = e & 7;
        *(uint4*)(Xw + (size_t)(b * NH + h) * HSLAB + v * 320 + (t0 + tl) * 8) =
            *(const uint4*)&xsT[v * 8 + tl][h * 8];
    }

    for (int s = 0; s < 3; ++s) {
        const ushort* wp = Wabf + (((s * 4 + mat) * 64 + lane) << 4);
        union { uint4 u; bf16x8 v; } ua, ub;
        ua.u = *(const uint4*)wp;
        ub.u = *(const uint4*)(wp + 8);
        float br[4];
        #pragma unroll
        for (int r = 0; r < 4; ++r) br[r] = biasS3[s * 64 + mat * 16 + lq * 4 + r];

        if (s) __syncthreads();        // Gram[s-1] done reading abT

        const int ntEnd = half ? 13 : 7;
        for (int nt = half ? 7 : 0; nt < ntEnd; ++nt) {
            const bf16x8 b0 = *(const bf16x8*)&xsT[nt * 16 + ln][lq * 8];
            const bf16x8 b1 = *(const bf16x8*)&xsT[nt * 16 + ln][lq * 8 + 32];
            f32x4 acc = (f32x4){0.f, 0.f, 0.f, 0.f};
            acc = __builtin_amdgcn_mfma_f32_16x16x32_bf16(ua.v, b0, acc, 0, 0, 0);
            acc = __builtin_amdgcn_mfma_f32_16x16x32_bf16(ub.v, b1, acc, 0, 0, 0);
            const int p = nt * 16 + ln;
            if (p < 200) {
                const int v = p >> 3, tl = p & 7;
                #pragma unroll
                for (int r = 0; r < 4; ++r)
                    abT[mat][v][(lq * 4 + r) * 8 + tl] = f2bb(acc[r] + br[r]);
            }
        }
        __syncthreads();               // abT ready

        {
            const int np = w >> 2, mt = (w >> 1) & 1, ntl = w & 1;
            const ushort* Ap = &abT[np * 2 + 0][mt * 16 + ln][lq * 8];
            const ushort* Bp = &abT[np * 2 + 1][ntl * 16 + ln][lq * 8];
            f32x4 g = (f32x4){0.f, 0.f, 0.f, 0.f};
            g = __builtin_amdgcn_mfma_f32_16x16x32_bf16(
                    *(const bf16x8*)Ap, *(const bf16x8*)Bp, g, 0, 0, 0);
            g = __builtin_amdgcn_mfma_f32_16x16x32_bf16(
                    *(const bf16x8*)(Ap + 32), *(const bf16x8*)(Bp + 32), g, 0, 0, 0);
            g = __builtin_amdgcn_mfma_f32_16x16x32_bf16(
                    *(const bf16x8*)(Ap + 64), *(const bf16x8*)(Bp + 64), g, 0, 0, 0);
            g = __builtin_amdgcn_mfma_f32_16x16x32_bf16(
                    *(const bf16x8*)(Ap + 96), *(const bf16x8*)(Bp + 96), g, 0, 0, 0);
            const int vp = ntl * 16 + ln;
            if (vp < V1) {
                float* Mb = Mpart + (((size_t)tc * 256 + b) * 6 + (s * 2 + np)) * 625;
                #pragma unroll
                for (int r = 0; r < 4; ++r) {
                    const int v = mt * 16 + lq * 4 + r;
                    if (v < V1) Mb[v * V1 + vp] = g[r];
                }
            }
        }
    }
}

// ---------------------------------------------------------------------------
// reduce_softmax (unchanged).
// ---------------------------------------------------------------------------
__global__ __launch_bounds__(128) void reduce_softmax(
    const float* __restrict__ Mpart,
    const float* __restrict__ PA0, const float* __restrict__ PA1,
    const float* __restrict__ WdK, const float* __restrict__ WdV,
    ushort* __restrict__ Sbf, ushort* __restrict__ Wdf) {
    __shared__ float Ms[625];
    const int tid = threadIdx.x, b = blockIdx.x, snp = blockIdx.y;
    const int s = snp >> 1, np = snp & 1;

    if (b == 0) {
        for (int e = tid; e < 256; e += 128) {
            const int wv = e >> 6, l = e & 63;
            const int lnn = l & 15, lqq = l >> 4;
            const float* Wp = (np ? WdV : WdK) + s * 4096 + (wv * 16 + lnn) * 64 + lqq * 8;
            ushort* dst = Wdf + (((np * 3 + s) * 4 + wv) * 64 + l) * 16;
            #pragma unroll
            for (int j = 0; j < 8; ++j) {
                dst[j] = f2bb(Wp[j]);
                dst[8 + j] = f2bb(Wp[32 + j]);
            }
        }
    }

    for (int e = tid; e < 625; e += 128) {
        float sum = 0.f;
        #pragma unroll
        for (int tcc = 0; tcc < 5; ++tcc)
            sum += Mpart[(((size_t)tcc * 256 + b) * 6 + snp) * 625 + e];
        Ms[e] = sum;
    }
    __syncthreads();
    if (tid < 32) {
        ushort* SbfRow = Sbf + ((((size_t)b * 2 + np) * 3 + s) << 10) + tid * 32;
        if (tid < V1) {
            const int vp = tid;
            const float invIT = 1.0f / 640.0f;
            float mx = -1e30f;
            for (int v = 0; v < V1; ++v) mx = fmaxf(mx, Ms[v * V1 + vp]);
            float sum = 0.f;
            for (int v = 0; v < V1; ++v) sum += expf((Ms[v * V1 + vp] - mx) * invIT);
            const float rs = 1.f / sum;
            const float* PAn = np ? PA1 : PA0;
            for (int v = 0; v < V1; ++v) {
                const float e_ = expf((Ms[v * V1 + vp] - mx) * invIT);
                SbfRow[v] = f2bb(e_ * rs + PAn[(s * V1 + v) * V1 + vp]);
            }
            for (int v = V1; v < 32; ++v) SbfRow[v] = 0;
        } else {
            for (int v = 0; v < 32; ++v) SbfRow[v] = 0;
        }
    }
}

// ---------------------------------------------------------------------------
// gcn_S2O (V=10 fco) — MFMA version, s-fused. grid (256 b) x 256 thr.
// Per chunk (5): stage xsT (bf16 [p=v*8+tl][c] swz64) once; proj MFMA
// (30 tiles: s x mat x nt, A-frags from WabfO/L2); Gram MFMA (wave s,
// K=128/chunk, acc persistent). abT rows v>=10 zeroed once -> contribute 0.
// Tail: column softmax + PA -> SbfO (same layout as before). b==0 emits Wdf3.
// ---------------------------------------------------------------------------
__global__ __launch_bounds__(256) void gcn_S2O(
    const float* __restrict__ X,
    const ushort* __restrict__ WabfO,
    const float* __restrict__ ba0, const float* __restrict__ bb0,
    const float* __restrict__ PA0, const float* __restrict__ WdO,
    ushort* __restrict__ SbfO, ushort* __restrict__ Wdf3) {
    __shared__ ushort xsT[80 * 64];        // swz64
    __shared__ ushort abT[3][2][16][136];  // [s][mat][v][j*8+tl]; v>=10 zero
    __shared__ float biasS[96];            // [s][mat*16+j]
    __shared__ float Ms[3][16][16];        // [s][v][vp]

    const int tid = threadIdx.x, b = blockIdx.x;
    const int lane = tid & 63, w = tid >> 6;
    const int ln = lane & 15, lq = lane >> 4;

    if (b == 0) {   // Wdf3 prep (fco Wd fragment order [s][wv][lane][16])
        for (int e = tid; e < 768; e += 256) {
            const int s = e >> 8, wv = (e >> 6) & 3, l = e & 63;
            const int lnn = l & 15, lqq = l >> 4;
            const float* Wp = WdO + s * 4096 + (wv * 16 + lnn) * 64 + lqq * 8;
            ushort* dst = Wdf3 + (((s * 4 + wv) * 64 + l) << 4);
            #pragma unroll
            for (int j = 0; j < 8; ++j) {
                dst[j] = f2bb(Wp[j]);
                dst[8 + j] = f2bb(Wp[32 + j]);
            }
        }
    }
    // zero abT once (rows v>=10 stay zero -> Gram contributions are 0)
    for (int e = tid; e < 6528; e += 256) ((uint*)abT)[e] = 0u;
    if (tid < 96) {
        const int s = tid >> 5, m = (tid >> 4) & 1, j = tid & 15;
        biasS[tid] = (m ? bb0 : ba0)[s * 16 + j];
    }

    f32x4 gacc = (f32x4){0.f, 0.f, 0.f, 0.f};
    const float* Xb = X + (size_t)b * V2 * DD;

    for (int tc = 0; tc < 5; ++tc) {
        const int t0 = tc * 8;
        // ---- stage xsT (fp32 -> bf16, transposed) ----
        for (int e = tid; e < 640; e += 256) {
            const int v = e >> 6, c = e & 63;
            const float* src = Xb + (size_t)v * DD + c * TT + t0;
            const float4 f0 = *(const float4*)src;
            const float4 f1 = *(const float4*)(src + 4);
            const float tmp[8] = {f0.x, f0.y, f0.z, f0.w, f1.x, f1.y, f1.z, f1.w};
            #pragma unroll
            for (int tl = 0; tl < 8; ++tl) xsT[swz64(v * 8 + tl, c)] = f2bb(tmp[tl]);
        }
        __syncthreads();   // xsT ready (also covers abT-zero/biasS on tc=0,
                           // and Gram[tc-1] done reading abT)

        // ---- proj MFMA: 30 tiles (s, mat, nt); wave w takes r10 = w, w+4, w+8
        for (int s = 0; s < 3; ++s) {
            const ushort* wp0 = WabfO + (((s * 2 + 0) * 64 + lane) << 4);
            const ushort* wp1 = WabfO + (((s * 2 + 1) * 64 + lane) << 4);
            union { uint4 u; bf16x8 v; } a00, a01, a10, a11;
            a00.u = *(const uint4*)wp0;  a01.u = *(const uint4*)(wp0 + 8);
            a10.u = *(const uint4*)wp1;  a11.u = *(const uint4*)(wp1 + 8);
            for (int r10 = w; r10 < 10; r10 += 4) {
                const int mat = (r10 >= 5) ? 1 : 0;
                const int nt = mat ? (r10 - 5) : r10;
                const bf16x8 b0 = *(const bf16x8*)&xsT[swz64(nt * 16 + ln, lq * 8)];
                const bf16x8 b1 = *(const bf16x8*)&xsT[swz64(nt * 16 + ln, lq * 8 + 32)];
                f32x4 acc = (f32x4){0.f, 0.f, 0.f, 0.f};
                acc = __builtin_amdgcn_mfma_f32_16x16x32_bf16(
                        mat ? a10.v : a00.v, b0, acc, 0, 0, 0);
                acc = __builtin_amdgcn_mfma_f32_16x16x32_bf16(
                        mat ? a11.v : a01.v, b1, acc, 0, 0, 0);
                const int p = nt * 16 + ln;   // < 80 always
                const int v = p >> 3, tl = p & 7;
                #pragma unroll
                for (int r = 0; r < 4; ++r)
                    abT[s][mat][v][(lq * 4 + r) * 8 + tl] =
                        f2bb(acc[r] + biasS[s * 32 + mat * 16 + lq * 4 + r]);
            }
        }
        __syncthreads();   // abT ready

        // ---- Gram MFMA: wave s computes M_s (K=128 this chunk) ----
        if (w < 3) {
            const ushort* Ap = &abT[w][0][ln][lq * 8];
            const ushort* Bp = &abT[w][1][ln][lq * 8];
            gacc = __builtin_amdgcn_mfma_f32_16x16x32_bf16(
                    *(const bf16x8*)Ap, *(const bf16x8*)Bp, gacc, 0, 0, 0);
            gacc = __builtin_amdgcn_mfma_f32_16x16x32_bf16(
                    *(const bf16x8*)(Ap + 32), *(const bf16x8*)(Bp + 32), gacc, 0, 0, 0);
            gacc = __builtin_amdgcn_mfma_f32_16x16x32_bf16(
                    *(const bf16x8*)(Ap + 64), *(const bf16x8*)(Bp + 64), gacc, 0, 0, 0);
            gacc = __builtin_amdgcn_mfma_f32_16x16x32_bf16(
                    *(const bf16x8*)(Ap + 96), *(const bf16x8*)(Bp + 96), gacc, 0, 0, 0);
        }
    }

    // ---- write M, softmax tail ----
    if (w < 3) {
        #pragma unroll
        for (int r = 0; r < 4; ++r) Ms[w][lq * 4 + r][ln] = gacc[r];
    }
    __syncthreads();

    const float invIT = 1.0f / 640.0f;
    if (tid < 48) {
        const int s = tid >> 4, vp = tid & 15;
        ushort* So = SbfO + ((size_t)b * 3 + s) * 256 + vp * 16;
        if (vp < V2) {
            float mx = -1e30f;
            for (int v = 0; v < V2; ++v) mx = fmaxf(mx, Ms[s][v][vp]);
            float sum = 0.f;
            for (int v = 0; v < V2; ++v) sum += expf((Ms[s][v][vp] - mx) * invIT);
            const float rs = 1.f / sum;
            for (int v = 0; v < V2; ++v) {
                const float e_ = expf((Ms[s][v][vp] - mx) * invIT);
                So[v] = f2bb(e_ * rs + PA0[(s * V2 + v) * V2 + vp]);
            }
            for (int v = V2; v < 16; ++v) So[v] = 0;
        } else {
            for (int v = 0; v < 16; ++v) So[v] = 0;
        }
    }
}

// ---------------------------------------------------------------------------
// gcn_applyKV (unchanged, verified).
// ---------------------------------------------------------------------------
__global__ __launch_bounds__(256) void gcn_applyKV(
    const bf16* __restrict__ Xbf,
    const ushort* __restrict__ Sbf, const ushort* __restrict__ Wdf,
    const float* __restrict__ bdK, const float* __restrict__ gK, const float* __restrict__ beK,
    const float* __restrict__ bdV, const float* __restrict__ gV, const float* __restrict__ beV,
    bf16* __restrict__ Kg, bf16* __restrict__ Vg) {

    __shared__ ushort xsT[100 * 64];   // [p=v*4+tl][c], swz64 (persist)
    __shared__ ushort SlTs[6144];      // [(g*3+s)*1024 + vp*32 + v0] (persist)
    __shared__ ushort uC[8192];        // xsC [c][tl*32+v0] swzC, then zsT [p][c] swz64
    __shared__ float bias6[6 * 64];

    const int tid = threadIdx.x, b = blockIdx.x, chunk = blockIdx.y;
    const int lane = tid & 63, w = tid >> 6;
    const int ln = lane & 15, lq = lane >> 4;
    const int t0 = chunk * 4;

    if (tid < 64) {
        bias6[tid]       = bdK[tid] + bdK[64 + tid] + bdK[128 + tid];
        bias6[64 + tid]  = bdV[tid] + bdV[64 + tid] + bdV[128 + tid];
        bias6[128 + tid] = gK[tid] * rsqrtf(1.f + 1e-5f);
        bias6[192 + tid] = gV[tid] * rsqrtf(1.f + 1e-5f);
        bias6[256 + tid] = beK[tid];
        bias6[320 + tid] = beV[tid];
    }
    const bf16* Xb = Xbf + (size_t)b * NH * HSLAB;
    for (int e = tid; e < 1024; e += 256) {
        const int h = e >> 7, v = (e >> 2) & 31, tl = e & 3;
        if (v < V1)
            *(uint4*)&xsT[swz64(v * 4 + tl, h * 8)] =
                *(const uint4*)(Xb + (size_t)h * HSLAB + v * 320 + (t0 + tl) * 8);
    }
    {
        const ushort* Sb = Sbf + (size_t)b * 6144;
        for (int e = tid; e < 768; e += 256)
            ((uint4*)SlTs)[e] = ((const uint4*)Sb)[e];
    }
    __syncthreads();   // xsT + SlTs staged

    {
        const int c = lane, q = w;
        #pragma unroll
        for (int j = 0; j < 4; ++j) {
            ushort vals[8];
            #pragma unroll
            for (int i = 0; i < 8; ++i) {
                const int v0 = q * 8 + i;
                vals[i] = (v0 < V1) ? xsT[swz64(v0 * 4 + j, c)] : (ushort)0;
            }
            uint4 pk;
            pk.x = (uint)vals[0] | ((uint)vals[1] << 16);
            pk.y = (uint)vals[2] | ((uint)vals[3] << 16);
            pk.z = (uint)vals[4] | ((uint)vals[5] << 16);
            pk.w = (uint)vals[6] | ((uint)vals[7] << 16);
            *(uint4*)&uC[swzC(c, j * 32 + q * 8)] = pk;
        }
    }
    __syncthreads();   // xsC ready

    bf16x8 aF[4];
    #pragma unroll
    for (int tl = 0; tl < 4; ++tl)
        aF[tl] = *(const bf16x8*)&uC[swzC(w * 16 + ln, tl * 32 + lq * 8)];
    __syncthreads();   // aF reads done -> uC becomes zsT

    for (int g = 0; g < 2; ++g) {
        f32x4 acc[7];
        #pragma unroll
        for (int tn = 0; tn < 7; ++tn) acc[tn] = (f32x4){0.f, 0.f, 0.f, 0.f};

        for (int s = 0; s < 3; ++s) {
            const ushort* wp = Wdf + ((((g * 3 + s) * 4 + w) * 64 + lane) << 4);
            union { uint4 u; bf16x8 v; } ua, ub;
            ua.u = *(const uint4*)wp;
            ub.u = *(const uint4*)(wp + 8);

            if (g | s) __syncthreads();

            #pragma unroll
            for (int nt = 0; nt < 2; ++nt) {
                const bf16x8 bF =
                    *(const bf16x8*)&SlTs[((g * 3 + s) << 10) + (nt * 16 + ln) * 32 + lq * 8];
                const int v = nt * 16 + ln;
                #pragma unroll
                for (int tl = 0; tl < 4; ++tl) {
                    f32x4 d = (f32x4){0.f, 0.f, 0.f, 0.f};
                    d = __builtin_amdgcn_mfma_f32_16x16x32_bf16(aF[tl], bF, d, 0, 0, 0);
                    if (v < V1) {
                        uint2 pk;
                        pk.x = (uint)f2bb(d[0]) | ((uint)f2bb(d[1]) << 16);
                        pk.y = (uint)f2bb(d[2]) | ((uint)f2bb(d[3]) << 16);
                        *(uint2*)&uC[swz64(v * 4 + tl, w * 16 + lq * 4)] = pk;
                    }
                }
            }
            __syncthreads();   // zsT ready

            #pragma unroll
            for (int tn = 0; tn < 7; ++tn) {
                const bf16x8 b0 = *(const bf16x8*)&uC[swz64(tn * 16 + ln, lq * 8)];
                const bf16x8 b1 = *(const bf16x8*)&uC[swz64(tn * 16 + ln, lq * 8 + 32)];
                acc[tn] = __builtin_amdgcn_mfma_f32_16x16x32_bf16(ua.v, b0, acc[tn], 0, 0, 0);
                acc[tn] = __builtin_amdgcn_mfma_f32_16x16x32_bf16(ub.v, b1, acc[tn], 0, 0, 0);
            }
        }
        __syncthreads();   // GEMM-2 done reading zsT

        {
            const int c0 = w * 16 + lq * 4;
            float bb[4], ss[4], be[4];
            #pragma unroll
            for (int r = 0; r < 4; ++r) {
                bb[r] = bias6[g * 64 + c0 + r];
                ss[r] = bias6[128 + g * 64 + c0 + r];
                be[r] = bias6[256 + g * 64 + c0 + r];
            }
            #pragma unroll
            for (int tn = 0; tn < 7; ++tn) {
                const int p = tn * 16 + ln;
                if (p < 100) {
                    const uint2 u = *(const uint2*)&xsT[swz64(p, c0)];
                    const float rs[4] = {blo(u.x), bhi(u.x), blo(u.y), bhi(u.y)};
                    float y[4];
                    #pragma unroll
                    for (int r = 0; r < 4; ++r)
                        y[r] = fmaxf((acc[tn][r] + bb[r]) * ss[r] + be[r] + rs[r], 0.f);
                    uint2 pk;
                    pk.x = (uint)f2bb(y[0]) | ((uint)f2bb(y[1]) << 16);
                    pk.y = (uint)f2bb(y[2]) | ((uint)f2bb(y[3]) << 16);
                    *(uint2*)&uC[swz64(p, c0)] = pk;
                }
            }
        }
        __syncthreads();

        bf16* outp = (g ? Vg : Kg) + (size_t)b * NH * HSLAB;
        for (int e = tid; e < 1024; e += 256) {
            const int h = e >> 7, v = (e >> 2) & 31, tl = e & 3;
            if (v < V1)
                *(uint4*)(outp + (size_t)h * HSLAB + v * 320 + (t0 + tl) * 8) =
                    *(const uint4*)&uC[swz64(v * 4 + tl, h * 8)];
        }
    }
}

// ---------------------------------------------------------------------------
// gcn_applyO (unchanged).
// ---------------------------------------------------------------------------
__global__ __launch_bounds__(256) void gcn_applyO(
    const float* __restrict__ X,            // O fp32 (b, v=10, c, t)
    const ushort* __restrict__ SbfO, const ushort* __restrict__ Wdf3,
    const float* __restrict__ bdO, const float* __restrict__ gO, const float* __restrict__ beO,
    float* __restrict__ out_f, const float* __restrict__ Obuf) {

    __shared__ ushort xsT[80 * 64];    // [p=v*8+tl][c], swz64 (persist: residual)
    __shared__ ushort uC[8192];        // xsC16 [c][tl*16+v0] swzC, then zsT [p][c] swz64
    __shared__ ushort SlTs16[832];     // [s][v][v0] 3*16*16 (+spec-pad)
    __shared__ float bias3[3 * 64];

    const int tid = threadIdx.x, b = blockIdx.x, chunk = blockIdx.y;
    const int lane = tid & 63, w = tid >> 6;
    const int ln = lane & 15, lq = lane >> 4;
    const int t0 = chunk * 8;

    if (tid < 64) {
        bias3[tid]       = bdO[tid] + bdO[64 + tid] + bdO[128 + tid];
        bias3[64 + tid]  = gO[tid] * rsqrtf(1.f + 1e-5f);
        bias3[128 + tid] = beO[tid];
    }
    const float* Xb = X + (size_t)b * V2 * DD;
    for (int e = tid; e < 640; e += 256) {
        const int v = e >> 6, c = e & 63;
        const float* src = Xb + (size_t)v * DD + c * TT + t0;
        const float4 f0 = *(const float4*)src;
        const float4 f1 = *(const float4*)(src + 4);
        const float tmp[8] = {f0.x, f0.y, f0.z, f0.w, f1.x, f1.y, f1.z, f1.w};
        #pragma unroll
        for (int tl = 0; tl < 8; ++tl) xsT[swz64(v * 8 + tl, c)] = f2bb(tmp[tl]);
    }
    {
        const uint4* Sb = (const uint4*)(SbfO + (size_t)b * 768);
        for (int e = tid; e < 96; e += 256) ((uint4*)SlTs16)[e] = Sb[e];
    }
    __syncthreads();   // xsT + SlTs16 staged

    {
        const int c = lane;
        #pragma unroll
        for (int jj = 0; jj < 4; ++jj) {
            const int u_ = w * 4 + jj;            // 16 combos: tl(8) x q(2)
            const int tl = u_ >> 1, q = u_ & 1;
            ushort vals[8];
            #pragma unroll
            for (int i = 0; i < 8; ++i) {
                const int v0 = q * 8 + i;
                vals[i] = (v0 < V2) ? xsT[swz64(v0 * 8 + tl, c)] : (ushort)0;
            }
            uint4 pk;
            pk.x = (uint)vals[0] | ((uint)vals[1] << 16);
            pk.y = (uint)vals[2] | ((uint)vals[3] << 16);
            pk.z = (uint)vals[4] | ((uint)vals[5] << 16);
            pk.w = (uint)vals[6] | ((uint)vals[7] << 16);
            *(uint4*)&uC[swzC(c, tl * 16 + q * 8)] = pk;
        }
    }
    __syncthreads();   // xsC16 ready

    union { uint4 u; bf16x8 v; } z8; z8.u = (uint4){0u, 0u, 0u, 0u};
    bf16x8 aF[8];
    #pragma unroll
    for (int tl = 0; tl < 8; ++tl)
        aF[tl] = (lq < 2) ? *(const bf16x8*)&uC[swzC(w * 16 + ln, tl * 16 + lq * 8)]
                          : z8.v;
    __syncthreads();   // aF reads done -> uC becomes zsT

    f32x4 acc[5];
    #pragma unroll
    for (int tn = 0; tn < 5; ++tn) acc[tn] = (f32x4){0.f, 0.f, 0.f, 0.f};

    for (int s = 0; s < 3; ++s) {
        const ushort* wp = Wdf3 + (((s * 4 + w) * 64 + lane) << 4);
        union { uint4 u; bf16x8 v; } ua, ub;
        ua.u = *(const uint4*)wp;
        ub.u = *(const uint4*)(wp + 8);

        if (s) __syncthreads();   // prior GEMM-2 done with zsT

        const bf16x8 bF = (lq < 2)
            ? *(const bf16x8*)&SlTs16[s * 256 + ln * 16 + lq * 8] : z8.v;
        #pragma unroll
        for (int tl = 0; tl < 8; ++tl) {
            f32x4 d = (f32x4){0.f, 0.f, 0.f, 0.f};
            d = __builtin_amdgcn_mfma_f32_16x16x32_bf16(aF[tl], bF, d, 0, 0, 0);
            if (ln < V2) {    // col = ln -> v
                uint2 pk;
                pk.x = (uint)f2bb(d[0]) | ((uint)f2bb(d[1]) << 16);
                pk.y = (uint)f2bb(d[2]) | ((uint)f2bb(d[3]) << 16);
                *(uint2*)&uC[swz64(ln * 8 + tl, w * 16 + lq * 4)] = pk;
            }
        }
        __syncthreads();   // zsT ready

        #pragma unroll
        for (int tn = 0; tn < 5; ++tn) {
            const bf16x8 b0 = *(const bf16x8*)&uC[swz64(tn * 16 + ln, lq * 8)];
            const bf16x8 b1 = *(const bf16x8*)&uC[swz64(tn * 16 + ln, lq * 8 + 32)];
            acc[tn] = __builtin_amdgcn_mfma_f32_16x16x32_bf16(ua.v, b0, acc[tn], 0, 0, 0);
            acc[tn] = __builtin_amdgcn_mfma_f32_16x16x32_bf16(ub.v, b1, acc[tn], 0, 0, 0);
        }
    }
    __syncthreads();   // GEMM-2 done reading zsT

    {
        const int c0 = w * 16 + lq * 4;
        float bb[4], ss[4], be[4];
        #pragma unroll
        for (int r = 0; r < 4; ++r) {
            bb[r] = bias3[c0 + r];
            ss[r] = bias3[64 + c0 + r];
            be[r] = bias3[128 + c0 + r];
        }
        #pragma unroll
        for (int tn = 0; tn < 5; ++tn) {
            const int p = tn * 16 + ln;   // < 80
            const uint2 u = *(const uint2*)&xsT[swz64(p, c0)];
            const float rs[4] = {blo(u.x), bhi(u.x), blo(u.y), bhi(u.y)};
            float y[4];
            #pragma unroll
            for (int r = 0; r < 4; ++r)
                y[r] = fmaxf((acc[tn][r] + bb[r]) * ss[r] + be[r] + rs[r], 0.f);
            uint2 pk;
            pk.x = (uint)f2bb(y[0]) | ((uint)f2bb(y[1]) << 16);
            pk.y = (uint)f2bb(y[2]) | ((uint)f2bb(y[3]) << 16);
            *(uint2*)&uC[swz64(p, c0)] = pk;
        }
    }
    __syncthreads();

    {
        const int v = tid & 15, ci = tid >> 4;
        if (v < V2) {
            #pragma unroll
            for (int r = 0; r < 4; ++r) {
                const int c = ci * 4 + r;
                const size_t base = (size_t)b * V2 * DD + (size_t)v * DD + c * TT + t0;
                const float4 o0 = *(const float4*)&Obuf[base];
                const float4 o1 = *(const float4*)&Obuf[base + 4];
                float4 y0, y1;
                y0.x = o0.x + b2f_us(uC[swz64(v * 8 + 0, c)]);
                y0.y = o0.y + b2f_us(uC[swz64(v * 8 + 1, c)]);
                y0.z = o0.z + b2f_us(uC[swz64(v * 8 + 2, c)]);
                y0.w = o0.w + b2f_us(uC[swz64(v * 8 + 3, c)]);
                y1.x = o1.x + b2f_us(uC[swz64(v * 8 + 4, c)]);
                y1.y = o1.y + b2f_us(uC[swz64(v * 8 + 5, c)]);
                y1.z = o1.z + b2f_us(uC[swz64(v * 8 + 6, c)]);
                y1.w = o1.w + b2f_us(uC[swz64(v * 8 + 7, c)]);
                *(float4*)&out_f[base] = y0;
                *(float4*)&out_f[base + 4] = y1;
            }
        }
    }
}

// ---------------------------------------------------------------------------
// attention (MFMA QK + float4 PV, unchanged from round 8 — verified).
// ---------------------------------------------------------------------------
__global__ __launch_bounds__(256) void attn_kernel(const float* __restrict__ Q,
                                                   const bf16* __restrict__ Kg,
                                                   const bf16* __restrict__ Vg,
                                                   float* __restrict__ O) {
    __shared__ float smA[10240];       // 40,960B: qs2h+qs2l+ksw (bf16) -> vbuf fp32
    __shared__ float attP[4][16][16];  // per-wave QK partials
    __shared__ float attF[16][32];     // combined scores -> probabilities
    ushort* qs2h = (ushort*)smA;               // [16][320] swz320 (rows>=10 garbage)
    ushort* qs2l = (ushort*)smA + 5120;        // [16][320] swz320
    ushort* ksw  = (ushort*)smA + 10240;       // [32][320] swz320 (rows>=25 garbage)
    float* vbuf = smA;                         // [25][324] fp32 (overlays after QK)

    const int b = blockIdx.x, h = blockIdx.y, tid = threadIdx.x;
    const int lane = tid & 63, w = tid >> 6;
    const int ln = lane & 15, lq = lane >> 4;

    // ---- stage Q (hi/lo bf16, k-order) + K (direct slab copy, swizzled) ----
    const float* Qb = Q + (size_t)b * 10 * DD + h * DSH;
    for (int e = tid; e < 800; e += 256) {
        const int q = e / 80, seg = e % 80;
        const int dd0 = seg * 4;
        const float4 f = *(const float4*)(Qb + (size_t)q * DD + dd0);
        const float ff[4] = {f.x, f.y, f.z, f.w};
        #pragma unroll
        for (int j = 0; j < 4; ++j) {
            const int dd = dd0 + j;
            const int k = (dd % 40) * 8 + dd / 40;   // slab k-order
            const int idx = swz320(q, k);
            const ushort hi = f2bb(ff[j]);
            qs2h[idx] = hi;
            qs2l[idx] = f2bb(ff[j] - b2f_us(hi));
        }
    }
    const bf16* Kb = Kg + (size_t)(b * NH + h) * HSLAB;
    for (int e = tid; e < 1000; e += 256) {
        const int kk = e / 40, g = e % 40;
        const int gp = (g & ~7) | ((g ^ kk) & 7);
        *(uint4*)&ksw[kk * 320 + gp * 8] = *(const uint4*)(Kb + (size_t)e * 8);
    }
    __syncthreads();

    // ---- QK^T MFMA: wave w -> (ntl = w&1, k-chunks (w>>1)*5 .. +4) ----
    {
        const int ntl = w & 1;
        const int ch0 = (w >> 1) * 5;
        f32x4 d = (f32x4){0.f, 0.f, 0.f, 0.f};
        #pragma unroll
        for (int c5 = 0; c5 < 5; ++c5) {
            const int k0 = (ch0 + c5) * 32 + lq * 8;
            const bf16x8 ah = *(const bf16x8*)&qs2h[swz320(ln, k0)];
            const bf16x8 al = *(const bf16x8*)&qs2l[swz320(ln, k0)];
            const bf16x8 bF = *(const bf16x8*)&ksw[swz320(ntl * 16 + ln, k0)];
            d = __builtin_amdgcn_mfma_f32_16x16x32_bf16(ah, bF, d, 0, 0, 0);
            d = __builtin_amdgcn_mfma_f32_16x16x32_bf16(al, bF, d, 0, 0, 0);
        }
        #pragma unroll
        for (int r = 0; r < 4; ++r) attP[w][lq * 4 + r][ln] = d[r];
    }
    __syncthreads();   // attP complete; qs2/ksw dead

    // ---- combine partials + scale; stage V fp32 (stride 324) over smA ----
    const float scale = 0.019764235376052370f;  // 1/sqrt(2560)
    for (int e = tid; e < 512; e += 256) {
        const int q = e >> 5, kk = e & 31;
        const int ntl = kk >> 4, kkl = kk & 15;
        attF[q][kk] = (attP[ntl][q][kkl] + attP[ntl + 2][q][kkl]) * scale;
    }
    const bf16* Vb = Vg + (size_t)(b * NH + h) * HSLAB;
    for (int e = tid; e < 1000; e += 256) {
        const int kk = e / TT, t = e % TT;
        const uint4 u = *(const uint4*)(Vb + (size_t)e * 8);
        const ushort* us = (const ushort*)&u;
        float* dst = &vbuf[kk * 324 + t];
        #pragma unroll
        for (int cl = 0; cl < 8; ++cl) dst[cl * 40] = b2f_us(us[cl]);
    }
    __syncthreads();   // attF raw scores + vbuf ready

    // ---- softmax over kk per q row ----
    if (tid < 10) {
        float mx = -1e30f;
        for (int k = 0; k < V1; ++k) mx = fmaxf(mx, attF[tid][k]);
        float sum = 0.f;
        for (int k = 0; k < V1; ++k) {
            float e_ = expf(attF[tid][k] - mx);
            attF[tid][k] = e_;
            sum += e_;
        }
        float r = 1.0f / sum;
        for (int k = 0; k < V1; ++k) attF[tid][k] *= r;
    }
    __syncthreads();

    // ---- PV (float4) + residual from global Q (L2-hot) ----
    float* Ob = O + (size_t)b * 10 * DD + h * DSH;
    for (int e = tid; e < 800; e += 256) {
        const int q = e / 80, seg = e % 80;
        const int dl0 = seg * 4;
        float ax = 0.f, ay = 0.f, az = 0.f, aw = 0.f;
        #pragma unroll
        for (int kk = 0; kk < V1; ++kk) {
            const float a = attF[q][kk];
            const float4 v = *(const float4*)&vbuf[kk * 324 + dl0];
            ax += a * v.x; ay += a * v.y; az += a * v.z; aw += a * v.w;
        }
        const float4 qv = *(const float4*)(Qb + (size_t)q * DD + dl0);
        float4 o;
        o.x = qv.x + ax; o.y = qv.y + ay; o.z = qv.z + az; o.w = qv.w + aw;
        *(float4*)(Ob + (size_t)q * DD + dl0) = o;
    }
}

// ---------------------------------------------------------------------------
extern "C" void kernel_launch(void* const* d_in, const int* in_sizes, int n_in,
                              void* d_out, int out_size, void* d_ws, size_t ws_size,
                              hipStream_t stream) {
    const float* Q = (const float*)d_in[0];
    const float* K = (const float*)d_in[1];
    const float* fck_PA = (const float*)d_in[2];
    const float* fck_Wa = (const float*)d_in[3];
    const float* fck_ba = (const float*)d_in[4];
    const float* fck_Wb = (const float*)d_in[5];
    const float* fck_bb = (const float*)d_in[6];
    const float* fck_Wd = (const float*)d_in[7];
    const float* fck_bd = (const float*)d_in[8];
    const float* fck_gamma = (const float*)d_in[9];
    const float* fck_beta = (const float*)d_in[10];
    const float* fcv_PA = (const float*)d_in[11];
    const float* fcv_Wa = (const float*)d_in[12];
    const float* fcv_ba = (const float*)d_in[13];
    const float* fcv_Wb = (const float*)d_in[14];
    const float* fcv_bb = (const float*)d_in[15];
    const float* fcv_Wd = (const float*)d_in[16];
    const float* fcv_bd = (const float*)d_in[17];
    const float* fcv_gamma = (const float*)d_in[18];
    const float* fcv_beta = (const float*)d_in[19];
    const float* fco_PA = (const float*)d_in[20];
    const float* fco_Wa = (const float*)d_in[21];
    const float* fco_ba = (const float*)d_in[22];
    const float* fco_Wb = (const float*)d_in[23];
    const float* fco_bb = (const float*)d_in[24];
    const float* fco_Wd = (const float*)d_in[25];
    const float* fco_bd = (const float*)d_in[26];
    const float* fco_gamma = (const float*)d_in[27];
    const float* fco_beta = (const float*)d_in[28];

    // Workspace map (round-9):
    //   [0, 32.768 MB)        Xbf (head-major bf16 K) — overwritten in place
    //                         by gcn_applyKV as Vg (same addressing).
    //   [32.768, 65.536)      Kg (head-major; dead after attn) — then SbfO
    //                         (393 KB) + Wdf3 (24.6 KB) for the fco tail.
    //   [65.536, 84.736)      Mpart (S3->reduce);  then O (attn->applyO)
    //   [65.536, 91.750)        O spans this region (disjoint lifetimes)
    //   [84.736, 87.882)      Sbf  (reduce->applyKV, dead before attn)
    //   [88.000, 88.197)      Wdf  (reduce->applyKV, dead before attn)
    //   [95.590, 95.623)      Wabf (24.6 KB) + WabfO (12.3 KB @ +32768)
    char* wsb = (char*)d_ws;
    bf16* Xbf = (bf16*)(wsb);
    bf16* Vg = (bf16*)(wsb);                     // in-place over Xbf
    bf16* Kg = (bf16*)(wsb + 32768000);
    float* Mpart = (float*)(wsb + 65536000);     // [5][256][6][625] fp32 = 19.2 MB
    float* O = (float*)(wsb + 65536000);         // 26.2 MB, live after applyKV
    ushort* Sbf = (ushort*)(wsb + 84736000);     // [256][2][3][32][32] bf16 = 3.1 MB
    ushort* Wdf = (ushort*)(wsb + 88000000);     // [2][3][4][64][16] bf16 = 192 KB
    ushort* SbfO = (ushort*)(wsb + 32768000);    // [256][3][16][16] bf16 (over dead Kg)
    ushort* Wdf3 = (ushort*)(wsb + 33300000);    // [3][4][64][16] bf16 = 24.6 KB
    ushort* Wabf = (ushort*)(wsb + 95590400);    // [3][4][64][16] bf16 = 24.6 KB
    ushort* WabfO = (ushort*)(wsb + 95590400 + 32768);  // [3][2][64][16] bf16 = 12.3 KB

    prep_wabf<<<dim3(1), dim3(256), 0, stream>>>(
        fck_Wa, fck_Wb, fcv_Wa, fcv_Wb, fco_Wa, fco_Wb, Wabf, WabfO);

    gcn_S3<<<dim3(BB * 5), dim3(512), 0, stream>>>(
        K, Wabf, fck_ba, fck_bb, fcv_ba, fcv_bb, Xbf, Mpart);

    reduce_softmax<<<dim3(BB, 6), dim3(128), 0, stream>>>(
        Mpart, fck_PA, fcv_PA, fck_Wd, fcv_Wd, Sbf, Wdf);

    gcn_applyKV<<<dim3(BB, 10), dim3(256), 0, stream>>>(
        Xbf, Sbf, Wdf,
        fck_bd, fck_gamma, fck_beta,
        fcv_bd, fcv_gamma, fcv_beta, Kg, Vg);

    attn_kernel<<<dim3(BB, NH), dim3(256), 0, stream>>>(Q, Kg, Vg, O);

    gcn_S2O<<<dim3(BB), dim3(256), 0, stream>>>(
        O, WabfO, fco_ba, fco_bb, fco_PA, fco_Wd, SbfO, Wdf3);

    gcn_applyO<<<dim3(BB, 5), dim3(256), 0, stream>>>(
        O, SbfO, Wdf3, fco_bd, fco_gamma, fco_beta, (float*)d_out, O);
}